// Round 6
// baseline (342.261 us; speedup 1.0000x reference)
//
#include <hip/hip_runtime.h>
#include <hip/hip_bf16.h>
#include <math.h>

constexpr int BB = 4;
constexpr int NN = 4096;
constexpr int CC = 512;
constexpr int HH = 8;
constexpr int DD = 64;
constexpr int NCNT = NN - 2;

typedef __bf16 bf16x8 __attribute__((ext_vector_type(8)));
typedef float f32x4 __attribute__((ext_vector_type(4)));

__device__ __forceinline__ float b2f(ushort u) {
  unsigned v = ((unsigned)u) << 16;
  return __builtin_bit_cast(float, v);
}
__device__ __forceinline__ ushort f2b(float f) {
  __hip_bfloat16 h = __float2bfloat16(f);
  return __builtin_bit_cast(ushort, h);
}
__device__ __forceinline__ void gload16(const ushort* g, ushort* l) {
  __builtin_amdgcn_global_load_lds(
      (const __attribute__((address_space(1))) unsigned int*)g,
      (__attribute__((address_space(3))) unsigned int*)l, 16, 0, 0);
}

// ---------------------------------------------------------------------------
// K1: second-diff sign counts (sliding window) + fused x -> bf16
// ---------------------------------------------------------------------------
__global__ void k_counts_prep(const float* __restrict__ x,
                              int* __restrict__ peak, int* __restrict__ valley,
                              ushort* __restrict__ Xh) {
  int b = blockIdx.x >> 6;
  int tile = blockIdx.x & 63;
  int c = threadIdx.x;
  int lane = threadIdx.x & 63;
  int i0 = tile * 64;
  const float* xb = x + (size_t)b * NN * CC + c;
  float x0 = xb[(size_t)i0 * CC];
  float x1 = xb[(size_t)(i0 + 1 < NN ? i0 + 1 : i0) * CC];
  for (int ii = 0; ii < 64; ++ii) {
    int i = i0 + ii;
    Xh[((size_t)b * NN + i) * CC + c] = f2b(x0);
    if (i < NCNT) {
      float x2 = xb[(size_t)(i + 2) * CC];
      float d2 = (x2 - x1) - (x1 - x0);
      unsigned long long mneg = __ballot(d2 < 0.0f);
      unsigned long long mpos = __ballot(d2 > 0.0f);
      if (lane == 0) {
        atomicAdd(&peak[i], __popcll(mneg));
        atomicAdd(&valley[i], __popcll(mpos));
      }
      x0 = x1; x1 = x2;
    } else {
      x0 = x1;  // i = 4094 -> next writes x[4095]
    }
  }
}

// ---------------------------------------------------------------------------
// K2pre: Gaussian tables etab[a] = exp(-(a*iw)^2), a in 0..4095
// ---------------------------------------------------------------------------
__global__ void k_etab(const float* __restrict__ lpw, const float* __restrict__ lvw,
                       float* __restrict__ etabP, float* __restrict__ etabV) {
  int i = blockIdx.x * 256 + threadIdx.x;
  float ipw = expf(-lpw[0]);
  float ivw = expf(-lvw[0]);
  float t1 = (float)i * ipw;
  float t2 = (float)i * ivw;
  etabP[i] = expf(-t1 * t1);
  etabV[i] = expf(-t2 * t2);
}

// ---------------------------------------------------------------------------
// K2a: Gaussian sums via tables (args bit-identical to direct exp form)
// ---------------------------------------------------------------------------
__global__ void k_gsum(const int* __restrict__ peak, const int* __restrict__ valley,
                       const float* __restrict__ etabP, const float* __restrict__ etabV,
                       float* __restrict__ attn) {
  int p = blockIdx.x;
  int tid = threadIdx.x;
  float acc = 0.f;
  for (int i = tid; i < NCNT; i += 256) {
    int a = p - 1 - i;
    a = a < 0 ? -a : a;
    acc += (float)peak[i] * etabP[a] + (float)valley[i] * etabV[a];
  }
  __shared__ float red[256];
  red[tid] = acc;
  __syncthreads();
  for (int s = 128; s > 0; s >>= 1) {
    if (tid < s) red[tid] += red[tid + s];
    __syncthreads();
  }
  if (tid == 0) attn[p] = red[0];
}

// ---------------------------------------------------------------------------
// K2b: min-max normalize
// ---------------------------------------------------------------------------
__global__ void k_norm(const float* __restrict__ attn, float* __restrict__ gate) {
  int tid = threadIdx.x;  // 1024
  float v0 = attn[tid], v1 = attn[tid + 1024], v2 = attn[tid + 2048], v3 = attn[tid + 3072];
  float mn = fminf(fminf(v0, v1), fminf(v2, v3));
  float mx = fmaxf(fmaxf(v0, v1), fmaxf(v2, v3));
  __shared__ float rmn[1024], rmx[1024];
  rmn[tid] = mn; rmx[tid] = mx;
  __syncthreads();
  for (int s = 512; s > 0; s >>= 1) {
    if (tid < s) {
      rmn[tid] = fminf(rmn[tid], rmn[tid + s]);
      rmx[tid] = fmaxf(rmx[tid], rmx[tid + s]);
    }
    __syncthreads();
  }
  float lo = rmn[0];
  float denom = rmx[0] - rmn[0] + 1e-6f;
  gate[tid]        = (v0 - lo) / denom;
  gate[tid + 1024] = (v1 - lo) / denom;
  gate[tid + 2048] = (v2 - lo) / denom;
  gate[tid + 3072] = (v3 - lo) / denom;
}

// ---------------------------------------------------------------------------
// K3a: spectral PE conv path -> pe2 [64][4096]
// ---------------------------------------------------------------------------
__global__ void k_pe(const float* __restrict__ omega,
                     const float* __restrict__ w1, const float* __restrict__ b1,
                     const float* __restrict__ w2, const float* __restrict__ b2,
                     float* __restrict__ pe2) {
  int n = blockIdx.x;
  int j = threadIdx.x;  // 64
  __shared__ float pec[3][64];
  __shared__ float hs[128];
  for (int t = 0; t < 3; ++t) {
    int m = n + t - 1;
    float v = 0.f;
    if (m >= 0 && m < NN) {
      int l1 = m >> 6, l2 = m & 63;
      float rel = (float)(l1 - l2);
      v = (j < 32) ? sinf(rel * omega[j]) : cosf(rel * omega[j - 32]);
    }
    pec[t][j] = v;
  }
  __syncthreads();
  for (int o = j; o < 128; o += 64) {
    int ci = o >> 1;
    float hv = b1[o];
    #pragma unroll
    for (int t = 0; t < 3; ++t) hv += pec[t][ci] * w1[o * 3 + t];
    hv = 0.5f * hv * (1.f + erff(hv * 0.70710678118654752f));
    hs[o] = hv;
  }
  __syncthreads();
  float acc = b2[j];
  for (int o = 0; o < 128; ++o) acc += hs[o] * w2[j * 128 + o];
  pe2[(size_t)j * NN + n] = acc;
}

// ---------------------------------------------------------------------------
// K3b: channel means -> sigmoid gate gpe[64]
// ---------------------------------------------------------------------------
__global__ void k_gatepe(const float* __restrict__ pe2,
                         const float* __restrict__ wg, const float* __restrict__ bg,
                         float* __restrict__ gpe) {
  int tid = threadIdx.x;  // 256
  int j = tid & 63, part = tid >> 6;
  float s = 0.f;
  const float* row = pe2 + (size_t)j * NN + part * 1024;
  for (int t = 0; t < 1024; ++t) s += row[t];
  __shared__ float ps[4][64];
  __shared__ float mean[64];
  ps[part][j] = s;
  __syncthreads();
  if (tid < 64) mean[j] = (ps[0][j] + ps[1][j] + ps[2][j] + ps[3][j]) * (1.f / 4096.f);
  __syncthreads();
  if (tid < 64) {
    float g = bg[j];
    for (int k2 = 0; k2 < 64; ++k2) g += wg[j * 64 + k2] * mean[k2];
    gpe[j] = 1.f / (1.f + expf(-g));
  }
}

// ---------------------------------------------------------------------------
// K3c: rope multiplier
// ---------------------------------------------------------------------------
__global__ void k_ropemul(const float* __restrict__ pe2, const float* __restrict__ gpe,
                          float* __restrict__ ropem) {
  int idx = blockIdx.x * 256 + threadIdx.x;
  int n = idx >> 6, dd = idx & 63;
  ropem[idx] = 1.f + pe2[(size_t)dd * NN + n] * gpe[n >> 6] * 0.35355339059327373f;
}

// Prep: f32 -> bf16 (weights)
__global__ void k_prep_h(const float* __restrict__ src,
                         ushort* __restrict__ Sh, int nelem) {
  int idx4 = (blockIdx.x * 256 + threadIdx.x) * 4;
  if (idx4 >= nelem) return;
  float4 v = *(const float4*)&src[idx4];
  ushort4 h;
  ((ushort*)&h)[0] = f2b(v.x);
  ((ushort*)&h)[1] = f2b(v.y);
  ((ushort*)&h)[2] = f2b(v.z);
  ((ushort*)&h)[3] = f2b(v.w);
  *(ushort4*)&Sh[idx4] = h;
}

// ---------------------------------------------------------------------------
// Fat-tile MFMA GEMM: 256 x BN tile, BK=32, 8 waves (2m x 4n), 3-buffer LDS
// ring, one barrier + counted vmcnt(4) per K-tile (tile t+2 staged during t).
// XOR-(row&3) bank swizzle both-sides. K = 512 fixed (16 K-tiles).
// BTERMS=2: B = Bh + Bl (2-term, per-batch if BPERB).
// EPI=0: f32 out (+bias). EPI=1: qkv epilogue (gate, elu+1, rope; q/k written
// TRANSPOSED [bh][d][n] bf16; v written [row][c] bf16).
// ---------------------------------------------------------------------------
template <int BN, int BTERMS, int EPI, int BPERB>
__global__ __launch_bounds__(512, 2) void k_gemm8(
    const ushort* __restrict__ Ag, const ushort* __restrict__ Bgh,
    const ushort* __restrict__ Bgl,
    const float* __restrict__ bias, const float* __restrict__ gate,
    const float* __restrict__ ropem,
    float* __restrict__ outF, ushort* __restrict__ qT, ushort* __restrict__ kT,
    ushort* __restrict__ vb, int ntn, int ncols) {
  constexpr int NF = BN / 64;  // n-frags per wave
  const int nwg = gridDim.x;
  const int hw = blockIdx.x;
  const int logical = (hw & 7) * (nwg >> 3) + (hw >> 3);
  const int m0 = (logical / ntn) * 256, n0 = (logical % ntn) * BN;

  const int tid = threadIdx.x, wave = tid >> 6, lane = tid & 63;
  const int wm = wave >> 2, wn = wave & 3;
  const int l15 = lane & 15, kj = lane >> 4;

  __shared__ __attribute__((aligned(16))) ushort sA[3][8192];  // 16 KB/slot
  __shared__ __attribute__((aligned(16))) ushort sB[3][8192];  // 16 KB/slot
  f32x4 acc[8][NF] = {};

  // staging constants: thread handles chunks j*512+tid; row = j*128+(tid>>2)
  const int rS = tid >> 2;
  const int uSw = (tid & 3) ^ (rS & 3);  // inverse-swizzled source unit
  const int sdst = wave * 512;           // + j*4096 (ushort units)

  // read-side: swizzled LDS offsets (ushort units)
  const int rowA = wm * 128 + l15;
  const int offA = rowA * 32 + (kj ^ (rowA & 3)) * 8;   // + m*512
  const int rowB = wn * (BN / 4) + l15;
  const int offB = rowB * 32 + (kj ^ (rowB & 3)) * 8;   // + nf*512 (+4096 Bl)

  const ushort* Bh_ = Bgh + (BPERB ? (size_t)(m0 >> 12) * 262144 : 0);
  const ushort* Bl_ = (BTERMS == 2)
      ? (Bgl + (BPERB ? (size_t)(m0 >> 12) * 262144 : 0)) : nullptr;

#define STAGE(T, S)                                                         \
  {                                                                         \
    const int k0s = (T) * 32;                                               \
    gload16(Ag + (size_t)(m0 + rS) * CC + k0s + uSw * 8, &sA[S][sdst]);     \
    gload16(Ag + (size_t)(m0 + 128 + rS) * CC + k0s + uSw * 8,              \
            &sA[S][4096 + sdst]);                                           \
    if (BTERMS == 1) {                                                      \
      gload16(Bh_ + (size_t)(n0 + rS) * CC + k0s + uSw * 8, &sB[S][sdst]);  \
      gload16(Bh_ + (size_t)(n0 + 128 + rS) * CC + k0s + uSw * 8,           \
              &sB[S][4096 + sdst]);                                         \
    } else {                                                                \
      gload16(Bh_ + (size_t)(n0 + rS) * CC + k0s + uSw * 8, &sB[S][sdst]);  \
      gload16(Bl_ + (size_t)(n0 + rS) * CC + k0s + uSw * 8,                 \
              &sB[S][4096 + sdst]);                                         \
    }                                                                       \
  }

  STAGE(0, 0);
  STAGE(1, 1);
  asm volatile("s_waitcnt vmcnt(4)" ::: "memory");
  __builtin_amdgcn_sched_barrier(0);
  __builtin_amdgcn_s_barrier();

  #pragma unroll
  for (int t = 0; t < 16; ++t) {
    if (t < 14) STAGE(t + 2, (t + 2) % 3);
    const int cur = t % 3;
    bf16x8 af[8];
    #pragma unroll
    for (int m = 0; m < 8; ++m)
      af[m] = *(const bf16x8*)(&sA[cur][offA + m * 512]);
    bf16x8 bh[NF], bl[NF];
    #pragma unroll
    for (int nf = 0; nf < NF; ++nf) {
      bh[nf] = *(const bf16x8*)(&sB[cur][offB + nf * 512]);
      if (BTERMS == 2) bl[nf] = *(const bf16x8*)(&sB[cur][4096 + offB + nf * 512]);
    }
    __builtin_amdgcn_s_setprio(1);
    #pragma unroll
    for (int m = 0; m < 8; ++m)
      #pragma unroll
      for (int nf = 0; nf < NF; ++nf) {
        acc[m][nf] = __builtin_amdgcn_mfma_f32_16x16x32_bf16(af[m], bh[nf], acc[m][nf], 0, 0, 0);
        if (BTERMS == 2)
          acc[m][nf] = __builtin_amdgcn_mfma_f32_16x16x32_bf16(af[m], bl[nf], acc[m][nf], 0, 0, 0);
      }
    __builtin_amdgcn_s_setprio(0);
    if (t < 15) {
      if (t < 14) {
        asm volatile("s_waitcnt vmcnt(4)" ::: "memory");
      } else {
        asm volatile("s_waitcnt vmcnt(0)" ::: "memory");
      }
      __builtin_amdgcn_sched_barrier(0);
      __builtin_amdgcn_s_barrier();
    }
  }
#undef STAGE

  #pragma unroll
  for (int m = 0; m < 8; ++m) {
    #pragma unroll
    for (int nf = 0; nf < NF; ++nf) {
      #pragma unroll
      for (int r = 0; r < 4; ++r) {
        int row = m0 + wm * 128 + m * 16 + kj * 4 + r;
        int col = n0 + wn * (BN / 4) + nf * 16 + l15;
        if (EPI == 0) {
          outF[(size_t)row * ncols + col] = acc[m][nf][r] + bias[col];
        } else {
          int nseq = row & (NN - 1), b = row >> 12;
          float val = acc[m][nf][r] * gate[nseq] + bias[col];
          int part = col >> 9, c = col & 511, h = c >> 6, dd = c & 63;
          if (part == 2) {
            vb[(size_t)row * CC + c] = f2b(val);
          } else {
            size_t oi = ((size_t)(b * HH + h) * DD + dd) * NN + nseq;  // [bh][d][n]
            float e = val > 0.f ? val + 1.f : expf(val);  // elu+1
            float res = e * ropem[nseq * 64 + dd];
            (part == 0 ? qT : kT)[oi] = f2b(res);
          }
        }
      }
    }
  }
}

// ---------------------------------------------------------------------------
// K5a: ctx via MFMA straight from global. qT/kT: [bh][64 d][4096 n] bf16.
// grid 256 = bh*8 + kchunk; 4 waves each cover 128 n; partial per wave.
// ---------------------------------------------------------------------------
__global__ __launch_bounds__(256) void k_ctx_mfma(
    const ushort* __restrict__ qT, const ushort* __restrict__ kT,
    float* __restrict__ ctxp) {
  int blk = blockIdx.x;
  int bh = blk >> 3, chunk = blk & 7;
  int wave = threadIdx.x >> 6, lane = threadIdx.x & 63;
  int l15 = lane & 15, kj = lane >> 4;
  const size_t base = (size_t)bh * DD * NN;
  const int n0 = chunk * 512 + wave * 128;
  f32x4 acc[4][4] = {};
  for (int ks = 0; ks < 4; ++ks) {
    const int nb = n0 + ks * 32 + kj * 8;
    bf16x8 qa[4], ka[4];
    #pragma unroll
    for (int m = 0; m < 4; ++m)
      qa[m] = *(const bf16x8*)(qT + base + (size_t)(m * 16 + l15) * NN + nb);
    #pragma unroll
    for (int n = 0; n < 4; ++n)
      ka[n] = *(const bf16x8*)(kT + base + (size_t)(n * 16 + l15) * NN + nb);
    #pragma unroll
    for (int m = 0; m < 4; ++m)
      #pragma unroll
      for (int n = 0; n < 4; ++n)
        acc[m][n] = __builtin_amdgcn_mfma_f32_16x16x32_bf16(qa[m], ka[n], acc[m][n], 0, 0, 0);
  }
  const float scale = 1.f / 512.f;
  float* dst = ctxp + ((size_t)bh * 32 + chunk * 4 + wave) * 4096;
  #pragma unroll
  for (int m = 0; m < 4; ++m)
    #pragma unroll
    for (int n = 0; n < 4; ++n)
      #pragma unroll
      for (int r = 0; r < 4; ++r)
        dst[(m * 16 + kj * 4 + r) * 64 + n * 16 + l15] = acc[m][n][r] * scale;
}

// K5b: deterministic reduce of 32 partials -> ctx[bh][64][64]
__global__ void k_ctx_red(const float* __restrict__ ctxp, float* __restrict__ ctx) {
  int bh = blockIdx.x;
  int tid = threadIdx.x;
  for (int r = 0; r < 16; ++r) {
    int idx = tid + 256 * r;
    float s = 0.f;
    for (int c2 = 0; c2 < 32; ++c2) s += ctxp[((size_t)bh * 32 + c2) * 4096 + idx];
    ctx[(size_t)bh * 4096 + idx] = s;
  }
}

// ---------------------------------------------------------------------------
// K6: M_b[(h,d)][o] = (1/512) * sum_e ctx[b,h,d,e] * wp[o, h*64+e]
// stored [b][o][h*64+d] bf16 hi/lo.
// ---------------------------------------------------------------------------
__global__ __launch_bounds__(256) void k_mproj(
    const float* __restrict__ ctx, const float* __restrict__ wp,
    ushort* __restrict__ Mh, ushort* __restrict__ Ml) {
  int blk = blockIdx.x;
  int b = blk >> 5, h = (blk >> 2) & 7, oq = blk & 3;
  int tid = threadIdx.x;
  int o = oq * 128 + (tid & 127);
  int d0 = (tid >> 7) * 32;
  __shared__ float cs[64][64];
  #pragma unroll
  for (int it = 0; it < 4; ++it) {
    int idx = (tid + 256 * it) * 4;
    *(float4*)&cs[idx >> 6][idx & 63] =
        *(const float4*)&ctx[(size_t)(b * 8 + h) * 4096 + idx];
  }
  __syncthreads();
  float wv[64];
  #pragma unroll
  for (int e = 0; e < 64; ++e) wv[e] = wp[(size_t)o * 512 + h * 64 + e];
  for (int d = d0; d < d0 + 32; ++d) {
    float s = 0.f;
    #pragma unroll
    for (int e = 0; e < 64; ++e) s += cs[d][e] * wv[e];
    s *= (1.f / 512.f);
    ushort hi = f2b(s);
    size_t idx = ((size_t)b * 512 + o) * 512 + h * 64 + d;
    Mh[idx] = hi;
    Ml[idx] = f2b(s - b2f(hi));
  }
}

// ---------------------------------------------------------------------------
extern "C" void kernel_launch(void* const* d_in, const int* in_sizes, int n_in,
                              void* d_out, int out_size, void* d_ws, size_t ws_size,
                              hipStream_t stream) {
  const float* x    = (const float*)d_in[0];
  const float* lpw  = (const float*)d_in[1];
  const float* lvw  = (const float*)d_in[2];
  const float* wqkv = (const float*)d_in[3];
  const float* bqkv = (const float*)d_in[4];
  const float* wproj= (const float*)d_in[5];
  const float* bproj= (const float*)d_in[6];
  const float* omega= (const float*)d_in[7];
  const float* w1   = (const float*)d_in[8];
  const float* b1   = (const float*)d_in[9];
  const float* w2   = (const float*)d_in[10];
  const float* b2   = (const float*)d_in[11];
  const float* wg   = (const float*)d_in[12];
  const float* bg   = (const float*)d_in[13];
  float* out = (float*)d_out;

  constexpr size_t MB = 1024 * 1024;
  char* w = (char*)d_ws;
  int*   peak   = (int*)(w);
  int*   valley = (int*)(w + 16 * 1024);
  float* attn   = (float*)(w + 32 * 1024);
  float* gate   = (float*)(w + 48 * 1024);
  float* pe2    = (float*)(w + 64 * 1024);        // 1 MiB
  float* gpe    = (float*)(w + 1088 * 1024);
  float* ropem  = (float*)(w + 1152 * 1024);      // 1 MiB
  float* etabP  = (float*)(w + 2176 * 1024);      // 16 KiB
  float* etabV  = (float*)(w + 2192 * 1024);      // 16 KiB
  ushort* Xh    = (ushort*)(w + 4 * MB);          // 16 MiB bf16 [B*N, C]
  ushort* qT    = (ushort*)(w + 20 * MB);         // 16 MiB bf16 [B,H,D,N]
  ushort* kT    = (ushort*)(w + 36 * MB);         // 16 MiB
  ushort* vb    = (ushort*)(w + 52 * MB);         // 16 MiB bf16 [B*N, C]
  ushort* Wh    = (ushort*)(w + 68 * MB);         // 1.5 MiB
  ushort* Mh    = (ushort*)(w + 70 * MB);         // 2 MiB [B][512][512]
  ushort* Ml    = (ushort*)(w + 72 * MB);         // 2 MiB
  float* ctxp   = (float*)(w + 75 * MB);          // 16 MiB
  float* ctx    = (float*)(w + 91 * MB);          // 0.5 MiB

  hipMemsetAsync(peak, 0, 2 * 4096 * sizeof(int), stream);

  k_counts_prep<<<BB * 64, 512, 0, stream>>>(x, peak, valley, Xh);
  k_etab<<<16, 256, 0, stream>>>(lpw, lvw, etabP, etabV);
  k_gsum<<<NN, 256, 0, stream>>>(peak, valley, etabP, etabV, attn);
  k_norm<<<1, 1024, 0, stream>>>(attn, gate);
  k_pe<<<NN, 64, 0, stream>>>(omega, w1, b1, w2, b2, pe2);
  k_gatepe<<<1, 256, 0, stream>>>(pe2, wg, bg, gpe);
  k_ropemul<<<1024, 256, 0, stream>>>(pe2, gpe, ropem);
  k_prep_h<<<768, 256, 0, stream>>>(wqkv, Wh, 3 * CC * CC);

  // qkv: M=16384, N=1536 -> 64 x 6 = 384 blocks (XCD-swizzled)
  k_gemm8<256, 1, 1, 0><<<384, 512, 0, stream>>>(Xh, Wh, nullptr, bqkv, gate,
                                                 ropem, nullptr, qT, kT, vb, 6, 0);
  k_ctx_mfma<<<256, 256, 0, stream>>>(qT, kT, ctxp);
  k_ctx_red<<<32, 256, 0, stream>>>(ctxp, ctx);
  k_mproj<<<128, 256, 0, stream>>>(ctx, wproj, Mh, Ml);

  // fused out+proj: out = V[16384x512] * M_b^T + bias; 64 x 4 = 256 blocks
  k_gemm8<128, 2, 0, 1><<<256, 512, 0, stream>>>(vb, Mh, Ml, bproj, nullptr,
                                                 nullptr, out, nullptr, nullptr,
                                                 nullptr, 4, CC);
}

// Round 7
// 323.097 us; speedup vs baseline: 1.0593x; 1.0593x over previous
//
#include <hip/hip_runtime.h>
#include <hip/hip_bf16.h>
#include <math.h>

constexpr int BB = 4;
constexpr int NN = 4096;
constexpr int CC = 512;
constexpr int HH = 8;
constexpr int DD = 64;
constexpr int NCNT = NN - 2;

typedef __bf16 bf16x8 __attribute__((ext_vector_type(8)));
typedef float f32x4 __attribute__((ext_vector_type(4)));

__device__ __forceinline__ float b2f(ushort u) {
  unsigned v = ((unsigned)u) << 16;
  return __builtin_bit_cast(float, v);
}
__device__ __forceinline__ ushort f2b(float f) {
  __hip_bfloat16 h = __float2bfloat16(f);
  return __builtin_bit_cast(ushort, h);
}
__device__ __forceinline__ void gload16(const ushort* g, ushort* l) {
  __builtin_amdgcn_global_load_lds(
      (const __attribute__((address_space(1))) unsigned int*)g,
      (__attribute__((address_space(3))) unsigned int*)l, 16, 0, 0);
}

// ---------------------------------------------------------------------------
// K1: second-diff sign counts (sliding window) + fused x -> bf16
// ---------------------------------------------------------------------------
__global__ void k_counts_prep(const float* __restrict__ x,
                              int* __restrict__ peak, int* __restrict__ valley,
                              ushort* __restrict__ Xh) {
  int b = blockIdx.x >> 6;
  int tile = blockIdx.x & 63;
  int c = threadIdx.x;
  int lane = threadIdx.x & 63;
  int i0 = tile * 64;
  const float* xb = x + (size_t)b * NN * CC + c;
  float x0 = xb[(size_t)i0 * CC];
  float x1 = xb[(size_t)(i0 + 1 < NN ? i0 + 1 : i0) * CC];
  for (int ii = 0; ii < 64; ++ii) {
    int i = i0 + ii;
    Xh[((size_t)b * NN + i) * CC + c] = f2b(x0);
    if (i < NCNT) {
      float x2 = xb[(size_t)(i + 2) * CC];
      float d2 = (x2 - x1) - (x1 - x0);
      unsigned long long mneg = __ballot(d2 < 0.0f);
      unsigned long long mpos = __ballot(d2 > 0.0f);
      if (lane == 0) {
        atomicAdd(&peak[i], __popcll(mneg));
        atomicAdd(&valley[i], __popcll(mpos));
      }
      x0 = x1; x1 = x2;
    } else {
      x0 = x1;
    }
  }
}

// ---------------------------------------------------------------------------
// K2pre: Gaussian tables etab[a] = exp(-(a*iw)^2)
// ---------------------------------------------------------------------------
__global__ void k_etab(const float* __restrict__ lpw, const float* __restrict__ lvw,
                       float* __restrict__ etabP, float* __restrict__ etabV) {
  int i = blockIdx.x * 256 + threadIdx.x;
  float ipw = expf(-lpw[0]);
  float ivw = expf(-lvw[0]);
  float t1 = (float)i * ipw;
  float t2 = (float)i * ivw;
  etabP[i] = expf(-t1 * t1);
  etabV[i] = expf(-t2 * t2);
}

// ---------------------------------------------------------------------------
// K2a: Gaussian sums via tables
// ---------------------------------------------------------------------------
__global__ void k_gsum(const int* __restrict__ peak, const int* __restrict__ valley,
                       const float* __restrict__ etabP, const float* __restrict__ etabV,
                       float* __restrict__ attn) {
  int p = blockIdx.x;
  int tid = threadIdx.x;
  float acc = 0.f;
  for (int i = tid; i < NCNT; i += 256) {
    int a = p - 1 - i;
    a = a < 0 ? -a : a;
    acc += (float)peak[i] * etabP[a] + (float)valley[i] * etabV[a];
  }
  __shared__ float red[256];
  red[tid] = acc;
  __syncthreads();
  for (int s = 128; s > 0; s >>= 1) {
    if (tid < s) red[tid] += red[tid + s];
    __syncthreads();
  }
  if (tid == 0) attn[p] = red[0];
}

// ---------------------------------------------------------------------------
// K2b: min-max normalize
// ---------------------------------------------------------------------------
__global__ void k_norm(const float* __restrict__ attn, float* __restrict__ gate) {
  int tid = threadIdx.x;  // 1024
  float v0 = attn[tid], v1 = attn[tid + 1024], v2 = attn[tid + 2048], v3 = attn[tid + 3072];
  float mn = fminf(fminf(v0, v1), fminf(v2, v3));
  float mx = fmaxf(fmaxf(v0, v1), fmaxf(v2, v3));
  __shared__ float rmn[1024], rmx[1024];
  rmn[tid] = mn; rmx[tid] = mx;
  __syncthreads();
  for (int s = 512; s > 0; s >>= 1) {
    if (tid < s) {
      rmn[tid] = fminf(rmn[tid], rmn[tid + s]);
      rmx[tid] = fmaxf(rmx[tid], rmx[tid + s]);
    }
    __syncthreads();
  }
  float lo = rmn[0];
  float denom = rmx[0] - rmn[0] + 1e-6f;
  gate[tid]        = (v0 - lo) / denom;
  gate[tid + 1024] = (v1 - lo) / denom;
  gate[tid + 2048] = (v2 - lo) / denom;
  gate[tid + 3072] = (v3 - lo) / denom;
}

// ---------------------------------------------------------------------------
// K3a: spectral PE conv path -> pe2 [64][4096]
// ---------------------------------------------------------------------------
__global__ void k_pe(const float* __restrict__ omega,
                     const float* __restrict__ w1, const float* __restrict__ b1,
                     const float* __restrict__ w2, const float* __restrict__ b2,
                     float* __restrict__ pe2) {
  int n = blockIdx.x;
  int j = threadIdx.x;  // 64
  __shared__ float pec[3][64];
  __shared__ float hs[128];
  for (int t = 0; t < 3; ++t) {
    int m = n + t - 1;
    float v = 0.f;
    if (m >= 0 && m < NN) {
      int l1 = m >> 6, l2 = m & 63;
      float rel = (float)(l1 - l2);
      v = (j < 32) ? sinf(rel * omega[j]) : cosf(rel * omega[j - 32]);
    }
    pec[t][j] = v;
  }
  __syncthreads();
  for (int o = j; o < 128; o += 64) {
    int ci = o >> 1;
    float hv = b1[o];
    #pragma unroll
    for (int t = 0; t < 3; ++t) hv += pec[t][ci] * w1[o * 3 + t];
    hv = 0.5f * hv * (1.f + erff(hv * 0.70710678118654752f));
    hs[o] = hv;
  }
  __syncthreads();
  float acc = b2[j];
  for (int o = 0; o < 128; ++o) acc += hs[o] * w2[j * 128 + o];
  pe2[(size_t)j * NN + n] = acc;
}

// ---------------------------------------------------------------------------
// K3b: channel means -> sigmoid gate gpe[64]
// ---------------------------------------------------------------------------
__global__ void k_gatepe(const float* __restrict__ pe2,
                         const float* __restrict__ wg, const float* __restrict__ bg,
                         float* __restrict__ gpe) {
  int tid = threadIdx.x;  // 256
  int j = tid & 63, part = tid >> 6;
  float s = 0.f;
  const float* row = pe2 + (size_t)j * NN + part * 1024;
  for (int t = 0; t < 1024; ++t) s += row[t];
  __shared__ float ps[4][64];
  __shared__ float mean[64];
  ps[part][j] = s;
  __syncthreads();
  if (tid < 64) mean[j] = (ps[0][j] + ps[1][j] + ps[2][j] + ps[3][j]) * (1.f / 4096.f);
  __syncthreads();
  if (tid < 64) {
    float g = bg[j];
    for (int k2 = 0; k2 < 64; ++k2) g += wg[j * 64 + k2] * mean[k2];
    gpe[j] = 1.f / (1.f + expf(-g));
  }
}

// ---------------------------------------------------------------------------
// K3c: rope multiplier
// ---------------------------------------------------------------------------
__global__ void k_ropemul(const float* __restrict__ pe2, const float* __restrict__ gpe,
                          float* __restrict__ ropem) {
  int idx = blockIdx.x * 256 + threadIdx.x;
  int n = idx >> 6, dd = idx & 63;
  ropem[idx] = 1.f + pe2[(size_t)dd * NN + n] * gpe[n >> 6] * 0.35355339059327373f;
}

// Prep: f32 -> bf16 (weights)
__global__ void k_prep_h(const float* __restrict__ src,
                         ushort* __restrict__ Sh, int nelem) {
  int idx4 = (blockIdx.x * 256 + threadIdx.x) * 4;
  if (idx4 >= nelem) return;
  float4 v = *(const float4*)&src[idx4];
  ushort4 h;
  ((ushort*)&h)[0] = f2b(v.x);
  ((ushort*)&h)[1] = f2b(v.y);
  ((ushort*)&h)[2] = f2b(v.z);
  ((ushort*)&h)[3] = f2b(v.w);
  *(ushort4*)&Sh[idx4] = h;
}

// ---------------------------------------------------------------------------
// Plain double-buffered bf16 MFMA GEMM (m97-style, NO inline asm).
// 128x128 tile, BK=32, 4 waves (2x2), 2 LDS buffers, one __syncthreads/step.
// Per step: STAGE(t+1) -> ds_read frags(t) -> MFMA -> barrier.
// Zero-conflict swizzle (round-5 verified). XCD grid swizzle.
// EPI=1: qk epilogue (gate, elu+1, rope; q/k stored TRANSPOSED [bh][d][n]).
// EPI=2: out epilogue (gate*acc + beff[b][col], f32 out, per-batch B).
// ---------------------------------------------------------------------------
template <int BTERMS, int EPI>
__global__ __launch_bounds__(256) void k_gemm_t(
    const ushort* __restrict__ Ag, const ushort* __restrict__ Bgh,
    const ushort* __restrict__ Bgl,
    const float* __restrict__ bias, const float* __restrict__ gate,
    const float* __restrict__ ropem,
    float* __restrict__ outF, ushort* __restrict__ qT, ushort* __restrict__ kT,
    int ntn, int ncols) {
  const int nwg = gridDim.x;
  const int hw = blockIdx.x;
  const int logical = (hw & 7) * (nwg >> 3) + (hw >> 3);
  const int m0 = (logical / ntn) * 128, n0 = (logical % ntn) * 128;

  const int tid = threadIdx.x, wave = tid >> 6, lane = tid & 63;
  const int wm = wave >> 1, wn = wave & 1;
  __shared__ ushort sA[2][4096];
  __shared__ ushort sB[2][BTERMS * 4096];
  f32x4 acc[4][4] = {};

  const int lr = lane >> 2;
  const int ci = lane & 3;
  const int scol = (ci ^ ((lr >> 1) & 3)) * 8;           // inverse-swz source col
  const int rA = lane & 15;
  const int cswz = ((lane >> 4) ^ ((rA >> 1) & 3)) * 8;  // read-side swizzle

  const int chunk0 = wave * 2, chunk1 = wave * 2 + 1;
  const int row0 = chunk0 * 16 + lr, row1 = chunk1 * 16 + lr;

  const ushort* Bh_ = Bgh + (EPI == 2 ? (size_t)(m0 >> 12) * 262144 : 0);
  const ushort* Bl_ = (BTERMS == 2)
      ? (Bgl + (EPI == 2 ? (size_t)(m0 >> 12) * 262144 : 0)) : nullptr;

#define STAGE(T, S)                                                        \
  {                                                                        \
    const int k0s = (T) * 32;                                              \
    size_t ga0 = (size_t)(m0 + row0) * CC + k0s + scol;                    \
    size_t ga1 = (size_t)(m0 + row1) * CC + k0s + scol;                    \
    size_t gb0 = (size_t)(n0 + row0) * CC + k0s + scol;                    \
    size_t gb1 = (size_t)(n0 + row1) * CC + k0s + scol;                    \
    gload16(Ag + ga0, &sA[S][chunk0 * 512]);                               \
    gload16(Ag + ga1, &sA[S][chunk1 * 512]);                               \
    gload16(Bh_ + gb0, &sB[S][chunk0 * 512]);                              \
    gload16(Bh_ + gb1, &sB[S][chunk1 * 512]);                              \
    if (BTERMS == 2) {                                                     \
      gload16(Bl_ + gb0, &sB[S][4096 + chunk0 * 512]);                     \
      gload16(Bl_ + gb1, &sB[S][4096 + chunk1 * 512]);                     \
    }                                                                      \
  }

  STAGE(0, 0);
  __syncthreads();  // tile 0 landed (vmcnt drained by barrier)

  for (int t = 0; t < 16; ++t) {
    if (t < 15) STAGE(t + 1, (t + 1) & 1);  // issue early; lands by barrier
    const int cur = t & 1;
    bf16x8 af[4], bh[4], bl[4];
    #pragma unroll
    for (int m = 0; m < 4; ++m)
      af[m] = *(const bf16x8*)(&sA[cur][(wm * 64 + m * 16 + rA) * 32 + cswz]);
    #pragma unroll
    for (int n = 0; n < 4; ++n) {
      int off = (wn * 64 + n * 16 + rA) * 32 + cswz;
      bh[n] = *(const bf16x8*)(&sB[cur][off]);
      if (BTERMS == 2) bl[n] = *(const bf16x8*)(&sB[cur][4096 + off]);
    }
    #pragma unroll
    for (int m = 0; m < 4; ++m)
      #pragma unroll
      for (int n = 0; n < 4; ++n) {
        acc[m][n] = __builtin_amdgcn_mfma_f32_16x16x32_bf16(af[m], bh[n], acc[m][n], 0, 0, 0);
        if (BTERMS == 2)
          acc[m][n] = __builtin_amdgcn_mfma_f32_16x16x32_bf16(af[m], bl[n], acc[m][n], 0, 0, 0);
      }
    __syncthreads();  // next tile landed; this tile's reads done
  }
#undef STAGE

  #pragma unroll
  for (int m = 0; m < 4; ++m) {
    #pragma unroll
    for (int n = 0; n < 4; ++n) {
      #pragma unroll
      for (int r = 0; r < 4; ++r) {
        int row = m0 + wm * 64 + m * 16 + (lane >> 4) * 4 + r;
        int col = n0 + wn * 64 + n * 16 + (lane & 15);
        int nseq = row & (NN - 1), b = row >> 12;
        if (EPI == 2) {
          float val = acc[m][n][r] * gate[nseq] + bias[b * 512 + col];
          outF[(size_t)row * ncols + col] = val;
        } else {
          float val = acc[m][n][r] * gate[nseq] + bias[col];
          int part = col >> 9, h = (col >> 6) & 7, dd = col & 63;
          float e = val > 0.f ? val + 1.f : expf(val);  // elu+1
          float res = e * ropem[nseq * 64 + dd];
          size_t oi = ((size_t)(b * HH + h) * DD + dd) * NN + nseq;  // [bh][d][n]
          (part == 0 ? qT : kT)[oi] = f2b(res);
        }
      }
    }
  }
}

// ---------------------------------------------------------------------------
// K5a: ctx via MFMA straight from global. qT/kT: [bh][64 d][4096 n] bf16.
// ---------------------------------------------------------------------------
__global__ __launch_bounds__(256) void k_ctx_mfma(
    const ushort* __restrict__ qT, const ushort* __restrict__ kT,
    float* __restrict__ ctxp) {
  int blk = blockIdx.x;
  int bh = blk >> 3, chunk = blk & 7;
  int wave = threadIdx.x >> 6, lane = threadIdx.x & 63;
  int l15 = lane & 15, kj = lane >> 4;
  const size_t base = (size_t)bh * DD * NN;
  const int n0 = chunk * 512 + wave * 128;
  f32x4 acc[4][4] = {};
  for (int ks = 0; ks < 4; ++ks) {
    const int nb = n0 + ks * 32 + kj * 8;
    bf16x8 qa[4], ka[4];
    #pragma unroll
    for (int m = 0; m < 4; ++m)
      qa[m] = *(const bf16x8*)(qT + base + (size_t)(m * 16 + l15) * NN + nb);
    #pragma unroll
    for (int n = 0; n < 4; ++n)
      ka[n] = *(const bf16x8*)(kT + base + (size_t)(n * 16 + l15) * NN + nb);
    #pragma unroll
    for (int m = 0; m < 4; ++m)
      #pragma unroll
      for (int n = 0; n < 4; ++n)
        acc[m][n] = __builtin_amdgcn_mfma_f32_16x16x32_bf16(qa[m], ka[n], acc[m][n], 0, 0, 0);
  }
  const float scale = 1.f / 512.f;
  float* dst = ctxp + ((size_t)bh * 32 + chunk * 4 + wave) * 4096;
  #pragma unroll
  for (int m = 0; m < 4; ++m)
    #pragma unroll
    for (int n = 0; n < 4; ++n)
      #pragma unroll
      for (int r = 0; r < 4; ++r)
        dst[(m * 16 + kj * 4 + r) * 64 + n * 16 + l15] = acc[m][n][r] * scale;
}

// K5b: deterministic reduce of 32 partials -> ctx[bh][64][64]
__global__ void k_ctx_red(const float* __restrict__ ctxp, float* __restrict__ ctx) {
  int bh = blockIdx.x;
  int tid = threadIdx.x;
  for (int r = 0; r < 16; ++r) {
    int idx = tid + 256 * r;
    float s = 0.f;
    for (int c2 = 0; c2 < 32; ++c2) s += ctxp[((size_t)bh * 32 + c2) * 4096 + idx];
    ctx[(size_t)bh * 4096 + idx] = s;
  }
}

// ---------------------------------------------------------------------------
// K6: Mf[b][o][h*64+d] = (1/512) * sum_e ctx[b,h,d,e] * wp[o, h*64+e]  (f32)
// ---------------------------------------------------------------------------
__global__ __launch_bounds__(256) void k_mproj(
    const float* __restrict__ ctx, const float* __restrict__ wp,
    float* __restrict__ Mf) {
  int blk = blockIdx.x;
  int b = blk >> 5, h = (blk >> 2) & 7, oq = blk & 3;
  int tid = threadIdx.x;
  int o = oq * 128 + (tid & 127);
  int d0 = (tid >> 7) * 32;
  __shared__ float cs[64][64];
  #pragma unroll
  for (int it = 0; it < 4; ++it) {
    int idx = (tid + 256 * it) * 4;
    *(float4*)&cs[idx >> 6][idx & 63] =
        *(const float4*)&ctx[(size_t)(b * 8 + h) * 4096 + idx];
  }
  __syncthreads();
  float wv[64];
  #pragma unroll
  for (int e = 0; e < 64; ++e) wv[e] = wp[(size_t)o * 512 + h * 64 + e];
  for (int d = d0; d < d0 + 32; ++d) {
    float s = 0.f;
    #pragma unroll
    for (int e = 0; e < 64; ++e) s += cs[d][e] * wv[e];
    Mf[((size_t)b * 512 + o) * 512 + h * 64 + d] = s * (1.f / 512.f);
  }
}

// ---------------------------------------------------------------------------
// K7: G2[b][o][c] = sum_{c'} Mf[b][o][c'] * Wv[c'][c]   (Wv = wqkv rows 1024+)
// f32 compute, bf16 hi/lo output. grid 256 = (b, ot, ct); 64x64 tiles.
// ---------------------------------------------------------------------------
__global__ __launch_bounds__(256) void k_g2(
    const float* __restrict__ Mf, const float* __restrict__ wqkv,
    ushort* __restrict__ G2h, ushort* __restrict__ G2l) {
  int blk = blockIdx.x;
  int b = blk >> 6, ot = (blk >> 3) & 7, ct = blk & 7;
  int tx = threadIdx.x & 15, ty = threadIdx.x >> 4;
  __shared__ float As[32][65], Ws[32][65];
  float acc[4][4] = {};
  const float* Mb = Mf + (size_t)b * 262144;
  for (int k0 = 0; k0 < 512; k0 += 32) {
    #pragma unroll
    for (int it = 0; it < 8; ++it) {
      int e = threadIdx.x + 256 * it;  // 2048
      int m = e >> 5, kk = e & 31;
      As[kk][m] = Mb[(size_t)(ot * 64 + m) * 512 + k0 + kk];
      int kk2 = e >> 6, cc = e & 63;
      Ws[kk2][cc] = wqkv[(size_t)(1024 + k0 + kk2) * 512 + ct * 64 + cc];
    }
    __syncthreads();
    #pragma unroll
    for (int kk = 0; kk < 32; ++kk) {
      float a[4], wv[4];
      #pragma unroll
      for (int i = 0; i < 4; ++i) a[i] = As[kk][ty + 16 * i];
      #pragma unroll
      for (int j = 0; j < 4; ++j) wv[j] = Ws[kk][tx + 16 * j];
      #pragma unroll
      for (int i = 0; i < 4; ++i)
        #pragma unroll
        for (int j = 0; j < 4; ++j) acc[i][j] += a[i] * wv[j];
    }
    __syncthreads();
  }
  #pragma unroll
  for (int i = 0; i < 4; ++i)
    #pragma unroll
    for (int j = 0; j < 4; ++j) {
      size_t idx = ((size_t)b * 512 + ot * 64 + ty + 16 * i) * 512 + ct * 64 + tx + 16 * j;
      float s = acc[i][j];
      ushort hi = f2b(s);
      G2h[idx] = hi;
      G2l[idx] = f2b(s - b2f(hi));
    }
}

// K8: beff[b][o] = sum_{c'} bqkv[1024+c'] * Mf[b][o][c'] + bproj[o]
__global__ void k_beff(const float* __restrict__ Mf, const float* __restrict__ bqkv,
                       const float* __restrict__ bproj, float* __restrict__ beff) {
  int t = blockIdx.x * 256 + threadIdx.x;  // 2048
  int b = t >> 9, o = t & 511;
  const float* row = Mf + ((size_t)b * 512 + o) * 512;
  float s = bproj[o];
  for (int c = 0; c < 512; ++c) s += bqkv[1024 + c] * row[c];
  beff[t] = s;
}

// ---------------------------------------------------------------------------
extern "C" void kernel_launch(void* const* d_in, const int* in_sizes, int n_in,
                              void* d_out, int out_size, void* d_ws, size_t ws_size,
                              hipStream_t stream) {
  const float* x    = (const float*)d_in[0];
  const float* lpw  = (const float*)d_in[1];
  const float* lvw  = (const float*)d_in[2];
  const float* wqkv = (const float*)d_in[3];
  const float* bqkv = (const float*)d_in[4];
  const float* wproj= (const float*)d_in[5];
  const float* bproj= (const float*)d_in[6];
  const float* omega= (const float*)d_in[7];
  const float* w1   = (const float*)d_in[8];
  const float* b1   = (const float*)d_in[9];
  const float* w2   = (const float*)d_in[10];
  const float* b2   = (const float*)d_in[11];
  const float* wg   = (const float*)d_in[12];
  const float* bg   = (const float*)d_in[13];
  float* out = (float*)d_out;

  constexpr size_t MB = 1024 * 1024;
  char* w = (char*)d_ws;
  int*   peak   = (int*)(w);
  int*   valley = (int*)(w + 16 * 1024);
  float* attn   = (float*)(w + 32 * 1024);
  float* gate   = (float*)(w + 48 * 1024);
  float* pe2    = (float*)(w + 64 * 1024);        // 1 MiB
  float* gpe    = (float*)(w + 1088 * 1024);
  float* ropem  = (float*)(w + 1152 * 1024);      // 1 MiB
  float* etabP  = (float*)(w + 2176 * 1024);
  float* etabV  = (float*)(w + 2192 * 1024);
  ushort* Xh    = (ushort*)(w + 4 * MB);          // 16 MiB bf16 [B*N, C]
  ushort* qT    = (ushort*)(w + 20 * MB);         // 16 MiB bf16 [B,H,D,N]
  ushort* kT    = (ushort*)(w + 36 * MB);         // 16 MiB
  ushort* Whqk  = (ushort*)(w + 52 * MB);         // 1 MiB (q,k weights bf16)
  float* Mf     = (float*)(w + 53 * MB);          // 4 MiB f32 [B][512][512]
  ushort* G2h   = (ushort*)(w + 57 * MB);         // 2 MiB
  ushort* G2l   = (ushort*)(w + 59 * MB);         // 2 MiB
  float* beff   = (float*)(w + 61 * MB);          // 8 KiB
  float* ctxp   = (float*)(w + 62 * MB);          // 16 MiB
  float* ctx    = (float*)(w + 78 * MB);          // 0.5 MiB -> 78.5 MiB total

  hipMemsetAsync(peak, 0, 2 * 4096 * sizeof(int), stream);

  k_counts_prep<<<BB * 64, 512, 0, stream>>>(x, peak, valley, Xh);
  k_etab<<<16, 256, 0, stream>>>(lpw, lvw, etabP, etabV);
  k_gsum<<<NN, 256, 0, stream>>>(peak, valley, etabP, etabV, attn);
  k_norm<<<1, 1024, 0, stream>>>(attn, gate);
  k_pe<<<NN, 64, 0, stream>>>(omega, w1, b1, w2, b2, pe2);
  k_gatepe<<<1, 256, 0, stream>>>(pe2, wg, bg, gpe);
  k_ropemul<<<1024, 256, 0, stream>>>(pe2, gpe, ropem);
  k_prep_h<<<512, 256, 0, stream>>>(wqkv, Whqk, 1024 * CC);

  // q,k GEMM: M=16384, N=1024 -> 128 x 8 = 1024 blocks (4/CU)
  k_gemm_t<1, 1><<<1024, 256, 0, stream>>>(Xh, Whqk, nullptr, bqkv, gate, ropem,
                                           nullptr, qT, kT, 8, 0);
  k_ctx_mfma<<<256, 256, 0, stream>>>(qT, kT, ctxp);
  k_ctx_red<<<32, 256, 0, stream>>>(ctxp, ctx);
  k_mproj<<<128, 256, 0, stream>>>(ctx, wproj, Mf);
  k_g2<<<256, 256, 0, stream>>>(Mf, wqkv, G2h, G2l);
  k_beff<<<8, 256, 0, stream>>>(Mf, bqkv, bproj, beff);

  // out GEMM: out = gate*(Xh * G2_b^T) + beff; M=16384, N=512 -> 512 blocks (2/CU)
  k_gemm_t<2, 2><<<512, 256, 0, stream>>>(Xh, G2h, G2l, beff, gate, nullptr,
                                          out, nullptr, nullptr, 4, CC);
}

// Round 8
// 252.927 us; speedup vs baseline: 1.3532x; 1.2774x over previous
//
#include <hip/hip_runtime.h>
#include <hip/hip_bf16.h>
#include <math.h>

constexpr int BB = 4;
constexpr int NN = 4096;
constexpr int CC = 512;
constexpr int HH = 8;
constexpr int DD = 64;
constexpr int NCNT = NN - 2;

typedef __bf16 bf16x8 __attribute__((ext_vector_type(8)));
typedef float f32x4 __attribute__((ext_vector_type(4)));

__device__ __forceinline__ float b2f(ushort u) {
  unsigned v = ((unsigned)u) << 16;
  return __builtin_bit_cast(float, v);
}
__device__ __forceinline__ ushort f2b(float f) {
  __hip_bfloat16 h = __float2bfloat16(f);
  return __builtin_bit_cast(ushort, h);
}
__device__ __forceinline__ void gload16(const ushort* g, ushort* l) {
  __builtin_amdgcn_global_load_lds(
      (const __attribute__((address_space(1))) unsigned int*)g,
      (__attribute__((address_space(3))) unsigned int*)l, 16, 0, 0);
}

// ---------------------------------------------------------------------------
// K1: second-diff sign counts (sliding window) + fused x -> bf16
// ---------------------------------------------------------------------------
__global__ void k_counts_prep(const float* __restrict__ x,
                              int* __restrict__ peak, int* __restrict__ valley,
                              ushort* __restrict__ Xh) {
  int b = blockIdx.x >> 6;
  int tile = blockIdx.x & 63;
  int c = threadIdx.x;
  int lane = threadIdx.x & 63;
  int i0 = tile * 64;
  const float* xb = x + (size_t)b * NN * CC + c;
  float x0 = xb[(size_t)i0 * CC];
  float x1 = xb[(size_t)(i0 + 1 < NN ? i0 + 1 : i0) * CC];
  for (int ii = 0; ii < 64; ++ii) {
    int i = i0 + ii;
    Xh[((size_t)b * NN + i) * CC + c] = f2b(x0);
    if (i < NCNT) {
      float x2 = xb[(size_t)(i + 2) * CC];
      float d2 = (x2 - x1) - (x1 - x0);
      unsigned long long mneg = __ballot(d2 < 0.0f);
      unsigned long long mpos = __ballot(d2 > 0.0f);
      if (lane == 0) {
        atomicAdd(&peak[i], __popcll(mneg));
        atomicAdd(&valley[i], __popcll(mpos));
      }
      x0 = x1; x1 = x2;
    } else {
      x0 = x1;
    }
  }
}

// ---------------------------------------------------------------------------
// K2pre: Gaussian tables etab[a] = exp(-(a*iw)^2)
// ---------------------------------------------------------------------------
__global__ void k_etab(const float* __restrict__ lpw, const float* __restrict__ lvw,
                       float* __restrict__ etabP, float* __restrict__ etabV) {
  int i = blockIdx.x * 256 + threadIdx.x;
  float ipw = expf(-lpw[0]);
  float ivw = expf(-lvw[0]);
  float t1 = (float)i * ipw;
  float t2 = (float)i * ivw;
  etabP[i] = expf(-t1 * t1);
  etabV[i] = expf(-t2 * t2);
}

// ---------------------------------------------------------------------------
// K2a: Gaussian sums via tables
// ---------------------------------------------------------------------------
__global__ void k_gsum(const int* __restrict__ peak, const int* __restrict__ valley,
                       const float* __restrict__ etabP, const float* __restrict__ etabV,
                       float* __restrict__ attn) {
  int p = blockIdx.x;
  int tid = threadIdx.x;
  float acc = 0.f;
  for (int i = tid; i < NCNT; i += 256) {
    int a = p - 1 - i;
    a = a < 0 ? -a : a;
    acc += (float)peak[i] * etabP[a] + (float)valley[i] * etabV[a];
  }
  __shared__ float red[256];
  red[tid] = acc;
  __syncthreads();
  for (int s = 128; s > 0; s >>= 1) {
    if (tid < s) red[tid] += red[tid + s];
    __syncthreads();
  }
  if (tid == 0) attn[p] = red[0];
}

// ---------------------------------------------------------------------------
// K2b: min-max normalize
// ---------------------------------------------------------------------------
__global__ void k_norm(const float* __restrict__ attn, float* __restrict__ gate) {
  int tid = threadIdx.x;  // 1024
  float v0 = attn[tid], v1 = attn[tid + 1024], v2 = attn[tid + 2048], v3 = attn[tid + 3072];
  float mn = fminf(fminf(v0, v1), fminf(v2, v3));
  float mx = fmaxf(fmaxf(v0, v1), fmaxf(v2, v3));
  __shared__ float rmn[1024], rmx[1024];
  rmn[tid] = mn; rmx[tid] = mx;
  __syncthreads();
  for (int s = 512; s > 0; s >>= 1) {
    if (tid < s) {
      rmn[tid] = fminf(rmn[tid], rmn[tid + s]);
      rmx[tid] = fmaxf(rmx[tid], rmx[tid + s]);
    }
    __syncthreads();
  }
  float lo = rmn[0];
  float denom = rmx[0] - rmn[0] + 1e-6f;
  gate[tid]        = (v0 - lo) / denom;
  gate[tid + 1024] = (v1 - lo) / denom;
  gate[tid + 2048] = (v2 - lo) / denom;
  gate[tid + 3072] = (v3 - lo) / denom;
}

// ---------------------------------------------------------------------------
// K3a: spectral PE conv path -> pe2 [64][4096]
// ---------------------------------------------------------------------------
__global__ void k_pe(const float* __restrict__ omega,
                     const float* __restrict__ w1, const float* __restrict__ b1,
                     const float* __restrict__ w2, const float* __restrict__ b2,
                     float* __restrict__ pe2) {
  int n = blockIdx.x;
  int j = threadIdx.x;  // 64
  __shared__ float pec[3][64];
  __shared__ float hs[128];
  for (int t = 0; t < 3; ++t) {
    int m = n + t - 1;
    float v = 0.f;
    if (m >= 0 && m < NN) {
      int l1 = m >> 6, l2 = m & 63;
      float rel = (float)(l1 - l2);
      v = (j < 32) ? sinf(rel * omega[j]) : cosf(rel * omega[j - 32]);
    }
    pec[t][j] = v;
  }
  __syncthreads();
  for (int o = j; o < 128; o += 64) {
    int ci = o >> 1;
    float hv = b1[o];
    #pragma unroll
    for (int t = 0; t < 3; ++t) hv += pec[t][ci] * w1[o * 3 + t];
    hv = 0.5f * hv * (1.f + erff(hv * 0.70710678118654752f));
    hs[o] = hv;
  }
  __syncthreads();
  float acc = b2[j];
  for (int o = 0; o < 128; ++o) acc += hs[o] * w2[j * 128 + o];
  pe2[(size_t)j * NN + n] = acc;
}

// ---------------------------------------------------------------------------
// K3b: channel means -> sigmoid gate gpe[64]
// ---------------------------------------------------------------------------
__global__ void k_gatepe(const float* __restrict__ pe2,
                         const float* __restrict__ wg, const float* __restrict__ bg,
                         float* __restrict__ gpe) {
  int tid = threadIdx.x;  // 256
  int j = tid & 63, part = tid >> 6;
  float s = 0.f;
  const float* row = pe2 + (size_t)j * NN + part * 1024;
  for (int t = 0; t < 1024; ++t) s += row[t];
  __shared__ float ps[4][64];
  __shared__ float mean[64];
  ps[part][j] = s;
  __syncthreads();
  if (tid < 64) mean[j] = (ps[0][j] + ps[1][j] + ps[2][j] + ps[3][j]) * (1.f / 4096.f);
  __syncthreads();
  if (tid < 64) {
    float g = bg[j];
    for (int k2 = 0; k2 < 64; ++k2) g += wg[j * 64 + k2] * mean[k2];
    gpe[j] = 1.f / (1.f + expf(-g));
  }
}

// ---------------------------------------------------------------------------
// K3c: rope multiplier
// ---------------------------------------------------------------------------
__global__ void k_ropemul(const float* __restrict__ pe2, const float* __restrict__ gpe,
                          float* __restrict__ ropem) {
  int idx = blockIdx.x * 256 + threadIdx.x;
  int n = idx >> 6, dd = idx & 63;
  ropem[idx] = 1.f + pe2[(size_t)dd * NN + n] * gpe[n >> 6] * 0.35355339059327373f;
}

// Prep: f32 -> bf16 (weights)
__global__ void k_prep_h(const float* __restrict__ src,
                         ushort* __restrict__ Sh, int nelem) {
  int idx4 = (blockIdx.x * 256 + threadIdx.x) * 4;
  if (idx4 >= nelem) return;
  float4 v = *(const float4*)&src[idx4];
  ushort4 h;
  ((ushort*)&h)[0] = f2b(v.x);
  ((ushort*)&h)[1] = f2b(v.y);
  ((ushort*)&h)[2] = f2b(v.z);
  ((ushort*)&h)[3] = f2b(v.w);
  *(ushort4*)&Sh[idx4] = h;
}

// ---------------------------------------------------------------------------
// Plain double-buffered bf16 MFMA GEMM (m97-style, NO inline asm).
// 128x128 tile, BK=32, 4 waves (2x2), 2 LDS buffers, one __syncthreads/step.
// EPI=1: qk epilogue (gate, elu+1, rope; q/k stored TRANSPOSED [bh][d][n],
//        packed ushort4 stores over 4 consecutive nseq).
// EPI=2: out epilogue (gate*acc + beff[b][col], f32 out, per-batch B).
// ---------------------------------------------------------------------------
template <int BTERMS, int EPI>
__global__ __launch_bounds__(256) void k_gemm_t(
    const ushort* __restrict__ Ag, const ushort* __restrict__ Bgh,
    const ushort* __restrict__ Bgl,
    const float* __restrict__ bias, const float* __restrict__ gate,
    const float* __restrict__ ropem,
    float* __restrict__ outF, ushort* __restrict__ qT, ushort* __restrict__ kT,
    int ntn, int ncols) {
  const int nwg = gridDim.x;
  const int hw = blockIdx.x;
  const int logical = (hw & 7) * (nwg >> 3) + (hw >> 3);
  const int m0 = (logical / ntn) * 128, n0 = (logical % ntn) * 128;

  const int tid = threadIdx.x, wave = tid >> 6, lane = tid & 63;
  const int wm = wave >> 1, wn = wave & 1;
  __shared__ ushort sA[2][4096];
  __shared__ ushort sB[2][BTERMS * 4096];
  f32x4 acc[4][4] = {};

  const int lr = lane >> 2;
  const int ci = lane & 3;
  const int scol = (ci ^ ((lr >> 1) & 3)) * 8;           // inverse-swz source col
  const int rA = lane & 15;
  const int cswz = ((lane >> 4) ^ ((rA >> 1) & 3)) * 8;  // read-side swizzle

  const int chunk0 = wave * 2, chunk1 = wave * 2 + 1;
  const int row0 = chunk0 * 16 + lr, row1 = chunk1 * 16 + lr;

  const ushort* Bh_ = Bgh + (EPI == 2 ? (size_t)(m0 >> 12) * 262144 : 0);
  const ushort* Bl_ = (BTERMS == 2)
      ? (Bgl + (EPI == 2 ? (size_t)(m0 >> 12) * 262144 : 0)) : nullptr;

#define STAGE(T, S)                                                        \
  {                                                                        \
    const int k0s = (T) * 32;                                              \
    size_t ga0 = (size_t)(m0 + row0) * CC + k0s + scol;                    \
    size_t ga1 = (size_t)(m0 + row1) * CC + k0s + scol;                    \
    size_t gb0 = (size_t)(n0 + row0) * CC + k0s + scol;                    \
    size_t gb1 = (size_t)(n0 + row1) * CC + k0s + scol;                    \
    gload16(Ag + ga0, &sA[S][chunk0 * 512]);                               \
    gload16(Ag + ga1, &sA[S][chunk1 * 512]);                               \
    gload16(Bh_ + gb0, &sB[S][chunk0 * 512]);                              \
    gload16(Bh_ + gb1, &sB[S][chunk1 * 512]);                              \
    if (BTERMS == 2) {                                                     \
      gload16(Bl_ + gb0, &sB[S][4096 + chunk0 * 512]);                     \
      gload16(Bl_ + gb1, &sB[S][4096 + chunk1 * 512]);                     \
    }                                                                      \
  }

  STAGE(0, 0);
  __syncthreads();  // tile 0 landed (vmcnt drained by barrier)

  for (int t = 0; t < 16; ++t) {
    if (t < 15) STAGE(t + 1, (t + 1) & 1);  // issue early; lands by barrier
    const int cur = t & 1;
    bf16x8 af[4], bh[4], bl[4];
    #pragma unroll
    for (int m = 0; m < 4; ++m)
      af[m] = *(const bf16x8*)(&sA[cur][(wm * 64 + m * 16 + rA) * 32 + cswz]);
    #pragma unroll
    for (int n = 0; n < 4; ++n) {
      int off = (wn * 64 + n * 16 + rA) * 32 + cswz;
      bh[n] = *(const bf16x8*)(&sB[cur][off]);
      if (BTERMS == 2) bl[n] = *(const bf16x8*)(&sB[cur][4096 + off]);
    }
    #pragma unroll
    for (int m = 0; m < 4; ++m)
      #pragma unroll
      for (int n = 0; n < 4; ++n) {
        acc[m][n] = __builtin_amdgcn_mfma_f32_16x16x32_bf16(af[m], bh[n], acc[m][n], 0, 0, 0);
        if (BTERMS == 2)
          acc[m][n] = __builtin_amdgcn_mfma_f32_16x16x32_bf16(af[m], bl[n], acc[m][n], 0, 0, 0);
      }
    __syncthreads();  // next tile landed; this tile's reads done
  }
#undef STAGE

  const int kj = lane >> 4, l15 = lane & 15;
  #pragma unroll
  for (int m = 0; m < 4; ++m) {
    #pragma unroll
    for (int n = 0; n < 4; ++n) {
      if (EPI == 2) {
        #pragma unroll
        for (int r = 0; r < 4; ++r) {
          int row = m0 + wm * 64 + m * 16 + kj * 4 + r;
          int col = n0 + wn * 64 + n * 16 + l15;
          int nseq = row & (NN - 1), b = row >> 12;
          float val = acc[m][n][r] * gate[nseq] + bias[b * 512 + col];
          outF[(size_t)row * ncols + col] = val;
        }
      } else {
        // packed qT/kT store: 4 consecutive nseq at fixed channel
        int rowb = m0 + wm * 64 + m * 16 + kj * 4;
        int col = n0 + wn * 64 + n * 16 + l15;
        int nseqb = rowb & (NN - 1), b = rowb >> 12;
        int part = col >> 9, h = (col >> 6) & 7, dd = col & 63;
        ushort4 pk;
        #pragma unroll
        for (int r = 0; r < 4; ++r) {
          int nseq = nseqb + r;
          float val = acc[m][n][r] * gate[nseq] + bias[col];
          float e = val > 0.f ? val + 1.f : expf(val);  // elu+1
          ((ushort*)&pk)[r] = f2b(e * ropem[nseq * 64 + dd]);
        }
        ushort* dst = (part == 0 ? qT : kT) +
                      ((size_t)(b * HH + h) * DD + dd) * NN + nseqb;
        *(ushort4*)dst = pk;
      }
    }
  }
}

// ---------------------------------------------------------------------------
// K5a: ctx via MFMA straight from global. qT/kT: [bh][64 d][4096 n] bf16.
// ---------------------------------------------------------------------------
__global__ __launch_bounds__(256) void k_ctx_mfma(
    const ushort* __restrict__ qT, const ushort* __restrict__ kT,
    float* __restrict__ ctxp) {
  int blk = blockIdx.x;
  int bh = blk >> 3, chunk = blk & 7;
  int wave = threadIdx.x >> 6, lane = threadIdx.x & 63;
  int l15 = lane & 15, kj = lane >> 4;
  const size_t base = (size_t)bh * DD * NN;
  const int n0 = chunk * 512 + wave * 128;
  f32x4 acc[4][4] = {};
  for (int ks = 0; ks < 4; ++ks) {
    const int nb = n0 + ks * 32 + kj * 8;
    bf16x8 qa[4], ka[4];
    #pragma unroll
    for (int m = 0; m < 4; ++m)
      qa[m] = *(const bf16x8*)(qT + base + (size_t)(m * 16 + l15) * NN + nb);
    #pragma unroll
    for (int n = 0; n < 4; ++n)
      ka[n] = *(const bf16x8*)(kT + base + (size_t)(n * 16 + l15) * NN + nb);
    #pragma unroll
    for (int m = 0; m < 4; ++m)
      #pragma unroll
      for (int n = 0; n < 4; ++n)
        acc[m][n] = __builtin_amdgcn_mfma_f32_16x16x32_bf16(qa[m], ka[n], acc[m][n], 0, 0, 0);
  }
  const float scale = 1.f / 512.f;
  float* dst = ctxp + ((size_t)bh * 32 + chunk * 4 + wave) * 4096;
  #pragma unroll
  for (int m = 0; m < 4; ++m)
    #pragma unroll
    for (int n = 0; n < 4; ++n)
      #pragma unroll
      for (int r = 0; r < 4; ++r)
        dst[(m * 16 + kj * 4 + r) * 64 + n * 16 + l15] = acc[m][n][r] * scale;
}

// K5b: parallel deterministic reduce of 32 partials -> ctx[bh][64][64]
// one thread per output element; coalesced per-slice reads. grid 512.
__global__ void k_ctx_red(const float* __restrict__ ctxp, float* __restrict__ ctx) {
  int idx = blockIdx.x * 256 + threadIdx.x;  // 0..131071
  int bh = idx >> 12, off = idx & 4095;
  float s = 0.f;
  #pragma unroll
  for (int c2 = 0; c2 < 32; ++c2)
    s += ctxp[((size_t)bh * 32 + c2) * 4096 + off];
  ctx[idx] = s;
}

// ---------------------------------------------------------------------------
// K6: Mf[b][o][h*64+d] = (1/512) * sum_e ctx[b,h,d,e] * wp[o, h*64+e]  (f32)
// ---------------------------------------------------------------------------
__global__ __launch_bounds__(256) void k_mproj(
    const float* __restrict__ ctx, const float* __restrict__ wp,
    float* __restrict__ Mf) {
  int blk = blockIdx.x;
  int b = blk >> 5, h = (blk >> 2) & 7, oq = blk & 3;
  int tid = threadIdx.x;
  int o = oq * 128 + (tid & 127);
  int d0 = (tid >> 7) * 32;
  __shared__ float cs[64][64];
  #pragma unroll
  for (int it = 0; it < 4; ++it) {
    int idx = (tid + 256 * it) * 4;
    *(float4*)&cs[idx >> 6][idx & 63] =
        *(const float4*)&ctx[(size_t)(b * 8 + h) * 4096 + idx];
  }
  __syncthreads();
  float wv[64];
  #pragma unroll
  for (int e = 0; e < 64; ++e) wv[e] = wp[(size_t)o * 512 + h * 64 + e];
  for (int d = d0; d < d0 + 32; ++d) {
    float s = 0.f;
    #pragma unroll
    for (int e = 0; e < 64; ++e) s += cs[d][e] * wv[e];
    Mf[((size_t)b * 512 + o) * 512 + h * 64 + d] = s * (1.f / 512.f);
  }
}

// ---------------------------------------------------------------------------
// K7: G2[b][o][c] = sum_{c'} Mf[b][o][c'] * Wv[c'][c]   (Wv = wqkv rows 1024+)
// ---------------------------------------------------------------------------
__global__ __launch_bounds__(256) void k_g2(
    const float* __restrict__ Mf, const float* __restrict__ wqkv,
    ushort* __restrict__ G2h, ushort* __restrict__ G2l) {
  int blk = blockIdx.x;
  int b = blk >> 6, ot = (blk >> 3) & 7, ct = blk & 7;
  int tx = threadIdx.x & 15, ty = threadIdx.x >> 4;
  __shared__ float As[32][65], Ws[32][65];
  float acc[4][4] = {};
  const float* Mb = Mf + (size_t)b * 262144;
  for (int k0 = 0; k0 < 512; k0 += 32) {
    #pragma unroll
    for (int it = 0; it < 8; ++it) {
      int e = threadIdx.x + 256 * it;  // 2048
      int m = e >> 5, kk = e & 31;
      As[kk][m] = Mb[(size_t)(ot * 64 + m) * 512 + k0 + kk];
      int kk2 = e >> 6, cc = e & 63;
      Ws[kk2][cc] = wqkv[(size_t)(1024 + k0 + kk2) * 512 + ct * 64 + cc];
    }
    __syncthreads();
    #pragma unroll
    for (int kk = 0; kk < 32; ++kk) {
      float a[4], wv[4];
      #pragma unroll
      for (int i = 0; i < 4; ++i) a[i] = As[kk][ty + 16 * i];
      #pragma unroll
      for (int j = 0; j < 4; ++j) wv[j] = Ws[kk][tx + 16 * j];
      #pragma unroll
      for (int i = 0; i < 4; ++i)
        #pragma unroll
        for (int j = 0; j < 4; ++j) acc[i][j] += a[i] * wv[j];
    }
    __syncthreads();
  }
  #pragma unroll
  for (int i = 0; i < 4; ++i)
    #pragma unroll
    for (int j = 0; j < 4; ++j) {
      size_t idx = ((size_t)b * 512 + ot * 64 + ty + 16 * i) * 512 + ct * 64 + tx + 16 * j;
      float s = acc[i][j];
      ushort hi = f2b(s);
      G2h[idx] = hi;
      G2l[idx] = f2b(s - b2f(hi));
    }
}

// K8: beff[b][o] = sum_{c'} bqkv[1024+c'] * Mf[b][o][c'] + bproj[o]
// one wave per output; coalesced lane-strided reads + shuffle tree reduce.
__global__ void k_beff(const float* __restrict__ Mf, const float* __restrict__ bqkv,
                       const float* __restrict__ bproj, float* __restrict__ beff) {
  int w = threadIdx.x >> 6, lane = threadIdx.x & 63;
  int t = blockIdx.x * 4 + w;  // 0..2047
  int b = t >> 9, o = t & 511;
  const float* row = Mf + ((size_t)b * 512 + o) * 512;
  float s = 0.f;
  #pragma unroll
  for (int c = 0; c < 512; c += 64) s += bqkv[1024 + c + lane] * row[c + lane];
  #pragma unroll
  for (int off = 32; off > 0; off >>= 1) s += __shfl_down(s, off);
  if (lane == 0) beff[t] = s + bproj[o];
}

// ---------------------------------------------------------------------------
extern "C" void kernel_launch(void* const* d_in, const int* in_sizes, int n_in,
                              void* d_out, int out_size, void* d_ws, size_t ws_size,
                              hipStream_t stream) {
  const float* x    = (const float*)d_in[0];
  const float* lpw  = (const float*)d_in[1];
  const float* lvw  = (const float*)d_in[2];
  const float* wqkv = (const float*)d_in[3];
  const float* bqkv = (const float*)d_in[4];
  const float* wproj= (const float*)d_in[5];
  const float* bproj= (const float*)d_in[6];
  const float* omega= (const float*)d_in[7];
  const float* w1   = (const float*)d_in[8];
  const float* b1   = (const float*)d_in[9];
  const float* w2   = (const float*)d_in[10];
  const float* b2   = (const float*)d_in[11];
  const float* wg   = (const float*)d_in[12];
  const float* bg   = (const float*)d_in[13];
  float* out = (float*)d_out;

  constexpr size_t MB = 1024 * 1024;
  char* w = (char*)d_ws;
  int*   peak   = (int*)(w);
  int*   valley = (int*)(w + 16 * 1024);
  float* attn   = (float*)(w + 32 * 1024);
  float* gate   = (float*)(w + 48 * 1024);
  float* pe2    = (float*)(w + 64 * 1024);        // 1 MiB
  float* gpe    = (float*)(w + 1088 * 1024);
  float* ropem  = (float*)(w + 1152 * 1024);      // 1 MiB
  float* etabP  = (float*)(w + 2176 * 1024);
  float* etabV  = (float*)(w + 2192 * 1024);
  ushort* Xh    = (ushort*)(w + 4 * MB);          // 16 MiB bf16 [B*N, C]
  ushort* qT    = (ushort*)(w + 20 * MB);         // 16 MiB bf16 [B,H,D,N]
  ushort* kT    = (ushort*)(w + 36 * MB);         // 16 MiB
  ushort* Whqk  = (ushort*)(w + 52 * MB);         // 1 MiB (q,k weights bf16)
  float* Mf     = (float*)(w + 53 * MB);          // 4 MiB f32 [B][512][512]
  ushort* G2h   = (ushort*)(w + 57 * MB);         // 2 MiB
  ushort* G2l   = (ushort*)(w + 59 * MB);         // 2 MiB
  float* beff   = (float*)(w + 61 * MB);          // 8 KiB
  float* ctxp   = (float*)(w + 62 * MB);          // 16 MiB
  float* ctx    = (float*)(w + 78 * MB);          // 0.5 MiB -> 78.5 MiB total

  hipMemsetAsync(peak, 0, 2 * 4096 * sizeof(int), stream);

  k_counts_prep<<<BB * 64, 512, 0, stream>>>(x, peak, valley, Xh);
  k_etab<<<16, 256, 0, stream>>>(lpw, lvw, etabP, etabV);
  k_gsum<<<NN, 256, 0, stream>>>(peak, valley, etabP, etabV, attn);
  k_norm<<<1, 1024, 0, stream>>>(attn, gate);
  k_pe<<<NN, 64, 0, stream>>>(omega, w1, b1, w2, b2, pe2);
  k_gatepe<<<1, 256, 0, stream>>>(pe2, wg, bg, gpe);
  k_ropemul<<<1024, 256, 0, stream>>>(pe2, gpe, ropem);
  k_prep_h<<<512, 256, 0, stream>>>(wqkv, Whqk, 1024 * CC);

  // q,k GEMM: M=16384, N=1024 -> 128 x 8 = 1024 blocks (4/CU)
  k_gemm_t<1, 1><<<1024, 256, 0, stream>>>(Xh, Whqk, nullptr, bqkv, gate, ropem,
                                           nullptr, qT, kT, 8, 0);
  k_ctx_mfma<<<256, 256, 0, stream>>>(qT, kT, ctxp);
  k_ctx_red<<<512, 256, 0, stream>>>(ctxp, ctx);
  k_mproj<<<128, 256, 0, stream>>>(ctx, wproj, Mf);
  k_g2<<<256, 256, 0, stream>>>(Mf, wqkv, G2h, G2l);
  k_beff<<<512, 256, 0, stream>>>(Mf, bqkv, bproj, beff);

  // out GEMM: out = gate*(Xh * G2_b^T) + beff; M=16384, N=512 -> 512 blocks (2/CU)
  k_gemm_t<2, 2><<<512, 256, 0, stream>>>(Xh, G2h, G2l, beff, gate, nullptr,
                                          out, nullptr, nullptr, 4, CC);
}

// Round 9
// 226.574 us; speedup vs baseline: 1.5106x; 1.1163x over previous
//
#include <hip/hip_runtime.h>
#include <hip/hip_bf16.h>
#include <math.h>

constexpr int BB = 4;
constexpr int NN = 4096;
constexpr int CC = 512;
constexpr int HH = 8;
constexpr int DD = 64;
constexpr int NCNT = NN - 2;

typedef __bf16 bf16x8 __attribute__((ext_vector_type(8)));
typedef float f32x4 __attribute__((ext_vector_type(4)));

__device__ __forceinline__ float b2f(ushort u) {
  unsigned v = ((unsigned)u) << 16;
  return __builtin_bit_cast(float, v);
}
__device__ __forceinline__ ushort f2b(float f) {
  __hip_bfloat16 h = __float2bfloat16(f);
  return __builtin_bit_cast(ushort, h);
}
__device__ __forceinline__ void gload16(const ushort* g, ushort* l) {
  __builtin_amdgcn_global_load_lds(
      (const __attribute__((address_space(1))) unsigned int*)g,
      (__attribute__((address_space(3))) unsigned int*)l, 16, 0, 0);
}

// ---------------------------------------------------------------------------
// K1: second-diff sign counts + fused x -> bf16.
// Batched independent loads (18 rows up-front per thread) to kill the
// serial load->ballot->atomic latency chain. Grid 4x256, 512 thr.
// ---------------------------------------------------------------------------
__global__ __launch_bounds__(512) void k_counts_prep(
    const float* __restrict__ x, int* __restrict__ peak,
    int* __restrict__ valley, ushort* __restrict__ Xh) {
  int b = blockIdx.x >> 8;
  int tile = blockIdx.x & 255;
  int c = threadIdx.x;
  int lane = threadIdx.x & 63;
  int wv = threadIdx.x >> 6;
  int i0 = tile * 16;
  const float* xb = x + (size_t)b * NN * CC + c;

  float v[18];
  #pragma unroll
  for (int r = 0; r < 18; ++r) {
    int i = i0 + r;
    v[r] = xb[(size_t)(i < NN ? i : NN - 1) * CC];  // all independent loads
  }

  #pragma unroll
  for (int r = 0; r < 16; ++r)
    Xh[((size_t)b * NN + i0 + r) * CC + c] = f2b(v[r]);

  __shared__ int redP[16], redV[16];
  if (threadIdx.x < 16) { redP[threadIdx.x] = 0; redV[threadIdx.x] = 0; }
  __syncthreads();

  #pragma unroll
  for (int r = 0; r < 16; ++r) {
    int i = i0 + r;
    if (i < NCNT) {  // uniform across block
      float d2 = (v[r + 2] - v[r + 1]) - (v[r + 1] - v[r]);
      unsigned long long mneg = __ballot(d2 < 0.0f);
      unsigned long long mpos = __ballot(d2 > 0.0f);
      if (lane == 0) {
        atomicAdd(&redP[r], __popcll(mneg));
        atomicAdd(&redV[r], __popcll(mpos));
      }
    }
  }
  __syncthreads();
  if (threadIdx.x < 16) {
    int i = i0 + threadIdx.x;
    if (i < NCNT) {
      atomicAdd(&peak[i], redP[threadIdx.x]);
      atomicAdd(&valley[i], redV[threadIdx.x]);
    }
  }
  (void)wv;
}

// ---------------------------------------------------------------------------
// K2pre: Gaussian tables etab[a] = exp(-(a*iw)^2)
// ---------------------------------------------------------------------------
__global__ void k_etab(const float* __restrict__ lpw, const float* __restrict__ lvw,
                       float* __restrict__ etabP, float* __restrict__ etabV) {
  int i = blockIdx.x * 256 + threadIdx.x;
  float ipw = expf(-lpw[0]);
  float ivw = expf(-lvw[0]);
  float t1 = (float)i * ipw;
  float t2 = (float)i * ivw;
  etabP[i] = expf(-t1 * t1);
  etabV[i] = expf(-t2 * t2);
}

// ---------------------------------------------------------------------------
// K2a: Gaussian sums via tables
// ---------------------------------------------------------------------------
__global__ void k_gsum(const int* __restrict__ peak, const int* __restrict__ valley,
                       const float* __restrict__ etabP, const float* __restrict__ etabV,
                       float* __restrict__ attn) {
  int p = blockIdx.x;
  int tid = threadIdx.x;
  float acc = 0.f;
  for (int i = tid; i < NCNT; i += 256) {
    int a = p - 1 - i;
    a = a < 0 ? -a : a;
    acc += (float)peak[i] * etabP[a] + (float)valley[i] * etabV[a];
  }
  __shared__ float red[256];
  red[tid] = acc;
  __syncthreads();
  for (int s = 128; s > 0; s >>= 1) {
    if (tid < s) red[tid] += red[tid + s];
    __syncthreads();
  }
  if (tid == 0) attn[p] = red[0];
}

// ---------------------------------------------------------------------------
// K2b: min-max normalize
// ---------------------------------------------------------------------------
__global__ void k_norm(const float* __restrict__ attn, float* __restrict__ gate) {
  int tid = threadIdx.x;  // 1024
  float v0 = attn[tid], v1 = attn[tid + 1024], v2 = attn[tid + 2048], v3 = attn[tid + 3072];
  float mn = fminf(fminf(v0, v1), fminf(v2, v3));
  float mx = fmaxf(fmaxf(v0, v1), fmaxf(v2, v3));
  __shared__ float rmn[1024], rmx[1024];
  rmn[tid] = mn; rmx[tid] = mx;
  __syncthreads();
  for (int s = 512; s > 0; s >>= 1) {
    if (tid < s) {
      rmn[tid] = fminf(rmn[tid], rmn[tid + s]);
      rmx[tid] = fmaxf(rmx[tid], rmx[tid + s]);
    }
    __syncthreads();
  }
  float lo = rmn[0];
  float denom = rmx[0] - rmn[0] + 1e-6f;
  gate[tid]        = (v0 - lo) / denom;
  gate[tid + 1024] = (v1 - lo) / denom;
  gate[tid + 2048] = (v2 - lo) / denom;
  gate[tid + 3072] = (v3 - lo) / denom;
}

// ---------------------------------------------------------------------------
// K3a: spectral PE conv path -> pe2 [64][4096]
// ---------------------------------------------------------------------------
__global__ void k_pe(const float* __restrict__ omega,
                     const float* __restrict__ w1, const float* __restrict__ b1,
                     const float* __restrict__ w2, const float* __restrict__ b2,
                     float* __restrict__ pe2) {
  int n = blockIdx.x;
  int j = threadIdx.x;  // 64
  __shared__ float pec[3][64];
  __shared__ float hs[128];
  for (int t = 0; t < 3; ++t) {
    int m = n + t - 1;
    float v = 0.f;
    if (m >= 0 && m < NN) {
      int l1 = m >> 6, l2 = m & 63;
      float rel = (float)(l1 - l2);
      v = (j < 32) ? sinf(rel * omega[j]) : cosf(rel * omega[j - 32]);
    }
    pec[t][j] = v;
  }
  __syncthreads();
  for (int o = j; o < 128; o += 64) {
    int ci = o >> 1;
    float hv = b1[o];
    #pragma unroll
    for (int t = 0; t < 3; ++t) hv += pec[t][ci] * w1[o * 3 + t];
    hv = 0.5f * hv * (1.f + erff(hv * 0.70710678118654752f));
    hs[o] = hv;
  }
  __syncthreads();
  float acc = b2[j];
  for (int o = 0; o < 128; ++o) acc += hs[o] * w2[j * 128 + o];
  pe2[(size_t)j * NN + n] = acc;
}

// ---------------------------------------------------------------------------
// K3b: channel means -> sigmoid gate gpe[64]
// ---------------------------------------------------------------------------
__global__ void k_gatepe(const float* __restrict__ pe2,
                         const float* __restrict__ wg, const float* __restrict__ bg,
                         float* __restrict__ gpe) {
  int tid = threadIdx.x;  // 256
  int j = tid & 63, part = tid >> 6;
  float s = 0.f;
  const float* row = pe2 + (size_t)j * NN + part * 1024;
  for (int t = 0; t < 1024; ++t) s += row[t];
  __shared__ float ps[4][64];
  __shared__ float mean[64];
  ps[part][j] = s;
  __syncthreads();
  if (tid < 64) mean[j] = (ps[0][j] + ps[1][j] + ps[2][j] + ps[3][j]) * (1.f / 4096.f);
  __syncthreads();
  if (tid < 64) {
    float g = bg[j];
    for (int k2 = 0; k2 < 64; ++k2) g += wg[j * 64 + k2] * mean[k2];
    gpe[j] = 1.f / (1.f + expf(-g));
  }
}

// ---------------------------------------------------------------------------
// K3c: rope multiplier
// ---------------------------------------------------------------------------
__global__ void k_ropemul(const float* __restrict__ pe2, const float* __restrict__ gpe,
                          float* __restrict__ ropem) {
  int idx = blockIdx.x * 256 + threadIdx.x;
  int n = idx >> 6, dd = idx & 63;
  ropem[idx] = 1.f + pe2[(size_t)dd * NN + n] * gpe[n >> 6] * 0.35355339059327373f;
}

// Prep: f32 -> bf16 (weights)
__global__ void k_prep_h(const float* __restrict__ src,
                         ushort* __restrict__ Sh, int nelem) {
  int idx4 = (blockIdx.x * 256 + threadIdx.x) * 4;
  if (idx4 >= nelem) return;
  float4 v = *(const float4*)&src[idx4];
  ushort4 h;
  ((ushort*)&h)[0] = f2b(v.x);
  ((ushort*)&h)[1] = f2b(v.y);
  ((ushort*)&h)[2] = f2b(v.z);
  ((ushort*)&h)[3] = f2b(v.w);
  *(ushort4*)&Sh[idx4] = h;
}

// ---------------------------------------------------------------------------
// Plain double-buffered bf16 MFMA GEMM (m97-style, NO inline asm).
// 128x128 tile, BK=32, 4 waves (2x2), 2 LDS buffers, one __syncthreads/step.
// EPI=1: qk epilogue (gate, elu+1, rope; q/k stored TRANSPOSED [bh][d][n],
//        packed ushort4 stores over 4 consecutive nseq).
// EPI=2: out epilogue (gate*acc + beff[b][col], f32 out, per-batch B).
// ---------------------------------------------------------------------------
template <int BTERMS, int EPI>
__global__ __launch_bounds__(256) void k_gemm_t(
    const ushort* __restrict__ Ag, const ushort* __restrict__ Bgh,
    const ushort* __restrict__ Bgl,
    const float* __restrict__ bias, const float* __restrict__ gate,
    const float* __restrict__ ropem,
    float* __restrict__ outF, ushort* __restrict__ qT, ushort* __restrict__ kT,
    int ntn, int ncols) {
  const int nwg = gridDim.x;
  const int hw = blockIdx.x;
  const int logical = (hw & 7) * (nwg >> 3) + (hw >> 3);
  const int m0 = (logical / ntn) * 128, n0 = (logical % ntn) * 128;

  const int tid = threadIdx.x, wave = tid >> 6, lane = tid & 63;
  const int wm = wave >> 1, wn = wave & 1;
  __shared__ ushort sA[2][4096];
  __shared__ ushort sB[2][BTERMS * 4096];
  f32x4 acc[4][4] = {};

  const int lr = lane >> 2;
  const int ci = lane & 3;
  const int scol = (ci ^ ((lr >> 1) & 3)) * 8;           // inverse-swz source col
  const int rA = lane & 15;
  const int cswz = ((lane >> 4) ^ ((rA >> 1) & 3)) * 8;  // read-side swizzle

  const int chunk0 = wave * 2, chunk1 = wave * 2 + 1;
  const int row0 = chunk0 * 16 + lr, row1 = chunk1 * 16 + lr;

  const ushort* Bh_ = Bgh + (EPI == 2 ? (size_t)(m0 >> 12) * 262144 : 0);
  const ushort* Bl_ = (BTERMS == 2)
      ? (Bgl + (EPI == 2 ? (size_t)(m0 >> 12) * 262144 : 0)) : nullptr;

#define STAGE(T, S)                                                        \
  {                                                                        \
    const int k0s = (T) * 32;                                              \
    size_t ga0 = (size_t)(m0 + row0) * CC + k0s + scol;                    \
    size_t ga1 = (size_t)(m0 + row1) * CC + k0s + scol;                    \
    size_t gb0 = (size_t)(n0 + row0) * CC + k0s + scol;                    \
    size_t gb1 = (size_t)(n0 + row1) * CC + k0s + scol;                    \
    gload16(Ag + ga0, &sA[S][chunk0 * 512]);                               \
    gload16(Ag + ga1, &sA[S][chunk1 * 512]);                               \
    gload16(Bh_ + gb0, &sB[S][chunk0 * 512]);                              \
    gload16(Bh_ + gb1, &sB[S][chunk1 * 512]);                              \
    if (BTERMS == 2) {                                                     \
      gload16(Bl_ + gb0, &sB[S][4096 + chunk0 * 512]);                     \
      gload16(Bl_ + gb1, &sB[S][4096 + chunk1 * 512]);                     \
    }                                                                      \
  }

  STAGE(0, 0);
  __syncthreads();  // tile 0 landed (vmcnt drained by barrier)

  for (int t = 0; t < 16; ++t) {
    if (t < 15) STAGE(t + 1, (t + 1) & 1);  // issue early; lands by barrier
    const int cur = t & 1;
    bf16x8 af[4], bh[4], bl[4];
    #pragma unroll
    for (int m = 0; m < 4; ++m)
      af[m] = *(const bf16x8*)(&sA[cur][(wm * 64 + m * 16 + rA) * 32 + cswz]);
    #pragma unroll
    for (int n = 0; n < 4; ++n) {
      int off = (wn * 64 + n * 16 + rA) * 32 + cswz;
      bh[n] = *(const bf16x8*)(&sB[cur][off]);
      if (BTERMS == 2) bl[n] = *(const bf16x8*)(&sB[cur][4096 + off]);
    }
    #pragma unroll
    for (int m = 0; m < 4; ++m)
      #pragma unroll
      for (int n = 0; n < 4; ++n) {
        acc[m][n] = __builtin_amdgcn_mfma_f32_16x16x32_bf16(af[m], bh[n], acc[m][n], 0, 0, 0);
        if (BTERMS == 2)
          acc[m][n] = __builtin_amdgcn_mfma_f32_16x16x32_bf16(af[m], bl[n], acc[m][n], 0, 0, 0);
      }
    __syncthreads();  // next tile landed; this tile's reads done
  }
#undef STAGE

  const int kj = lane >> 4, l15 = lane & 15;
  #pragma unroll
  for (int m = 0; m < 4; ++m) {
    #pragma unroll
    for (int n = 0; n < 4; ++n) {
      if (EPI == 2) {
        #pragma unroll
        for (int r = 0; r < 4; ++r) {
          int row = m0 + wm * 64 + m * 16 + kj * 4 + r;
          int col = n0 + wn * 64 + n * 16 + l15;
          int nseq = row & (NN - 1), b = row >> 12;
          float val = acc[m][n][r] * gate[nseq] + bias[b * 512 + col];
          outF[(size_t)row * ncols + col] = val;
        }
      } else {
        // packed qT/kT store: 4 consecutive nseq at fixed channel
        int rowb = m0 + wm * 64 + m * 16 + kj * 4;
        int col = n0 + wn * 64 + n * 16 + l15;
        int nseqb = rowb & (NN - 1), b = rowb >> 12;
        int part = col >> 9, h = (col >> 6) & 7, dd = col & 63;
        ushort4 pk;
        #pragma unroll
        for (int r = 0; r < 4; ++r) {
          int nseq = nseqb + r;
          float val = acc[m][n][r] * gate[nseq] + bias[col];
          float e = val > 0.f ? val + 1.f : expf(val);  // elu+1
          ((ushort*)&pk)[r] = f2b(e * ropem[nseq * 64 + dd]);
        }
        ushort* dst = (part == 0 ? qT : kT) +
                      ((size_t)(b * HH + h) * DD + dd) * NN + nseqb;
        *(ushort4*)dst = pk;
      }
    }
  }
}

// ---------------------------------------------------------------------------
// K5a: ctx via MFMA straight from global. qT/kT: [bh][64 d][4096 n] bf16.
// ---------------------------------------------------------------------------
__global__ __launch_bounds__(256) void k_ctx_mfma(
    const ushort* __restrict__ qT, const ushort* __restrict__ kT,
    float* __restrict__ ctxp) {
  int blk = blockIdx.x;
  int bh = blk >> 3, chunk = blk & 7;
  int wave = threadIdx.x >> 6, lane = threadIdx.x & 63;
  int l15 = lane & 15, kj = lane >> 4;
  const size_t base = (size_t)bh * DD * NN;
  const int n0 = chunk * 512 + wave * 128;
  f32x4 acc[4][4] = {};
  for (int ks = 0; ks < 4; ++ks) {
    const int nb = n0 + ks * 32 + kj * 8;
    bf16x8 qa[4], ka[4];
    #pragma unroll
    for (int m = 0; m < 4; ++m)
      qa[m] = *(const bf16x8*)(qT + base + (size_t)(m * 16 + l15) * NN + nb);
    #pragma unroll
    for (int n = 0; n < 4; ++n)
      ka[n] = *(const bf16x8*)(kT + base + (size_t)(n * 16 + l15) * NN + nb);
    #pragma unroll
    for (int m = 0; m < 4; ++m)
      #pragma unroll
      for (int n = 0; n < 4; ++n)
        acc[m][n] = __builtin_amdgcn_mfma_f32_16x16x32_bf16(qa[m], ka[n], acc[m][n], 0, 0, 0);
  }
  const float scale = 1.f / 512.f;
  float* dst = ctxp + ((size_t)bh * 32 + chunk * 4 + wave) * 4096;
  #pragma unroll
  for (int m = 0; m < 4; ++m)
    #pragma unroll
    for (int n = 0; n < 4; ++n)
      #pragma unroll
      for (int r = 0; r < 4; ++r)
        dst[(m * 16 + kj * 4 + r) * 64 + n * 16 + l15] = acc[m][n][r] * scale;
}

// K5b: parallel deterministic reduce of 32 partials -> ctx[bh][64][64]
__global__ void k_ctx_red(const float* __restrict__ ctxp, float* __restrict__ ctx) {
  int idx = blockIdx.x * 256 + threadIdx.x;  // 0..131071
  int bh = idx >> 12, off = idx & 4095;
  float s = 0.f;
  #pragma unroll
  for (int c2 = 0; c2 < 32; ++c2)
    s += ctxp[((size_t)bh * 32 + c2) * 4096 + off];
  ctx[idx] = s;
}

// ---------------------------------------------------------------------------
// K6: Mf[b][o][h*64+d] = (1/512) * sum_e ctx[b,h,d,e] * wp[o, h*64+e]  (f32)
// ---------------------------------------------------------------------------
__global__ __launch_bounds__(256) void k_mproj(
    const float* __restrict__ ctx, const float* __restrict__ wp,
    float* __restrict__ Mf) {
  int blk = blockIdx.x;
  int b = blk >> 5, h = (blk >> 2) & 7, oq = blk & 3;
  int tid = threadIdx.x;
  int o = oq * 128 + (tid & 127);
  int d0 = (tid >> 7) * 32;
  __shared__ float cs[64][64];
  #pragma unroll
  for (int it = 0; it < 4; ++it) {
    int idx = (tid + 256 * it) * 4;
    *(float4*)&cs[idx >> 6][idx & 63] =
        *(const float4*)&ctx[(size_t)(b * 8 + h) * 4096 + idx];
  }
  __syncthreads();
  float wv[64];
  #pragma unroll
  for (int e = 0; e < 64; ++e) wv[e] = wp[(size_t)o * 512 + h * 64 + e];
  for (int d = d0; d < d0 + 32; ++d) {
    float s = 0.f;
    #pragma unroll
    for (int e = 0; e < 64; ++e) s += cs[d][e] * wv[e];
    Mf[((size_t)b * 512 + o) * 512 + h * 64 + d] = s * (1.f / 512.f);
  }
}

// ---------------------------------------------------------------------------
// K7: G2[b][o][c] = sum_{c'} Mf[b][o][c'] * Wv[c'][c]   (Wv = wqkv rows 1024+)
// ---------------------------------------------------------------------------
__global__ __launch_bounds__(256) void k_g2(
    const float* __restrict__ Mf, const float* __restrict__ wqkv,
    ushort* __restrict__ G2h, ushort* __restrict__ G2l) {
  int blk = blockIdx.x;
  int b = blk >> 6, ot = (blk >> 3) & 7, ct = blk & 7;
  int tx = threadIdx.x & 15, ty = threadIdx.x >> 4;
  __shared__ float As[32][65], Ws[32][65];
  float acc[4][4] = {};
  const float* Mb = Mf + (size_t)b * 262144;
  for (int k0 = 0; k0 < 512; k0 += 32) {
    #pragma unroll
    for (int it = 0; it < 8; ++it) {
      int e = threadIdx.x + 256 * it;  // 2048
      int m = e >> 5, kk = e & 31;
      As[kk][m] = Mb[(size_t)(ot * 64 + m) * 512 + k0 + kk];
      int kk2 = e >> 6, cc = e & 63;
      Ws[kk2][cc] = wqkv[(size_t)(1024 + k0 + kk2) * 512 + ct * 64 + cc];
    }
    __syncthreads();
    #pragma unroll
    for (int kk = 0; kk < 32; ++kk) {
      float a[4], wv[4];
      #pragma unroll
      for (int i = 0; i < 4; ++i) a[i] = As[kk][ty + 16 * i];
      #pragma unroll
      for (int j = 0; j < 4; ++j) wv[j] = Ws[kk][tx + 16 * j];
      #pragma unroll
      for (int i = 0; i < 4; ++i)
        #pragma unroll
        for (int j = 0; j < 4; ++j) acc[i][j] += a[i] * wv[j];
    }
    __syncthreads();
  }
  #pragma unroll
  for (int i = 0; i < 4; ++i)
    #pragma unroll
    for (int j = 0; j < 4; ++j) {
      size_t idx = ((size_t)b * 512 + ot * 64 + ty + 16 * i) * 512 + ct * 64 + tx + 16 * j;
      float s = acc[i][j];
      ushort hi = f2b(s);
      G2h[idx] = hi;
      G2l[idx] = f2b(s - b2f(hi));
    }
}

// K8: beff[b][o] = sum_{c'} bqkv[1024+c'] * Mf[b][o][c'] + bproj[o]
__global__ void k_beff(const float* __restrict__ Mf, const float* __restrict__ bqkv,
                       const float* __restrict__ bproj, float* __restrict__ beff) {
  int w = threadIdx.x >> 6, lane = threadIdx.x & 63;
  int t = blockIdx.x * 4 + w;  // 0..2047
  int b = t >> 9, o = t & 511;
  const float* row = Mf + ((size_t)b * 512 + o) * 512;
  float s = 0.f;
  #pragma unroll
  for (int c = 0; c < 512; c += 64) s += bqkv[1024 + c + lane] * row[c + lane];
  #pragma unroll
  for (int off = 32; off > 0; off >>= 1) s += __shfl_down(s, off);
  if (lane == 0) beff[t] = s + bproj[o];
}

// ---------------------------------------------------------------------------
extern "C" void kernel_launch(void* const* d_in, const int* in_sizes, int n_in,
                              void* d_out, int out_size, void* d_ws, size_t ws_size,
                              hipStream_t stream) {
  const float* x    = (const float*)d_in[0];
  const float* lpw  = (const float*)d_in[1];
  const float* lvw  = (const float*)d_in[2];
  const float* wqkv = (const float*)d_in[3];
  const float* bqkv = (const float*)d_in[4];
  const float* wproj= (const float*)d_in[5];
  const float* bproj= (const float*)d_in[6];
  const float* omega= (const float*)d_in[7];
  const float* w1   = (const float*)d_in[8];
  const float* b1   = (const float*)d_in[9];
  const float* w2   = (const float*)d_in[10];
  const float* b2   = (const float*)d_in[11];
  const float* wg   = (const float*)d_in[12];
  const float* bg   = (const float*)d_in[13];
  float* out = (float*)d_out;

  constexpr size_t MB = 1024 * 1024;
  char* w = (char*)d_ws;
  int*   peak   = (int*)(w);
  int*   valley = (int*)(w + 16 * 1024);
  float* attn   = (float*)(w + 32 * 1024);
  float* gate   = (float*)(w + 48 * 1024);
  float* pe2    = (float*)(w + 64 * 1024);        // 1 MiB
  float* gpe    = (float*)(w + 1088 * 1024);
  float* ropem  = (float*)(w + 1152 * 1024);      // 1 MiB
  float* etabP  = (float*)(w + 2176 * 1024);
  float* etabV  = (float*)(w + 2192 * 1024);
  ushort* Xh    = (ushort*)(w + 4 * MB);          // 16 MiB bf16 [B*N, C]
  ushort* qT    = (ushort*)(w + 20 * MB);         // 16 MiB bf16 [B,H,D,N]
  ushort* kT    = (ushort*)(w + 36 * MB);         // 16 MiB
  ushort* Whqk  = (ushort*)(w + 52 * MB);         // 1 MiB (q,k weights bf16)
  float* Mf     = (float*)(w + 53 * MB);          // 4 MiB f32 [B][512][512]
  ushort* G2h   = (ushort*)(w + 57 * MB);         // 2 MiB
  ushort* G2l   = (ushort*)(w + 59 * MB);         // 2 MiB
  float* beff   = (float*)(w + 61 * MB);          // 8 KiB
  float* ctxp   = (float*)(w + 62 * MB);          // 16 MiB
  float* ctx    = (float*)(w + 78 * MB);          // 0.5 MiB -> 78.5 MiB total

  hipMemsetAsync(peak, 0, 2 * 4096 * sizeof(int), stream);

  k_counts_prep<<<BB * 256, 512, 0, stream>>>(x, peak, valley, Xh);
  k_etab<<<16, 256, 0, stream>>>(lpw, lvw, etabP, etabV);
  k_gsum<<<NN, 256, 0, stream>>>(peak, valley, etabP, etabV, attn);
  k_norm<<<1, 1024, 0, stream>>>(attn, gate);
  k_pe<<<NN, 64, 0, stream>>>(omega, w1, b1, w2, b2, pe2);
  k_gatepe<<<1, 256, 0, stream>>>(pe2, wg, bg, gpe);
  k_ropemul<<<1024, 256, 0, stream>>>(pe2, gpe, ropem);
  k_prep_h<<<512, 256, 0, stream>>>(wqkv, Whqk, 1024 * CC);

  // q,k GEMM: M=16384, N=1024 -> 128 x 8 = 1024 blocks (4/CU)
  k_gemm_t<1, 1><<<1024, 256, 0, stream>>>(Xh, Whqk, nullptr, bqkv, gate, ropem,
                                           nullptr, qT, kT, 8, 0);
  k_ctx_mfma<<<256, 256, 0, stream>>>(qT, kT, ctxp);
  k_ctx_red<<<512, 256, 0, stream>>>(ctxp, ctx);
  k_mproj<<<128, 256, 0, stream>>>(ctx, wproj, Mf);
  k_g2<<<256, 256, 0, stream>>>(Mf, wqkv, G2h, G2l);
  k_beff<<<512, 256, 0, stream>>>(Mf, bqkv, bproj, beff);

  // out GEMM: out = gate*(Xh * G2_b^T) + beff; M=16384, N=512 -> 512 blocks (2/CU)
  k_gemm_t<2, 2><<<512, 256, 0, stream>>>(Xh, G2h, G2l, beff, gate, nullptr,
                                          out, nullptr, nullptr, 4, CC);
}

// Round 10
// 220.861 us; speedup vs baseline: 1.5497x; 1.0259x over previous
//
#include <hip/hip_runtime.h>
#include <hip/hip_bf16.h>
#include <math.h>

constexpr int BB = 4;
constexpr int NN = 4096;
constexpr int CC = 512;
constexpr int HH = 8;
constexpr int DD = 64;
constexpr int NCNT = NN - 2;

typedef __bf16 bf16x8 __attribute__((ext_vector_type(8)));
typedef float f32x4 __attribute__((ext_vector_type(4)));

__device__ __forceinline__ float b2f(ushort u) {
  unsigned v = ((unsigned)u) << 16;
  return __builtin_bit_cast(float, v);
}
__device__ __forceinline__ ushort f2b(float f) {
  __hip_bfloat16 h = __float2bfloat16(f);
  return __builtin_bit_cast(ushort, h);
}
__device__ __forceinline__ void gload16(const ushort* g, ushort* l) {
  __builtin_amdgcn_global_load_lds(
      (const __attribute__((address_space(1))) unsigned int*)g,
      (__attribute__((address_space(3))) unsigned int*)l, 16, 0, 0);
}

// ---------------------------------------------------------------------------
// K1: second-diff sign counts + fused x -> bf16.
// Each (b,tile) block exclusively owns rows [16*tile,16*tile+16) of batch b:
// writes per-batch partial counts pcnt[b][i] -- NO global atomics, NO memset.
// ---------------------------------------------------------------------------
__global__ __launch_bounds__(512) void k_counts_prep(
    const float* __restrict__ x, int* __restrict__ pcntP,
    int* __restrict__ pcntV, ushort* __restrict__ Xh) {
  int b = blockIdx.x >> 8;
  int tile = blockIdx.x & 255;
  int c = threadIdx.x;
  int lane = threadIdx.x & 63;
  int i0 = tile * 16;
  const float* xb = x + (size_t)b * NN * CC + c;

  float v[18];
  #pragma unroll
  for (int r = 0; r < 18; ++r) {
    int i = i0 + r;
    v[r] = xb[(size_t)(i < NN ? i : NN - 1) * CC];  // independent loads
  }

  #pragma unroll
  for (int r = 0; r < 16; ++r)
    Xh[((size_t)b * NN + i0 + r) * CC + c] = f2b(v[r]);

  __shared__ int redP[16], redV[16];
  if (threadIdx.x < 16) { redP[threadIdx.x] = 0; redV[threadIdx.x] = 0; }
  __syncthreads();

  #pragma unroll
  for (int r = 0; r < 16; ++r) {
    int i = i0 + r;
    if (i < NCNT) {  // uniform across block
      float d2 = (v[r + 2] - v[r + 1]) - (v[r + 1] - v[r]);
      unsigned long long mneg = __ballot(d2 < 0.0f);
      unsigned long long mpos = __ballot(d2 > 0.0f);
      if (lane == 0) {
        atomicAdd(&redP[r], __popcll(mneg));
        atomicAdd(&redV[r], __popcll(mpos));
      }
    }
  }
  __syncthreads();
  if (threadIdx.x < 16) {
    int i = i0 + threadIdx.x;
    if (i < NN) {
      pcntP[b * NN + i] = (i < NCNT) ? redP[threadIdx.x] : 0;
      pcntV[b * NN + i] = (i < NCNT) ? redV[threadIdx.x] : 0;
    }
  }
}

// ---------------------------------------------------------------------------
// K2pre: Gaussian tables etab[a] = exp(-(a*iw)^2)
// ---------------------------------------------------------------------------
__global__ void k_etab(const float* __restrict__ lpw, const float* __restrict__ lvw,
                       float* __restrict__ etabP, float* __restrict__ etabV) {
  int i = blockIdx.x * 256 + threadIdx.x;
  float ipw = expf(-lpw[0]);
  float ivw = expf(-lvw[0]);
  float t1 = (float)i * ipw;
  float t2 = (float)i * ivw;
  etabP[i] = expf(-t1 * t1);
  etabV[i] = expf(-t2 * t2);
}

// ---------------------------------------------------------------------------
// K2a: Gaussian sums via tables; counts = sum of 4 per-batch partials
// ---------------------------------------------------------------------------
__global__ void k_gsum(const int* __restrict__ pcntP, const int* __restrict__ pcntV,
                       const float* __restrict__ etabP, const float* __restrict__ etabV,
                       float* __restrict__ attn) {
  int p = blockIdx.x;
  int tid = threadIdx.x;
  float acc = 0.f;
  for (int i = tid; i < NCNT; i += 256) {
    int a = p - 1 - i;
    a = a < 0 ? -a : a;
    int cp = pcntP[i] + pcntP[NN + i] + pcntP[2 * NN + i] + pcntP[3 * NN + i];
    int cv = pcntV[i] + pcntV[NN + i] + pcntV[2 * NN + i] + pcntV[3 * NN + i];
    acc += (float)cp * etabP[a] + (float)cv * etabV[a];
  }
  __shared__ float red[256];
  red[tid] = acc;
  __syncthreads();
  for (int s = 128; s > 0; s >>= 1) {
    if (tid < s) red[tid] += red[tid + s];
    __syncthreads();
  }
  if (tid == 0) attn[p] = red[0];
}

// ---------------------------------------------------------------------------
// K2b: min-max normalize
// ---------------------------------------------------------------------------
__global__ void k_norm(const float* __restrict__ attn, float* __restrict__ gate) {
  int tid = threadIdx.x;  // 1024
  float v0 = attn[tid], v1 = attn[tid + 1024], v2 = attn[tid + 2048], v3 = attn[tid + 3072];
  float mn = fminf(fminf(v0, v1), fminf(v2, v3));
  float mx = fmaxf(fmaxf(v0, v1), fmaxf(v2, v3));
  __shared__ float rmn[1024], rmx[1024];
  rmn[tid] = mn; rmx[tid] = mx;
  __syncthreads();
  for (int s = 512; s > 0; s >>= 1) {
    if (tid < s) {
      rmn[tid] = fminf(rmn[tid], rmn[tid + s]);
      rmx[tid] = fmaxf(rmx[tid], rmx[tid + s]);
    }
    __syncthreads();
  }
  float lo = rmn[0];
  float denom = rmx[0] - rmn[0] + 1e-6f;
  gate[tid]        = (v0 - lo) / denom;
  gate[tid + 1024] = (v1 - lo) / denom;
  gate[tid + 2048] = (v2 - lo) / denom;
  gate[tid + 3072] = (v3 - lo) / denom;
}

// ---------------------------------------------------------------------------
// K3a: spectral PE conv path -> pe2 [64][4096]
// ---------------------------------------------------------------------------
__global__ void k_pe(const float* __restrict__ omega,
                     const float* __restrict__ w1, const float* __restrict__ b1,
                     const float* __restrict__ w2, const float* __restrict__ b2,
                     float* __restrict__ pe2) {
  int n = blockIdx.x;
  int j = threadIdx.x;  // 64
  __shared__ float pec[3][64];
  __shared__ float hs[128];
  for (int t = 0; t < 3; ++t) {
    int m = n + t - 1;
    float v = 0.f;
    if (m >= 0 && m < NN) {
      int l1 = m >> 6, l2 = m & 63;
      float rel = (float)(l1 - l2);
      v = (j < 32) ? sinf(rel * omega[j]) : cosf(rel * omega[j - 32]);
    }
    pec[t][j] = v;
  }
  __syncthreads();
  for (int o = j; o < 128; o += 64) {
    int ci = o >> 1;
    float hv = b1[o];
    #pragma unroll
    for (int t = 0; t < 3; ++t) hv += pec[t][ci] * w1[o * 3 + t];
    hv = 0.5f * hv * (1.f + erff(hv * 0.70710678118654752f));
    hs[o] = hv;
  }
  __syncthreads();
  float acc = b2[j];
  for (int o = 0; o < 128; ++o) acc += hs[o] * w2[j * 128 + o];
  pe2[(size_t)j * NN + n] = acc;
}

// ---------------------------------------------------------------------------
// K3b: channel means -> sigmoid gate gpe[64]
// ---------------------------------------------------------------------------
__global__ void k_gatepe(const float* __restrict__ pe2,
                         const float* __restrict__ wg, const float* __restrict__ bg,
                         float* __restrict__ gpe) {
  int tid = threadIdx.x;  // 256
  int j = tid & 63, part = tid >> 6;
  float s = 0.f;
  const float* row = pe2 + (size_t)j * NN + part * 1024;
  for (int t = 0; t < 1024; ++t) s += row[t];
  __shared__ float ps[4][64];
  __shared__ float mean[64];
  ps[part][j] = s;
  __syncthreads();
  if (tid < 64) mean[j] = (ps[0][j] + ps[1][j] + ps[2][j] + ps[3][j]) * (1.f / 4096.f);
  __syncthreads();
  if (tid < 64) {
    float g = bg[j];
    for (int k2 = 0; k2 < 64; ++k2) g += wg[j * 64 + k2] * mean[k2];
    gpe[j] = 1.f / (1.f + expf(-g));
  }
}

// ---------------------------------------------------------------------------
// K3c: rope multiplier
// ---------------------------------------------------------------------------
__global__ void k_ropemul(const float* __restrict__ pe2, const float* __restrict__ gpe,
                          float* __restrict__ ropem) {
  int idx = blockIdx.x * 256 + threadIdx.x;
  int n = idx >> 6, dd = idx & 63;
  ropem[idx] = 1.f + pe2[(size_t)dd * NN + n] * gpe[n >> 6] * 0.35355339059327373f;
}

// Prep: f32 -> bf16 (weights)
__global__ void k_prep_h(const float* __restrict__ src,
                         ushort* __restrict__ Sh, int nelem) {
  int idx4 = (blockIdx.x * 256 + threadIdx.x) * 4;
  if (idx4 >= nelem) return;
  float4 v = *(const float4*)&src[idx4];
  ushort4 h;
  ((ushort*)&h)[0] = f2b(v.x);
  ((ushort*)&h)[1] = f2b(v.y);
  ((ushort*)&h)[2] = f2b(v.z);
  ((ushort*)&h)[3] = f2b(v.w);
  *(ushort4*)&Sh[idx4] = h;
}

// ---------------------------------------------------------------------------
// Plain double-buffered bf16 MFMA GEMM (m97-style, NO inline asm).
// 128x128 tile, BK=32, 4 waves (2x2), 2 LDS buffers, one __syncthreads/step.
// EPI=1: qk epilogue (gate, elu+1, rope; q/k TRANSPOSED [bh][d][n], packed).
// EPI=2: out epilogue (gate*acc + beff[b][col], f32 out, per-batch B).
// ---------------------------------------------------------------------------
template <int BTERMS, int EPI>
__global__ __launch_bounds__(256) void k_gemm_t(
    const ushort* __restrict__ Ag, const ushort* __restrict__ Bgh,
    const ushort* __restrict__ Bgl,
    const float* __restrict__ bias, const float* __restrict__ gate,
    const float* __restrict__ ropem,
    float* __restrict__ outF, ushort* __restrict__ qT, ushort* __restrict__ kT,
    int ntn, int ncols) {
  const int nwg = gridDim.x;
  const int hw = blockIdx.x;
  const int logical = (hw & 7) * (nwg >> 3) + (hw >> 3);
  const int m0 = (logical / ntn) * 128, n0 = (logical % ntn) * 128;

  const int tid = threadIdx.x, wave = tid >> 6, lane = tid & 63;
  const int wm = wave >> 1, wn = wave & 1;
  __shared__ ushort sA[2][4096];
  __shared__ ushort sB[2][BTERMS * 4096];
  f32x4 acc[4][4] = {};

  const int lr = lane >> 2;
  const int ci = lane & 3;
  const int scol = (ci ^ ((lr >> 1) & 3)) * 8;           // inverse-swz source col
  const int rA = lane & 15;
  const int cswz = ((lane >> 4) ^ ((rA >> 1) & 3)) * 8;  // read-side swizzle

  const int chunk0 = wave * 2, chunk1 = wave * 2 + 1;
  const int row0 = chunk0 * 16 + lr, row1 = chunk1 * 16 + lr;

  const ushort* Bh_ = Bgh + (EPI == 2 ? (size_t)(m0 >> 12) * 262144 : 0);
  const ushort* Bl_ = (BTERMS == 2)
      ? (Bgl + (EPI == 2 ? (size_t)(m0 >> 12) * 262144 : 0)) : nullptr;

#define STAGE(T, S)                                                        \
  {                                                                        \
    const int k0s = (T) * 32;                                              \
    size_t ga0 = (size_t)(m0 + row0) * CC + k0s + scol;                    \
    size_t ga1 = (size_t)(m0 + row1) * CC + k0s + scol;                    \
    size_t gb0 = (size_t)(n0 + row0) * CC + k0s + scol;                    \
    size_t gb1 = (size_t)(n0 + row1) * CC + k0s + scol;                    \
    gload16(Ag + ga0, &sA[S][chunk0 * 512]);                               \
    gload16(Ag + ga1, &sA[S][chunk1 * 512]);                               \
    gload16(Bh_ + gb0, &sB[S][chunk0 * 512]);                              \
    gload16(Bh_ + gb1, &sB[S][chunk1 * 512]);                              \
    if (BTERMS == 2) {                                                     \
      gload16(Bl_ + gb0, &sB[S][4096 + chunk0 * 512]);                     \
      gload16(Bl_ + gb1, &sB[S][4096 + chunk1 * 512]);                     \
    }                                                                      \
  }

  STAGE(0, 0);
  __syncthreads();  // tile 0 landed (vmcnt drained by barrier)

  for (int t = 0; t < 16; ++t) {
    if (t < 15) STAGE(t + 1, (t + 1) & 1);  // issue early; lands by barrier
    const int cur = t & 1;
    bf16x8 af[4], bh[4], bl[4];
    #pragma unroll
    for (int m = 0; m < 4; ++m)
      af[m] = *(const bf16x8*)(&sA[cur][(wm * 64 + m * 16 + rA) * 32 + cswz]);
    #pragma unroll
    for (int n = 0; n < 4; ++n) {
      int off = (wn * 64 + n * 16 + rA) * 32 + cswz;
      bh[n] = *(const bf16x8*)(&sB[cur][off]);
      if (BTERMS == 2) bl[n] = *(const bf16x8*)(&sB[cur][4096 + off]);
    }
    #pragma unroll
    for (int m = 0; m < 4; ++m)
      #pragma unroll
      for (int n = 0; n < 4; ++n) {
        acc[m][n] = __builtin_amdgcn_mfma_f32_16x16x32_bf16(af[m], bh[n], acc[m][n], 0, 0, 0);
        if (BTERMS == 2)
          acc[m][n] = __builtin_amdgcn_mfma_f32_16x16x32_bf16(af[m], bl[n], acc[m][n], 0, 0, 0);
      }
    __syncthreads();  // next tile landed; this tile's reads done
  }
#undef STAGE

  const int kj = lane >> 4, l15 = lane & 15;
  #pragma unroll
  for (int m = 0; m < 4; ++m) {
    #pragma unroll
    for (int n = 0; n < 4; ++n) {
      if (EPI == 2) {
        #pragma unroll
        for (int r = 0; r < 4; ++r) {
          int row = m0 + wm * 64 + m * 16 + kj * 4 + r;
          int col = n0 + wn * 64 + n * 16 + l15;
          int nseq = row & (NN - 1), b = row >> 12;
          float val = acc[m][n][r] * gate[nseq] + bias[b * 512 + col];
          outF[(size_t)row * ncols + col] = val;
        }
      } else {
        // packed qT/kT store: 4 consecutive nseq at fixed channel
        int rowb = m0 + wm * 64 + m * 16 + kj * 4;
        int col = n0 + wn * 64 + n * 16 + l15;
        int nseqb = rowb & (NN - 1), b = rowb >> 12;
        int part = col >> 9, h = (col >> 6) & 7, dd = col & 63;
        ushort4 pk;
        #pragma unroll
        for (int r = 0; r < 4; ++r) {
          int nseq = nseqb + r;
          float val = acc[m][n][r] * gate[nseq] + bias[col];
          float e = val > 0.f ? val + 1.f : expf(val);  // elu+1
          ((ushort*)&pk)[r] = f2b(e * ropem[nseq * 64 + dd]);
        }
        ushort* dst = (part == 0 ? qT : kT) +
                      ((size_t)(b * HH + h) * DD + dd) * NN + nseqb;
        *(ushort4*)dst = pk;
      }
    }
  }
}

// ---------------------------------------------------------------------------
// K5a: ctx via MFMA straight from global. qT/kT: [bh][64 d][4096 n] bf16.
// ---------------------------------------------------------------------------
__global__ __launch_bounds__(256) void k_ctx_mfma(
    const ushort* __restrict__ qT, const ushort* __restrict__ kT,
    float* __restrict__ ctxp) {
  int blk = blockIdx.x;
  int bh = blk >> 3, chunk = blk & 7;
  int wave = threadIdx.x >> 6, lane = threadIdx.x & 63;
  int l15 = lane & 15, kj = lane >> 4;
  const size_t base = (size_t)bh * DD * NN;
  const int n0 = chunk * 512 + wave * 128;
  f32x4 acc[4][4] = {};
  for (int ks = 0; ks < 4; ++ks) {
    const int nb = n0 + ks * 32 + kj * 8;
    bf16x8 qa[4], ka[4];
    #pragma unroll
    for (int m = 0; m < 4; ++m)
      qa[m] = *(const bf16x8*)(qT + base + (size_t)(m * 16 + l15) * NN + nb);
    #pragma unroll
    for (int n = 0; n < 4; ++n)
      ka[n] = *(const bf16x8*)(kT + base + (size_t)(n * 16 + l15) * NN + nb);
    #pragma unroll
    for (int m = 0; m < 4; ++m)
      #pragma unroll
      for (int n = 0; n < 4; ++n)
        acc[m][n] = __builtin_amdgcn_mfma_f32_16x16x32_bf16(qa[m], ka[n], acc[m][n], 0, 0, 0);
  }
  const float scale = 1.f / 512.f;
  float* dst = ctxp + ((size_t)bh * 32 + chunk * 4 + wave) * 4096;
  #pragma unroll
  for (int m = 0; m < 4; ++m)
    #pragma unroll
    for (int n = 0; n < 4; ++n)
      #pragma unroll
      for (int r = 0; r < 4; ++r)
        dst[(m * 16 + kj * 4 + r) * 64 + n * 16 + l15] = acc[m][n][r] * scale;
}

// K5b: parallel deterministic reduce of 32 partials -> ctx[bh][64][64]
__global__ void k_ctx_red(const float* __restrict__ ctxp, float* __restrict__ ctx) {
  int idx = blockIdx.x * 256 + threadIdx.x;  // 0..131071
  int bh = idx >> 12, off = idx & 4095;
  float s = 0.f;
  #pragma unroll
  for (int c2 = 0; c2 < 32; ++c2)
    s += ctxp[((size_t)bh * 32 + c2) * 4096 + off];
  ctx[idx] = s;
}

// ---------------------------------------------------------------------------
// K6: Mf[b][o][h*64+d] = (1/512) * sum_e ctx[b,h,d,e] * wp[o, h*64+e]  (f32)
// ---------------------------------------------------------------------------
__global__ __launch_bounds__(256) void k_mproj(
    const float* __restrict__ ctx, const float* __restrict__ wp,
    float* __restrict__ Mf) {
  int blk = blockIdx.x;
  int b = blk >> 5, h = (blk >> 2) & 7, oq = blk & 3;
  int tid = threadIdx.x;
  int o = oq * 128 + (tid & 127);
  int d0 = (tid >> 7) * 32;
  __shared__ float cs[64][64];
  #pragma unroll
  for (int it = 0; it < 4; ++it) {
    int idx = (tid + 256 * it) * 4;
    *(float4*)&cs[idx >> 6][idx & 63] =
        *(const float4*)&ctx[(size_t)(b * 8 + h) * 4096 + idx];
  }
  __syncthreads();
  float wv[64];
  #pragma unroll
  for (int e = 0; e < 64; ++e) wv[e] = wp[(size_t)o * 512 + h * 64 + e];
  for (int d = d0; d < d0 + 32; ++d) {
    float s = 0.f;
    #pragma unroll
    for (int e = 0; e < 64; ++e) s += cs[d][e] * wv[e];
    Mf[((size_t)b * 512 + o) * 512 + h * 64 + d] = s * (1.f / 512.f);
  }
}

// ---------------------------------------------------------------------------
// K7: G2[b][o][c] = sum_{c'} Mf[b][o][c'] * Wv[c'][c]  (bf16 hi only)
// ---------------------------------------------------------------------------
__global__ __launch_bounds__(256) void k_g2(
    const float* __restrict__ Mf, const float* __restrict__ wqkv,
    ushort* __restrict__ G2h) {
  int blk = blockIdx.x;
  int b = blk >> 6, ot = (blk >> 3) & 7, ct = blk & 7;
  int tx = threadIdx.x & 15, ty = threadIdx.x >> 4;
  __shared__ float As[32][65], Ws[32][65];
  float acc[4][4] = {};
  const float* Mb = Mf + (size_t)b * 262144;
  for (int k0 = 0; k0 < 512; k0 += 32) {
    #pragma unroll
    for (int it = 0; it < 8; ++it) {
      int e = threadIdx.x + 256 * it;  // 2048
      int m = e >> 5, kk = e & 31;
      As[kk][m] = Mb[(size_t)(ot * 64 + m) * 512 + k0 + kk];
      int kk2 = e >> 6, cc = e & 63;
      Ws[kk2][cc] = wqkv[(size_t)(1024 + k0 + kk2) * 512 + ct * 64 + cc];
    }
    __syncthreads();
    #pragma unroll
    for (int kk = 0; kk < 32; ++kk) {
      float a[4], wv[4];
      #pragma unroll
      for (int i = 0; i < 4; ++i) a[i] = As[kk][ty + 16 * i];
      #pragma unroll
      for (int j = 0; j < 4; ++j) wv[j] = Ws[kk][tx + 16 * j];
      #pragma unroll
      for (int i = 0; i < 4; ++i)
        #pragma unroll
        for (int j = 0; j < 4; ++j) acc[i][j] += a[i] * wv[j];
    }
    __syncthreads();
  }
  #pragma unroll
  for (int i = 0; i < 4; ++i)
    #pragma unroll
    for (int j = 0; j < 4; ++j) {
      size_t idx = ((size_t)b * 512 + ot * 64 + ty + 16 * i) * 512 + ct * 64 + tx + 16 * j;
      G2h[idx] = f2b(acc[i][j]);
    }
}

// K8: beff[b][o] = sum_{c'} bqkv[1024+c'] * Mf[b][o][c'] + bproj[o]
__global__ void k_beff(const float* __restrict__ Mf, const float* __restrict__ bqkv,
                       const float* __restrict__ bproj, float* __restrict__ beff) {
  int w = threadIdx.x >> 6, lane = threadIdx.x & 63;
  int t = blockIdx.x * 4 + w;  // 0..2047
  int b = t >> 9, o = t & 511;
  const float* row = Mf + ((size_t)b * 512 + o) * 512;
  float s = 0.f;
  #pragma unroll
  for (int c = 0; c < 512; c += 64) s += bqkv[1024 + c + lane] * row[c + lane];
  #pragma unroll
  for (int off = 32; off > 0; off >>= 1) s += __shfl_down(s, off);
  if (lane == 0) beff[t] = s + bproj[o];
}

// ---------------------------------------------------------------------------
extern "C" void kernel_launch(void* const* d_in, const int* in_sizes, int n_in,
                              void* d_out, int out_size, void* d_ws, size_t ws_size,
                              hipStream_t stream) {
  const float* x    = (const float*)d_in[0];
  const float* lpw  = (const float*)d_in[1];
  const float* lvw  = (const float*)d_in[2];
  const float* wqkv = (const float*)d_in[3];
  const float* bqkv = (const float*)d_in[4];
  const float* wproj= (const float*)d_in[5];
  const float* bproj= (const float*)d_in[6];
  const float* omega= (const float*)d_in[7];
  const float* w1   = (const float*)d_in[8];
  const float* b1   = (const float*)d_in[9];
  const float* w2   = (const float*)d_in[10];
  const float* b2   = (const float*)d_in[11];
  const float* wg   = (const float*)d_in[12];
  const float* bg   = (const float*)d_in[13];
  float* out = (float*)d_out;

  constexpr size_t MB = 1024 * 1024;
  char* w = (char*)d_ws;
  int*   pcntP  = (int*)(w);                      // 64 KiB [4][4096]
  int*   pcntV  = (int*)(w + 64 * 1024);          // 64 KiB
  float* attn   = (float*)(w + 128 * 1024);
  float* gate   = (float*)(w + 144 * 1024);
  float* pe2    = (float*)(w + 160 * 1024);       // 1 MiB
  float* gpe    = (float*)(w + 1184 * 1024);
  float* ropem  = (float*)(w + 1248 * 1024);      // 1 MiB
  float* etabP  = (float*)(w + 2272 * 1024);
  float* etabV  = (float*)(w + 2288 * 1024);
  ushort* Xh    = (ushort*)(w + 4 * MB);          // 16 MiB bf16 [B*N, C]
  ushort* qT    = (ushort*)(w + 20 * MB);         // 16 MiB bf16 [B,H,D,N]
  ushort* kT    = (ushort*)(w + 36 * MB);         // 16 MiB
  ushort* Whqk  = (ushort*)(w + 52 * MB);         // 1 MiB (q,k weights bf16)
  float* Mf     = (float*)(w + 53 * MB);          // 4 MiB f32 [B][512][512]
  ushort* G2h   = (ushort*)(w + 57 * MB);         // 2 MiB
  float* beff   = (float*)(w + 59 * MB);          // 8 KiB
  float* ctxp   = (float*)(w + 60 * MB);          // 16 MiB
  float* ctx    = (float*)(w + 76 * MB);          // 0.5 MiB -> 76.5 MiB total

  k_counts_prep<<<BB * 256, 512, 0, stream>>>(x, pcntP, pcntV, Xh);
  k_etab<<<16, 256, 0, stream>>>(lpw, lvw, etabP, etabV);
  k_gsum<<<NN, 256, 0, stream>>>(pcntP, pcntV, etabP, etabV, attn);
  k_norm<<<1, 1024, 0, stream>>>(attn, gate);
  k_pe<<<NN, 64, 0, stream>>>(omega, w1, b1, w2, b2, pe2);
  k_gatepe<<<1, 256, 0, stream>>>(pe2, wg, bg, gpe);
  k_ropemul<<<1024, 256, 0, stream>>>(pe2, gpe, ropem);
  k_prep_h<<<512, 256, 0, stream>>>(wqkv, Whqk, 1024 * CC);

  // q,k GEMM: M=16384, N=1024 -> 1024 blocks (4/CU)
  k_gemm_t<1, 1><<<1024, 256, 0, stream>>>(Xh, Whqk, nullptr, bqkv, gate, ropem,
                                           nullptr, qT, kT, 8, 0);
  k_ctx_mfma<<<256, 256, 0, stream>>>(qT, kT, ctxp);
  k_ctx_red<<<512, 256, 0, stream>>>(ctxp, ctx);
  k_mproj<<<128, 256, 0, stream>>>(ctx, wproj, Mf);
  k_g2<<<256, 256, 0, stream>>>(Mf, wqkv, G2h);
  k_beff<<<512, 256, 0, stream>>>(Mf, bqkv, bproj, beff);

  // out GEMM: out = gate*(Xh * G2_b^T) + beff; M=16384, N=512 -> 512 blocks
  k_gemm_t<1, 2><<<512, 256, 0, stream>>>(Xh, G2h, nullptr, beff, gate, nullptr,
                                          out, nullptr, nullptr, 4, CC);
}

// Round 11
// 190.511 us; speedup vs baseline: 1.7965x; 1.1593x over previous
//
#include <hip/hip_runtime.h>
#include <hip/hip_bf16.h>
#include <math.h>

constexpr int BB = 4;
constexpr int NN = 4096;
constexpr int CC = 512;
constexpr int HH = 8;
constexpr int DD = 64;
constexpr int NCNT = NN - 2;

typedef __bf16 bf16x8 __attribute__((ext_vector_type(8)));
typedef float f32x4 __attribute__((ext_vector_type(4)));

__device__ __forceinline__ float b2f(ushort u) {
  unsigned v = ((unsigned)u) << 16;
  return __builtin_bit_cast(float, v);
}
__device__ __forceinline__ ushort f2b(float f) {
  __hip_bfloat16 h = __float2bfloat16(f);
  return __builtin_bit_cast(ushort, h);
}
__device__ __forceinline__ void gload16(const ushort* g, ushort* l) {
  __builtin_amdgcn_global_load_lds(
      (const __attribute__((address_space(1))) unsigned int*)g,
      (__attribute__((address_space(3))) unsigned int*)l, 16, 0, 0);
}

// ---------------------------------------------------------------------------
// K1: second-diff sign counts + fused x -> bf16 (per-batch partials, no atomics)
// ---------------------------------------------------------------------------
__global__ __launch_bounds__(512) void k_counts_prep(
    const float* __restrict__ x, int* __restrict__ pcntP,
    int* __restrict__ pcntV, ushort* __restrict__ Xh) {
  int b = blockIdx.x >> 8;
  int tile = blockIdx.x & 255;
  int c = threadIdx.x;
  int lane = threadIdx.x & 63;
  int i0 = tile * 16;
  const float* xb = x + (size_t)b * NN * CC + c;

  float v[18];
  #pragma unroll
  for (int r = 0; r < 18; ++r) {
    int i = i0 + r;
    v[r] = xb[(size_t)(i < NN ? i : NN - 1) * CC];  // independent loads
  }

  #pragma unroll
  for (int r = 0; r < 16; ++r)
    Xh[((size_t)b * NN + i0 + r) * CC + c] = f2b(v[r]);

  __shared__ int redP[16], redV[16];
  if (threadIdx.x < 16) { redP[threadIdx.x] = 0; redV[threadIdx.x] = 0; }
  __syncthreads();

  #pragma unroll
  for (int r = 0; r < 16; ++r) {
    int i = i0 + r;
    if (i < NCNT) {
      float d2 = (v[r + 2] - v[r + 1]) - (v[r + 1] - v[r]);
      unsigned long long mneg = __ballot(d2 < 0.0f);
      unsigned long long mpos = __ballot(d2 > 0.0f);
      if (lane == 0) {
        atomicAdd(&redP[r], __popcll(mneg));
        atomicAdd(&redV[r], __popcll(mpos));
      }
    }
  }
  __syncthreads();
  if (threadIdx.x < 16) {
    int i = i0 + threadIdx.x;
    pcntP[b * NN + i] = (i < NCNT) ? redP[threadIdx.x] : 0;
    pcntV[b * NN + i] = (i < NCNT) ? redV[threadIdx.x] : 0;
  }
}

// ---------------------------------------------------------------------------
// K2pre: exp tables + batch-summed float counts (one pass)
// ---------------------------------------------------------------------------
__global__ void k_etab2(const float* __restrict__ lpw, const float* __restrict__ lvw,
                        const int* __restrict__ pcntP, const int* __restrict__ pcntV,
                        float* __restrict__ etabP, float* __restrict__ etabV,
                        float* __restrict__ fcntP, float* __restrict__ fcntV) {
  int i = blockIdx.x * 256 + threadIdx.x;  // 0..4095
  float ipw = expf(-lpw[0]);
  float ivw = expf(-lvw[0]);
  float t1 = (float)i * ipw;
  float t2 = (float)i * ivw;
  etabP[i] = expf(-t1 * t1);
  etabV[i] = expf(-t2 * t2);
  fcntP[i] = (float)(pcntP[i] + pcntP[NN + i] + pcntP[2 * NN + i] + pcntP[3 * NN + i]);
  fcntV[i] = (float)(pcntV[i] + pcntV[NN + i] + pcntV[2 * NN + i] + pcntV[3 * NN + i]);
}

// ---------------------------------------------------------------------------
// K2a: Gaussian sums via tables (float counts)
// ---------------------------------------------------------------------------
__global__ void k_gsum(const float* __restrict__ fcntP, const float* __restrict__ fcntV,
                       const float* __restrict__ etabP, const float* __restrict__ etabV,
                       float* __restrict__ attn) {
  int p = blockIdx.x;
  int tid = threadIdx.x;
  float acc = 0.f;
  for (int i = tid; i < NCNT; i += 256) {
    int a = p - 1 - i;
    a = a < 0 ? -a : a;
    acc += fcntP[i] * etabP[a] + fcntV[i] * etabV[a];
  }
  __shared__ float red[256];
  red[tid] = acc;
  __syncthreads();
  for (int s = 128; s > 0; s >>= 1) {
    if (tid < s) red[tid] += red[tid + s];
    __syncthreads();
  }
  if (tid == 0) attn[p] = red[0];
}

// ---------------------------------------------------------------------------
// K2b: min-max normalize
// ---------------------------------------------------------------------------
__global__ void k_norm(const float* __restrict__ attn, float* __restrict__ gate) {
  int tid = threadIdx.x;  // 1024
  float v0 = attn[tid], v1 = attn[tid + 1024], v2 = attn[tid + 2048], v3 = attn[tid + 3072];
  float mn = fminf(fminf(v0, v1), fminf(v2, v3));
  float mx = fmaxf(fmaxf(v0, v1), fmaxf(v2, v3));
  __shared__ float rmn[1024], rmx[1024];
  rmn[tid] = mn; rmx[tid] = mx;
  __syncthreads();
  for (int s = 512; s > 0; s >>= 1) {
    if (tid < s) {
      rmn[tid] = fminf(rmn[tid], rmn[tid + s]);
      rmx[tid] = fmaxf(rmx[tid], rmx[tid + s]);
    }
    __syncthreads();
  }
  float lo = rmn[0];
  float denom = rmx[0] - rmn[0] + 1e-6f;
  gate[tid]        = (v0 - lo) / denom;
  gate[tid + 1024] = (v1 - lo) / denom;
  gate[tid + 2048] = (v2 - lo) / denom;
  gate[tid + 3072] = (v3 - lo) / denom;
}

// ---------------------------------------------------------------------------
// K3a: spectral PE conv path -> pe2 [64][4096]; 4 positions per 256-thr block
// ---------------------------------------------------------------------------
__global__ __launch_bounds__(256) void k_pe(
    const float* __restrict__ omega,
    const float* __restrict__ w1, const float* __restrict__ b1,
    const float* __restrict__ w2, const float* __restrict__ b2,
    float* __restrict__ pe2) {
  int g = threadIdx.x >> 6;   // group 0..3
  int j = threadIdx.x & 63;
  int n = blockIdx.x * 4 + g;
  __shared__ float pec[4][3][64];
  __shared__ float hs[4][128];
  for (int t = 0; t < 3; ++t) {
    int m = n + t - 1;
    float v = 0.f;
    if (m >= 0 && m < NN) {
      int l1 = m >> 6, l2 = m & 63;
      float rel = (float)(l1 - l2);
      v = (j < 32) ? sinf(rel * omega[j]) : cosf(rel * omega[j - 32]);
    }
    pec[g][t][j] = v;
  }
  __syncthreads();
  for (int o = j; o < 128; o += 64) {
    int ci = o >> 1;
    float hv = b1[o];
    #pragma unroll
    for (int t = 0; t < 3; ++t) hv += pec[g][t][ci] * w1[o * 3 + t];
    hv = 0.5f * hv * (1.f + erff(hv * 0.70710678118654752f));
    hs[g][o] = hv;
  }
  __syncthreads();
  float acc = b2[j];
  for (int o = 0; o < 128; ++o) acc += hs[g][o] * w2[j * 128 + o];
  pe2[(size_t)j * NN + n] = acc;
}

// ---------------------------------------------------------------------------
// K3b: channel means -> sigmoid gate gpe[64]
// ---------------------------------------------------------------------------
__global__ void k_gatepe(const float* __restrict__ pe2,
                         const float* __restrict__ wg, const float* __restrict__ bg,
                         float* __restrict__ gpe) {
  int tid = threadIdx.x;  // 256
  int j = tid & 63, part = tid >> 6;
  float s = 0.f;
  const float* row = pe2 + (size_t)j * NN + part * 1024;
  for (int t = 0; t < 1024; ++t) s += row[t];
  __shared__ float ps[4][64];
  __shared__ float mean[64];
  ps[part][j] = s;
  __syncthreads();
  if (tid < 64) mean[j] = (ps[0][j] + ps[1][j] + ps[2][j] + ps[3][j]) * (1.f / 4096.f);
  __syncthreads();
  if (tid < 64) {
    float g = bg[j];
    for (int k2 = 0; k2 < 64; ++k2) g += wg[j * 64 + k2] * mean[k2];
    gpe[j] = 1.f / (1.f + expf(-g));
  }
}

// ---------------------------------------------------------------------------
// K3c: rope multiplier
// ---------------------------------------------------------------------------
__global__ void k_ropemul(const float* __restrict__ pe2, const float* __restrict__ gpe,
                          float* __restrict__ ropem) {
  int idx = blockIdx.x * 256 + threadIdx.x;
  int n = idx >> 6, dd = idx & 63;
  ropem[idx] = 1.f + pe2[(size_t)dd * NN + n] * gpe[n >> 6] * 0.35355339059327373f;
}

// Prep: f32 -> bf16 (weights, hi only)
__global__ void k_prep_h(const float* __restrict__ src,
                         ushort* __restrict__ Sh, int nelem) {
  int idx4 = (blockIdx.x * 256 + threadIdx.x) * 4;
  if (idx4 >= nelem) return;
  float4 v = *(const float4*)&src[idx4];
  ushort4 h;
  ((ushort*)&h)[0] = f2b(v.x);
  ((ushort*)&h)[1] = f2b(v.y);
  ((ushort*)&h)[2] = f2b(v.z);
  ((ushort*)&h)[3] = f2b(v.w);
  *(ushort4*)&Sh[idx4] = h;
}

// ---------------------------------------------------------------------------
// Prep: Wv^T (wqkv rows 1024..1535 transposed) -> bf16 hi/lo [512 c][512 c']
// ---------------------------------------------------------------------------
__global__ __launch_bounds__(256) void k_prep_wvt(const float* __restrict__ wqkv,
                                                  ushort* __restrict__ Wvth,
                                                  ushort* __restrict__ Wvtl) {
  int bx = blockIdx.x & 7;   // c tile
  int by = blockIdx.x >> 3;  // c' tile
  __shared__ float t[64][65];
  int tid = threadIdx.x;
  #pragma unroll
  for (int it = 0; it < 4; ++it) {
    int idx = tid + it * 256;
    int r = idx >> 4;            // c' local
    int c4 = (idx & 15) * 4;     // c local
    float4 v = *(const float4*)&wqkv[(size_t)(1024 + by * 64 + r) * 512 + bx * 64 + c4];
    t[r][c4] = v.x; t[r][c4 + 1] = v.y; t[r][c4 + 2] = v.z; t[r][c4 + 3] = v.w;
  }
  __syncthreads();
  #pragma unroll
  for (int it = 0; it < 4; ++it) {
    int idx = tid + it * 256;
    int r = idx >> 4;            // c local (output row)
    int c4 = (idx & 15) * 4;     // c' local
    ushort4 h4, l4;
    #pragma unroll
    for (int q = 0; q < 4; ++q) {
      float v = t[c4 + q][r];
      ushort hi = f2b(v);
      ((ushort*)&h4)[q] = hi;
      ((ushort*)&l4)[q] = f2b(v - b2f(hi));
    }
    size_t o = (size_t)(bx * 64 + r) * 512 + by * 64 + c4;
    *(ushort4*)&Wvth[o] = h4;
    *(ushort4*)&Wvtl[o] = l4;
  }
}

// ---------------------------------------------------------------------------
// Plain double-buffered bf16 MFMA GEMM (m97-style).
// EPI=1: qk epilogue. EPI=2: out epilogue (f32, per-batch B). EPI=3: bf16 out.
// ---------------------------------------------------------------------------
template <int BTERMS, int EPI>
__global__ __launch_bounds__(256) void k_gemm_t(
    const ushort* __restrict__ Ag, const ushort* __restrict__ Bgh,
    const ushort* __restrict__ Bgl,
    const float* __restrict__ bias, const float* __restrict__ gate,
    const float* __restrict__ ropem,
    float* __restrict__ outF, ushort* __restrict__ qT, ushort* __restrict__ kT,
    int ntn, int ncols) {
  const int nwg = gridDim.x;
  const int hw = blockIdx.x;
  const int logical = (hw & 7) * (nwg >> 3) + (hw >> 3);
  const int m0 = (logical / ntn) * 128, n0 = (logical % ntn) * 128;

  const int tid = threadIdx.x, wave = tid >> 6, lane = tid & 63;
  const int wm = wave >> 1, wn = wave & 1;
  __shared__ ushort sA[2][4096];
  __shared__ ushort sB[2][BTERMS * 4096];
  f32x4 acc[4][4] = {};

  const int lr = lane >> 2;
  const int ci = lane & 3;
  const int scol = (ci ^ ((lr >> 1) & 3)) * 8;           // inverse-swz source col
  const int rA = lane & 15;
  const int cswz = ((lane >> 4) ^ ((rA >> 1) & 3)) * 8;  // read-side swizzle

  const int chunk0 = wave * 2, chunk1 = wave * 2 + 1;
  const int row0 = chunk0 * 16 + lr, row1 = chunk1 * 16 + lr;

  const ushort* Bh_ = Bgh + (EPI == 2 ? (size_t)(m0 >> 12) * 262144 : 0);
  const ushort* Bl_ = (BTERMS == 2)
      ? (Bgl + (EPI == 2 ? (size_t)(m0 >> 12) * 262144 : 0)) : nullptr;

#define STAGE(T, S)                                                        \
  {                                                                        \
    const int k0s = (T) * 32;                                              \
    size_t ga0 = (size_t)(m0 + row0) * CC + k0s + scol;                    \
    size_t ga1 = (size_t)(m0 + row1) * CC + k0s + scol;                    \
    size_t gb0 = (size_t)(n0 + row0) * CC + k0s + scol;                    \
    size_t gb1 = (size_t)(n0 + row1) * CC + k0s + scol;                    \
    gload16(Ag + ga0, &sA[S][chunk0 * 512]);                               \
    gload16(Ag + ga1, &sA[S][chunk1 * 512]);                               \
    gload16(Bh_ + gb0, &sB[S][chunk0 * 512]);                              \
    gload16(Bh_ + gb1, &sB[S][chunk1 * 512]);                              \
    if (BTERMS == 2) {                                                     \
      gload16(Bl_ + gb0, &sB[S][4096 + chunk0 * 512]);                     \
      gload16(Bl_ + gb1, &sB[S][4096 + chunk1 * 512]);                     \
    }                                                                      \
  }

  STAGE(0, 0);
  __syncthreads();

  for (int t = 0; t < 16; ++t) {
    if (t < 15) STAGE(t + 1, (t + 1) & 1);
    const int cur = t & 1;
    bf16x8 af[4], bh[4], bl[4];
    #pragma unroll
    for (int m = 0; m < 4; ++m)
      af[m] = *(const bf16x8*)(&sA[cur][(wm * 64 + m * 16 + rA) * 32 + cswz]);
    #pragma unroll
    for (int n = 0; n < 4; ++n) {
      int off = (wn * 64 + n * 16 + rA) * 32 + cswz;
      bh[n] = *(const bf16x8*)(&sB[cur][off]);
      if (BTERMS == 2) bl[n] = *(const bf16x8*)(&sB[cur][4096 + off]);
    }
    #pragma unroll
    for (int m = 0; m < 4; ++m)
      #pragma unroll
      for (int n = 0; n < 4; ++n) {
        acc[m][n] = __builtin_amdgcn_mfma_f32_16x16x32_bf16(af[m], bh[n], acc[m][n], 0, 0, 0);
        if (BTERMS == 2)
          acc[m][n] = __builtin_amdgcn_mfma_f32_16x16x32_bf16(af[m], bl[n], acc[m][n], 0, 0, 0);
      }
    __syncthreads();
  }
#undef STAGE

  const int kj = lane >> 4, l15 = lane & 15;
  #pragma unroll
  for (int m = 0; m < 4; ++m) {
    #pragma unroll
    for (int n = 0; n < 4; ++n) {
      if (EPI == 2) {
        #pragma unroll
        for (int r = 0; r < 4; ++r) {
          int row = m0 + wm * 64 + m * 16 + kj * 4 + r;
          int col = n0 + wn * 64 + n * 16 + l15;
          int nseq = row & (NN - 1), b = row >> 12;
          float val = acc[m][n][r] * gate[nseq] + bias[b * 512 + col];
          outF[(size_t)row * ncols + col] = val;
        }
      } else if (EPI == 3) {
        #pragma unroll
        for (int r = 0; r < 4; ++r) {
          int row = m0 + wm * 64 + m * 16 + kj * 4 + r;
          int col = n0 + wn * 64 + n * 16 + l15;
          qT[(size_t)row * ncols + col] = f2b(acc[m][n][r]);
        }
      } else {
        // qk: packed ushort4 store over 4 consecutive nseq
        int rowb = m0 + wm * 64 + m * 16 + kj * 4;
        int col = n0 + wn * 64 + n * 16 + l15;
        int nseqb = rowb & (NN - 1), b = rowb >> 12;
        int part = col >> 9, h = (col >> 6) & 7, dd = col & 63;
        ushort4 pk;
        #pragma unroll
        for (int r = 0; r < 4; ++r) {
          int nseq = nseqb + r;
          float val = acc[m][n][r] * gate[nseq] + bias[col];
          float e = val > 0.f ? val + 1.f : expf(val);  // elu+1
          ((ushort*)&pk)[r] = f2b(e * ropem[nseq * 64 + dd]);
        }
        ushort* dst = (part == 0 ? qT : kT) +
                      ((size_t)(b * HH + h) * DD + dd) * NN + nseqb;
        *(ushort4*)dst = pk;
      }
    }
  }
}

// ---------------------------------------------------------------------------
// K5a: ctx via MFMA from global; 512 blocks (2/CU), in-block LDS reduce of
// the 4 wave partials -> ctxp[bh*16+chunk][4096].
// ---------------------------------------------------------------------------
__global__ __launch_bounds__(256) void k_ctx_mfma(
    const ushort* __restrict__ qT, const ushort* __restrict__ kT,
    float* __restrict__ ctxp) {
  int blk = blockIdx.x;
  int bh = blk >> 4, chunk = blk & 15;
  int wave = threadIdx.x >> 6, lane = threadIdx.x & 63;
  int l15 = lane & 15, kj = lane >> 4;
  const size_t base = (size_t)bh * DD * NN;
  const int n0 = chunk * 256 + wave * 64;
  f32x4 acc[4][4] = {};
  #pragma unroll
  for (int ks = 0; ks < 2; ++ks) {
    const int nb = n0 + ks * 32 + kj * 8;
    bf16x8 qa[4], ka[4];
    #pragma unroll
    for (int m = 0; m < 4; ++m)
      qa[m] = *(const bf16x8*)(qT + base + (size_t)(m * 16 + l15) * NN + nb);
    #pragma unroll
    for (int n = 0; n < 4; ++n)
      ka[n] = *(const bf16x8*)(kT + base + (size_t)(n * 16 + l15) * NN + nb);
    #pragma unroll
    for (int m = 0; m < 4; ++m)
      #pragma unroll
      for (int n = 0; n < 4; ++n)
        acc[m][n] = __builtin_amdgcn_mfma_f32_16x16x32_bf16(qa[m], ka[n], acc[m][n], 0, 0, 0);
  }
  __shared__ float red[4][4096];
  #pragma unroll
  for (int m = 0; m < 4; ++m)
    #pragma unroll
    for (int n = 0; n < 4; ++n)
      #pragma unroll
      for (int r = 0; r < 4; ++r)
        red[wave][(m * 16 + kj * 4 + r) * 64 + n * 16 + l15] = acc[m][n][r];
  __syncthreads();
  const float scale = 1.f / 512.f;
  float* dst = ctxp + (size_t)(bh * 16 + chunk) * 4096;
  #pragma unroll
  for (int e = 0; e < 16; ++e) {
    int idx = threadIdx.x + e * 256;
    float s = red[0][idx] + red[1][idx] + red[2][idx] + red[3][idx];
    dst[idx] = s * scale;
  }
}

// K5b: reduce 16 partials -> ctx[bh][64][64]; one thread per element
__global__ void k_ctx_red(const float* __restrict__ ctxp, float* __restrict__ ctx) {
  int idx = blockIdx.x * 256 + threadIdx.x;  // 0..131071
  int bh = idx >> 12, off = idx & 4095;
  float s = 0.f;
  #pragma unroll
  for (int c2 = 0; c2 < 16; ++c2)
    s += ctxp[((size_t)bh * 16 + c2) * 4096 + off];
  ctx[idx] = s;
}

// ---------------------------------------------------------------------------
// K6: Mf[b][o][h*64+d] = (1/512)*sum_e ctx[b,h,d,e]*wp[o,h*64+e]; bf16 hi/lo.
// 256 blocks: (b, h, oq0..7), o = oq*64 + tid&63, d-group = tid>>6 (16 d).
// ---------------------------------------------------------------------------
__global__ __launch_bounds__(256) void k_mproj(
    const float* __restrict__ ctx, const float* __restrict__ wp,
    ushort* __restrict__ Mfh, ushort* __restrict__ Mfl) {
  int blk = blockIdx.x;
  int b = blk >> 6, h = (blk >> 3) & 7, oq = blk & 7;
  int tid = threadIdx.x;
  int o = oq * 64 + (tid & 63);
  int d0 = (tid >> 6) * 16;
  __shared__ float cs[64][64];
  #pragma unroll
  for (int it = 0; it < 4; ++it) {
    int idx = (tid + 256 * it) * 4;
    *(float4*)&cs[idx >> 6][idx & 63] =
        *(const float4*)&ctx[(size_t)(b * 8 + h) * 4096 + idx];
  }
  __syncthreads();
  float wv[64];
  #pragma unroll
  for (int e = 0; e < 64; ++e) wv[e] = wp[(size_t)o * 512 + h * 64 + e];
  for (int d = d0; d < d0 + 16; ++d) {
    float s = 0.f;
    #pragma unroll
    for (int e = 0; e < 64; ++e) s += cs[d][e] * wv[e];
    s *= (1.f / 512.f);
    ushort hi = f2b(s);
    size_t idx = ((size_t)b * 512 + o) * 512 + h * 64 + d;
    Mfh[idx] = hi;
    Mfl[idx] = f2b(s - b2f(hi));
  }
}

// K8: beff[b][o] = sum_c' bqkv[1024+c'] * Mf[b][o][c'] + bproj[o]
__global__ void k_beff(const ushort* __restrict__ Mfh, const ushort* __restrict__ Mfl,
                       const float* __restrict__ bqkv,
                       const float* __restrict__ bproj, float* __restrict__ beff) {
  int w = threadIdx.x >> 6, lane = threadIdx.x & 63;
  int t = blockIdx.x * 4 + w;  // 0..2047
  int b = t >> 9, o = t & 511;
  size_t base = ((size_t)b * 512 + o) * 512;
  float s = 0.f;
  #pragma unroll
  for (int c = 0; c < 512; c += 64) {
    float m = b2f(Mfh[base + c + lane]) + b2f(Mfl[base + c + lane]);
    s += bqkv[1024 + c + lane] * m;
  }
  #pragma unroll
  for (int off = 32; off > 0; off >>= 1) s += __shfl_down(s, off);
  if (lane == 0) beff[t] = s + bproj[o];
}

// ---------------------------------------------------------------------------
extern "C" void kernel_launch(void* const* d_in, const int* in_sizes, int n_in,
                              void* d_out, int out_size, void* d_ws, size_t ws_size,
                              hipStream_t stream) {
  const float* x    = (const float*)d_in[0];
  const float* lpw  = (const float*)d_in[1];
  const float* lvw  = (const float*)d_in[2];
  const float* wqkv = (const float*)d_in[3];
  const float* bqkv = (const float*)d_in[4];
  const float* wproj= (const float*)d_in[5];
  const float* bproj= (const float*)d_in[6];
  const float* omega= (const float*)d_in[7];
  const float* w1   = (const float*)d_in[8];
  const float* b1   = (const float*)d_in[9];
  const float* w2   = (const float*)d_in[10];
  const float* b2   = (const float*)d_in[11];
  const float* wg   = (const float*)d_in[12];
  const float* bg   = (const float*)d_in[13];
  float* out = (float*)d_out;

  constexpr size_t MB = 1024 * 1024;
  char* w = (char*)d_ws;
  int*   pcntP  = (int*)(w);                      // 64 KiB
  int*   pcntV  = (int*)(w + 64 * 1024);          // 64 KiB
  float* attn   = (float*)(w + 128 * 1024);
  float* gate   = (float*)(w + 144 * 1024);
  float* etabP  = (float*)(w + 160 * 1024);
  float* etabV  = (float*)(w + 176 * 1024);
  float* fcntP  = (float*)(w + 192 * 1024);
  float* fcntV  = (float*)(w + 208 * 1024);
  float* pe2    = (float*)(w + 256 * 1024);       // 1 MiB
  float* gpe    = (float*)(w + 1280 * 1024);
  float* ropem  = (float*)(w + 1344 * 1024);      // 1 MiB
  ushort* Xh    = (ushort*)(w + 4 * MB);          // 16 MiB
  ushort* qT    = (ushort*)(w + 20 * MB);         // 16 MiB [B,H,D,N]
  ushort* kT    = (ushort*)(w + 36 * MB);         // 16 MiB
  ushort* Whqk  = (ushort*)(w + 52 * MB);         // 1 MiB
  ushort* Wvth  = (ushort*)(w + 53 * MB);         // 0.5 MiB
  ushort* Wvtl  = (ushort*)(w + 53 * MB + 512 * 1024);  // 0.5 MiB
  ushort* Mfh   = (ushort*)(w + 54 * MB);         // 2 MiB [B*512][512]
  ushort* Mfl   = (ushort*)(w + 56 * MB);         // 2 MiB
  ushort* G2h   = (ushort*)(w + 58 * MB);         // 2 MiB
  float* beff   = (float*)(w + 60 * MB);          // 8 KiB
  float* ctxp   = (float*)(w + 61 * MB);          // 8 MiB
  float* ctx    = (float*)(w + 69 * MB);          // 0.5 MiB -> 69.5 MiB

  k_counts_prep<<<BB * 256, 512, 0, stream>>>(x, pcntP, pcntV, Xh);
  k_etab2<<<16, 256, 0, stream>>>(lpw, lvw, pcntP, pcntV, etabP, etabV, fcntP, fcntV);
  k_gsum<<<NN, 256, 0, stream>>>(fcntP, fcntV, etabP, etabV, attn);
  k_norm<<<1, 1024, 0, stream>>>(attn, gate);
  k_pe<<<1024, 256, 0, stream>>>(omega, w1, b1, w2, b2, pe2);
  k_gatepe<<<1, 256, 0, stream>>>(pe2, wg, bg, gpe);
  k_ropemul<<<1024, 256, 0, stream>>>(pe2, gpe, ropem);
  k_prep_h<<<512, 256, 0, stream>>>(wqkv, Whqk, 1024 * CC);
  k_prep_wvt<<<64, 256, 0, stream>>>(wqkv, Wvth, Wvtl);

  // q,k GEMM: M=16384, N=1024 -> 1024 blocks
  k_gemm_t<1, 1><<<1024, 256, 0, stream>>>(Xh, Whqk, nullptr, bqkv, gate, ropem,
                                           nullptr, qT, kT, 8, 0);
  k_ctx_mfma<<<512, 256, 0, stream>>>(qT, kT, ctxp);
  k_ctx_red<<<512, 256, 0, stream>>>(ctxp, ctx);
  k_mproj<<<256, 256, 0, stream>>>(ctx, wproj, Mfh, Mfl);
  // G2 = Mf * Wv^T via MFMA: M=2048, N=512 -> 64 blocks, bf16 out
  k_gemm_t<2, 3><<<64, 256, 0, stream>>>(Mfh, Wvth, Wvtl, nullptr, nullptr,
                                         nullptr, nullptr, G2h, nullptr, 4, 512);
  k_beff<<<512, 256, 0, stream>>>(Mfh, Mfl, bqkv, bproj, beff);

  // out GEMM: out = gate*(Xh * G2_b^T) + beff; M=16384, N=512 -> 512 blocks
  k_gemm_t<1, 2><<<512, 256, 0, stream>>>(Xh, G2h, nullptr, beff, gate, nullptr,
                                          out, nullptr, nullptr, 4, CC);
}

// Round 12
// 187.966 us; speedup vs baseline: 1.8209x; 1.0135x over previous
//
#include <hip/hip_runtime.h>
#include <hip/hip_bf16.h>
#include <math.h>

constexpr int BB = 4;
constexpr int NN = 4096;
constexpr int CC = 512;
constexpr int HH = 8;
constexpr int DD = 64;
constexpr int NCNT = NN - 2;

typedef __bf16 bf16x8 __attribute__((ext_vector_type(8)));
typedef float f32x4 __attribute__((ext_vector_type(4)));

__device__ __forceinline__ float b2f(ushort u) {
  unsigned v = ((unsigned)u) << 16;
  return __builtin_bit_cast(float, v);
}
__device__ __forceinline__ ushort f2b(float f) {
  __hip_bfloat16 h = __float2bfloat16(f);
  return __builtin_bit_cast(ushort, h);
}
__device__ __forceinline__ void gload16(const ushort* g, ushort* l) {
  __builtin_amdgcn_global_load_lds(
      (const __attribute__((address_space(1))) unsigned int*)g,
      (__attribute__((address_space(3))) unsigned int*)l, 16, 0, 0);
}

// ---------------------------------------------------------------------------
// K1: second-diff sign counts + fused x -> bf16 (per-batch partials, no atomics)
// ---------------------------------------------------------------------------
__global__ __launch_bounds__(512) void k_counts_prep(
    const float* __restrict__ x, int* __restrict__ pcntP,
    int* __restrict__ pcntV, ushort* __restrict__ Xh) {
  int b = blockIdx.x >> 8;
  int tile = blockIdx.x & 255;
  int c = threadIdx.x;
  int lane = threadIdx.x & 63;
  int i0 = tile * 16;
  const float* xb = x + (size_t)b * NN * CC + c;

  float v[18];
  #pragma unroll
  for (int r = 0; r < 18; ++r) {
    int i = i0 + r;
    v[r] = xb[(size_t)(i < NN ? i : NN - 1) * CC];  // independent loads
  }

  #pragma unroll
  for (int r = 0; r < 16; ++r)
    Xh[((size_t)b * NN + i0 + r) * CC + c] = f2b(v[r]);

  __shared__ int redP[16], redV[16];
  if (threadIdx.x < 16) { redP[threadIdx.x] = 0; redV[threadIdx.x] = 0; }
  __syncthreads();

  #pragma unroll
  for (int r = 0; r < 16; ++r) {
    int i = i0 + r;
    if (i < NCNT) {
      float d2 = (v[r + 2] - v[r + 1]) - (v[r + 1] - v[r]);
      unsigned long long mneg = __ballot(d2 < 0.0f);
      unsigned long long mpos = __ballot(d2 > 0.0f);
      if (lane == 0) {
        atomicAdd(&redP[r], __popcll(mneg));
        atomicAdd(&redV[r], __popcll(mpos));
      }
    }
  }
  __syncthreads();
  if (threadIdx.x < 16) {
    int i = i0 + threadIdx.x;
    pcntP[b * NN + i] = (i < NCNT) ? redP[threadIdx.x] : 0;
    pcntV[b * NN + i] = (i < NCNT) ? redV[threadIdx.x] : 0;
  }
}

// ---------------------------------------------------------------------------
// K2pre: exp tables + batch-summed float counts (one pass)
// ---------------------------------------------------------------------------
__global__ void k_etab2(const float* __restrict__ lpw, const float* __restrict__ lvw,
                        const int* __restrict__ pcntP, const int* __restrict__ pcntV,
                        float* __restrict__ etabP, float* __restrict__ etabV,
                        float* __restrict__ fcntP, float* __restrict__ fcntV) {
  int i = blockIdx.x * 256 + threadIdx.x;  // 0..4095
  float ipw = expf(-lpw[0]);
  float ivw = expf(-lvw[0]);
  float t1 = (float)i * ipw;
  float t2 = (float)i * ivw;
  etabP[i] = expf(-t1 * t1);
  etabV[i] = expf(-t2 * t2);
  fcntP[i] = (float)(pcntP[i] + pcntP[NN + i] + pcntP[2 * NN + i] + pcntP[3 * NN + i]);
  fcntV[i] = (float)(pcntV[i] + pcntV[NN + i] + pcntV[2 * NN + i] + pcntV[3 * NN + i]);
}

// ---------------------------------------------------------------------------
// K2a: Gaussian sums via tables (float counts)
// ---------------------------------------------------------------------------
__global__ void k_gsum(const float* __restrict__ fcntP, const float* __restrict__ fcntV,
                       const float* __restrict__ etabP, const float* __restrict__ etabV,
                       float* __restrict__ attn) {
  int p = blockIdx.x;
  int tid = threadIdx.x;
  float acc = 0.f;
  for (int i = tid; i < NCNT; i += 256) {
    int a = p - 1 - i;
    a = a < 0 ? -a : a;
    acc += fcntP[i] * etabP[a] + fcntV[i] * etabV[a];
  }
  __shared__ float red[256];
  red[tid] = acc;
  __syncthreads();
  for (int s = 128; s > 0; s >>= 1) {
    if (tid < s) red[tid] += red[tid + s];
    __syncthreads();
  }
  if (tid == 0) attn[p] = red[0];
}

// ---------------------------------------------------------------------------
// K2b: min-max normalize
// ---------------------------------------------------------------------------
__global__ void k_norm(const float* __restrict__ attn, float* __restrict__ gate) {
  int tid = threadIdx.x;  // 1024
  float v0 = attn[tid], v1 = attn[tid + 1024], v2 = attn[tid + 2048], v3 = attn[tid + 3072];
  float mn = fminf(fminf(v0, v1), fminf(v2, v3));
  float mx = fmaxf(fmaxf(v0, v1), fmaxf(v2, v3));
  __shared__ float rmn[1024], rmx[1024];
  rmn[tid] = mn; rmx[tid] = mx;
  __syncthreads();
  for (int s = 512; s > 0; s >>= 1) {
    if (tid < s) {
      rmn[tid] = fminf(rmn[tid], rmn[tid + s]);
      rmx[tid] = fmaxf(rmx[tid], rmx[tid + s]);
    }
    __syncthreads();
  }
  float lo = rmn[0];
  float denom = rmx[0] - rmn[0] + 1e-6f;
  gate[tid]        = (v0 - lo) / denom;
  gate[tid + 1024] = (v1 - lo) / denom;
  gate[tid + 2048] = (v2 - lo) / denom;
  gate[tid + 3072] = (v3 - lo) / denom;
}

// ---------------------------------------------------------------------------
// K3a: spectral PE conv path -> pe2 [64][4096]; 4 positions per 256-thr block
// ---------------------------------------------------------------------------
__global__ __launch_bounds__(256) void k_pe(
    const float* __restrict__ omega,
    const float* __restrict__ w1, const float* __restrict__ b1,
    const float* __restrict__ w2, const float* __restrict__ b2,
    float* __restrict__ pe2) {
  int g = threadIdx.x >> 6;   // group 0..3
  int j = threadIdx.x & 63;
  int n = blockIdx.x * 4 + g;
  __shared__ float pec[4][3][64];
  __shared__ float hs[4][128];
  for (int t = 0; t < 3; ++t) {
    int m = n + t - 1;
    float v = 0.f;
    if (m >= 0 && m < NN) {
      int l1 = m >> 6, l2 = m & 63;
      float rel = (float)(l1 - l2);
      v = (j < 32) ? sinf(rel * omega[j]) : cosf(rel * omega[j - 32]);
    }
    pec[g][t][j] = v;
  }
  __syncthreads();
  for (int o = j; o < 128; o += 64) {
    int ci = o >> 1;
    float hv = b1[o];
    #pragma unroll
    for (int t = 0; t < 3; ++t) hv += pec[g][t][ci] * w1[o * 3 + t];
    hv = 0.5f * hv * (1.f + erff(hv * 0.70710678118654752f));
    hs[g][o] = hv;
  }
  __syncthreads();
  float acc = b2[j];
  for (int o = 0; o < 128; ++o) acc += hs[g][o] * w2[j * 128 + o];
  pe2[(size_t)j * NN + n] = acc;
}

// ---------------------------------------------------------------------------
// K3b: channel means -> sigmoid gate gpe[64]
// ---------------------------------------------------------------------------
__global__ void k_gatepe(const float* __restrict__ pe2,
                         const float* __restrict__ wg, const float* __restrict__ bg,
                         float* __restrict__ gpe) {
  int tid = threadIdx.x;  // 256
  int j = tid & 63, part = tid >> 6;
  float s = 0.f;
  const float* row = pe2 + (size_t)j * NN + part * 1024;
  for (int t = 0; t < 1024; ++t) s += row[t];
  __shared__ float ps[4][64];
  __shared__ float mean[64];
  ps[part][j] = s;
  __syncthreads();
  if (tid < 64) mean[j] = (ps[0][j] + ps[1][j] + ps[2][j] + ps[3][j]) * (1.f / 4096.f);
  __syncthreads();
  if (tid < 64) {
    float g = bg[j];
    for (int k2 = 0; k2 < 64; ++k2) g += wg[j * 64 + k2] * mean[k2];
    gpe[j] = 1.f / (1.f + expf(-g));
  }
}

// ---------------------------------------------------------------------------
// K3c: rope multiplier
// ---------------------------------------------------------------------------
__global__ void k_ropemul(const float* __restrict__ pe2, const float* __restrict__ gpe,
                          float* __restrict__ ropem) {
  int idx = blockIdx.x * 256 + threadIdx.x;
  int n = idx >> 6, dd = idx & 63;
  ropem[idx] = 1.f + pe2[(size_t)dd * NN + n] * gpe[n >> 6] * 0.35355339059327373f;
}

// Prep: f32 -> bf16 (weights, hi only)
__global__ void k_prep_h(const float* __restrict__ src,
                         ushort* __restrict__ Sh, int nelem) {
  int idx4 = (blockIdx.x * 256 + threadIdx.x) * 4;
  if (idx4 >= nelem) return;
  float4 v = *(const float4*)&src[idx4];
  ushort4 h;
  ((ushort*)&h)[0] = f2b(v.x);
  ((ushort*)&h)[1] = f2b(v.y);
  ((ushort*)&h)[2] = f2b(v.z);
  ((ushort*)&h)[3] = f2b(v.w);
  *(ushort4*)&Sh[idx4] = h;
}

// ---------------------------------------------------------------------------
// Prep: Wv^T (wqkv rows 1024..1535 transposed) -> bf16 hi/lo [512 c][512 c']
// ---------------------------------------------------------------------------
__global__ __launch_bounds__(256) void k_prep_wvt(const float* __restrict__ wqkv,
                                                  ushort* __restrict__ Wvth,
                                                  ushort* __restrict__ Wvtl) {
  int bx = blockIdx.x & 7;   // c tile
  int by = blockIdx.x >> 3;  // c' tile
  __shared__ float t[64][65];
  int tid = threadIdx.x;
  #pragma unroll
  for (int it = 0; it < 4; ++it) {
    int idx = tid + it * 256;
    int r = idx >> 4;
    int c4 = (idx & 15) * 4;
    float4 v = *(const float4*)&wqkv[(size_t)(1024 + by * 64 + r) * 512 + bx * 64 + c4];
    t[r][c4] = v.x; t[r][c4 + 1] = v.y; t[r][c4 + 2] = v.z; t[r][c4 + 3] = v.w;
  }
  __syncthreads();
  #pragma unroll
  for (int it = 0; it < 4; ++it) {
    int idx = tid + it * 256;
    int r = idx >> 4;
    int c4 = (idx & 15) * 4;
    ushort4 h4, l4;
    #pragma unroll
    for (int q = 0; q < 4; ++q) {
      float v = t[c4 + q][r];
      ushort hi = f2b(v);
      ((ushort*)&h4)[q] = hi;
      ((ushort*)&l4)[q] = f2b(v - b2f(hi));
    }
    size_t o = (size_t)(bx * 64 + r) * 512 + by * 64 + c4;
    *(ushort4*)&Wvth[o] = h4;
    *(ushort4*)&Wvtl[o] = l4;
  }
}

// ---------------------------------------------------------------------------
// Plain double-buffered bf16 MFMA GEMM, fully unrolled K-loop (static buffer
// indices, pointer bases computed once -> per-step offsets fold into the
// instruction offset field). 128 x BN tile, BK=32, 4 waves (2x2).
// EPI=1: qk epilogue. EPI=2: out epilogue (f32, per-batch B). EPI=3: bf16 out.
// ---------------------------------------------------------------------------
template <int BN, int BTERMS, int EPI>
__global__ __launch_bounds__(256, 4) void k_gemm_t(
    const ushort* __restrict__ Ag, const ushort* __restrict__ Bgh,
    const ushort* __restrict__ Bgl,
    const float* __restrict__ bias, const float* __restrict__ gate,
    const float* __restrict__ ropem,
    float* __restrict__ outF, ushort* __restrict__ qT, ushort* __restrict__ kT,
    int ntn, int ncols) {
  constexpr int NF = BN / 32;  // B n-frags per wave (wave covers BN/2 cols)
  const int nwg = gridDim.x;
  const int hw = blockIdx.x;
  const int logical = (hw & 7) * (nwg >> 3) + (hw >> 3);
  const int m0 = (logical / ntn) * 128, n0 = (logical % ntn) * BN;

  const int tid = threadIdx.x, wave = tid >> 6, lane = tid & 63;
  const int wm = wave >> 1, wn = wave & 1;
  __shared__ ushort sA[2][4096];
  __shared__ ushort sB[2][BTERMS * BN * 32];
  f32x4 acc[4][NF] = {};

  const int lr = lane >> 2;
  const int ci = lane & 3;
  const int scol = (ci ^ ((lr >> 1) & 3)) * 8;           // inverse-swz source col
  const int rA = lane & 15;
  const int cswz = ((lane >> 4) ^ ((rA >> 1) & 3)) * 8;  // read-side swizzle

  const int chunk0 = wave * 2, chunk1 = wave * 2 + 1;

  const ushort* Bh_ = Bgh + (EPI == 2 ? (size_t)(m0 >> 12) * 262144 : 0);
  const ushort* Bl_ = (BTERMS == 2)
      ? (Bgl + (EPI == 2 ? (size_t)(m0 >> 12) * 262144 : 0)) : nullptr;

  // base pointers (computed once; per-step k-offset = T*32 elements)
  const ushort* pA0 = Ag + (size_t)(m0 + chunk0 * 16 + lr) * CC + scol;
  const ushort* pA1 = Ag + (size_t)(m0 + chunk1 * 16 + lr) * CC + scol;
  const ushort* pB0;
  const ushort* pB1 = nullptr;
  const ushort* pB0l = nullptr;
  const ushort* pB1l = nullptr;
  if (BN == 128) {
    pB0 = Bh_ + (size_t)(n0 + chunk0 * 16 + lr) * CC + scol;
    pB1 = Bh_ + (size_t)(n0 + chunk1 * 16 + lr) * CC + scol;
    if (BTERMS == 2) {
      pB0l = Bl_ + (size_t)(n0 + chunk0 * 16 + lr) * CC + scol;
      pB1l = Bl_ + (size_t)(n0 + chunk1 * 16 + lr) * CC + scol;
    }
  } else {
    pB0 = Bh_ + (size_t)(n0 + wave * 16 + lr) * CC + scol;
  }

#define STAGE(T, S)                                                        \
  {                                                                        \
    gload16(pA0 + (T) * 32, &sA[S][chunk0 * 512]);                         \
    gload16(pA1 + (T) * 32, &sA[S][chunk1 * 512]);                         \
    if (BN == 128) {                                                       \
      gload16(pB0 + (T) * 32, &sB[S][chunk0 * 512]);                       \
      gload16(pB1 + (T) * 32, &sB[S][chunk1 * 512]);                       \
      if (BTERMS == 2) {                                                   \
        gload16(pB0l + (T) * 32, &sB[S][4096 + chunk0 * 512]);             \
        gload16(pB1l + (T) * 32, &sB[S][4096 + chunk1 * 512]);             \
      }                                                                    \
    } else {                                                               \
      gload16(pB0 + (T) * 32, &sB[S][wave * 512]);                         \
    }                                                                      \
  }

  STAGE(0, 0);
  __syncthreads();  // tile 0 landed

  #pragma unroll
  for (int t = 0; t < 16; ++t) {
    if (t < 15) STAGE(t + 1, (t + 1) & 1);  // issue early; lands by barrier
    const int cur = t & 1;
    bf16x8 af[4], bhf[NF], blf[NF];
    #pragma unroll
    for (int m = 0; m < 4; ++m)
      af[m] = *(const bf16x8*)(&sA[cur][(wm * 64 + m * 16 + rA) * 32 + cswz]);
    #pragma unroll
    for (int n = 0; n < NF; ++n) {
      int off = (wn * (BN / 2) + n * 16 + rA) * 32 + cswz;
      bhf[n] = *(const bf16x8*)(&sB[cur][off]);
      if (BTERMS == 2) blf[n] = *(const bf16x8*)(&sB[cur][4096 + off]);
    }
    #pragma unroll
    for (int m = 0; m < 4; ++m)
      #pragma unroll
      for (int n = 0; n < NF; ++n) {
        acc[m][n] = __builtin_amdgcn_mfma_f32_16x16x32_bf16(af[m], bhf[n], acc[m][n], 0, 0, 0);
        if (BTERMS == 2)
          acc[m][n] = __builtin_amdgcn_mfma_f32_16x16x32_bf16(af[m], blf[n], acc[m][n], 0, 0, 0);
      }
    __syncthreads();  // next tile landed; this tile's reads done
  }
#undef STAGE

  const int kj = lane >> 4, l15 = lane & 15;
  #pragma unroll
  for (int m = 0; m < 4; ++m) {
    #pragma unroll
    for (int n = 0; n < NF; ++n) {
      if (EPI == 2) {
        #pragma unroll
        for (int r = 0; r < 4; ++r) {
          int row = m0 + wm * 64 + m * 16 + kj * 4 + r;
          int col = n0 + wn * (BN / 2) + n * 16 + l15;
          int nseq = row & (NN - 1), b = row >> 12;
          float val = acc[m][n][r] * gate[nseq] + bias[b * 512 + col];
          outF[(size_t)row * ncols + col] = val;
        }
      } else if (EPI == 3) {
        #pragma unroll
        for (int r = 0; r < 4; ++r) {
          int row = m0 + wm * 64 + m * 16 + kj * 4 + r;
          int col = n0 + wn * (BN / 2) + n * 16 + l15;
          qT[(size_t)row * ncols + col] = f2b(acc[m][n][r]);
        }
      } else {
        // qk: packed ushort4 store over 4 consecutive nseq
        int rowb = m0 + wm * 64 + m * 16 + kj * 4;
        int col = n0 + wn * (BN / 2) + n * 16 + l15;
        int nseqb = rowb & (NN - 1), b = rowb >> 12;
        int part = col >> 9, h = (col >> 6) & 7, dd = col & 63;
        ushort4 pk;
        #pragma unroll
        for (int r = 0; r < 4; ++r) {
          int nseq = nseqb + r;
          float val = acc[m][n][r] * gate[nseq] + bias[col];
          float e = val > 0.f ? val + 1.f : expf(val);  // elu+1
          ((ushort*)&pk)[r] = f2b(e * ropem[nseq * 64 + dd]);
        }
        ushort* dst = (part == 0 ? qT : kT) +
                      ((size_t)(b * HH + h) * DD + dd) * NN + nseqb;
        *(ushort4*)dst = pk;
      }
    }
  }
}

// ---------------------------------------------------------------------------
// K5a: ctx via MFMA from global; 512 blocks (2/CU), in-block LDS reduce of
// the 4 wave partials -> ctxp[bh*16+chunk][4096].
// ---------------------------------------------------------------------------
__global__ __launch_bounds__(256) void k_ctx_mfma(
    const ushort* __restrict__ qT, const ushort* __restrict__ kT,
    float* __restrict__ ctxp) {
  int blk = blockIdx.x;
  int bh = blk >> 4, chunk = blk & 15;
  int wave = threadIdx.x >> 6, lane = threadIdx.x & 63;
  int l15 = lane & 15, kj = lane >> 4;
  const size_t base = (size_t)bh * DD * NN;
  const int n0 = chunk * 256 + wave * 64;
  f32x4 acc[4][4] = {};
  #pragma unroll
  for (int ks = 0; ks < 2; ++ks) {
    const int nb = n0 + ks * 32 + kj * 8;
    bf16x8 qa[4], ka[4];
    #pragma unroll
    for (int m = 0; m < 4; ++m)
      qa[m] = *(const bf16x8*)(qT + base + (size_t)(m * 16 + l15) * NN + nb);
    #pragma unroll
    for (int n = 0; n < 4; ++n)
      ka[n] = *(const bf16x8*)(kT + base + (size_t)(n * 16 + l15) * NN + nb);
    #pragma unroll
    for (int m = 0; m < 4; ++m)
      #pragma unroll
      for (int n = 0; n < 4; ++n)
        acc[m][n] = __builtin_amdgcn_mfma_f32_16x16x32_bf16(qa[m], ka[n], acc[m][n], 0, 0, 0);
  }
  __shared__ float red[4][4096];
  #pragma unroll
  for (int m = 0; m < 4; ++m)
    #pragma unroll
    for (int n = 0; n < 4; ++n)
      #pragma unroll
      for (int r = 0; r < 4; ++r)
        red[wave][(m * 16 + kj * 4 + r) * 64 + n * 16 + l15] = acc[m][n][r];
  __syncthreads();
  const float scale = 1.f / 512.f;
  float* dst = ctxp + (size_t)(bh * 16 + chunk) * 4096;
  #pragma unroll
  for (int e = 0; e < 16; ++e) {
    int idx = threadIdx.x + e * 256;
    float s = red[0][idx] + red[1][idx] + red[2][idx] + red[3][idx];
    dst[idx] = s * scale;
  }
}

// K5b: reduce 16 partials -> ctx[bh][64][64]; one thread per element
__global__ void k_ctx_red(const float* __restrict__ ctxp, float* __restrict__ ctx) {
  int idx = blockIdx.x * 256 + threadIdx.x;  // 0..131071
  int bh = idx >> 12, off = idx & 4095;
  float s = 0.f;
  #pragma unroll
  for (int c2 = 0; c2 < 16; ++c2)
    s += ctxp[((size_t)bh * 16 + c2) * 4096 + off];
  ctx[idx] = s;
}

// ---------------------------------------------------------------------------
// K6: Mf[b][o][h*64+d] = (1/512)*sum_e ctx[b,h,d,e]*wp[o,h*64+e]; bf16 hi/lo.
// ---------------------------------------------------------------------------
__global__ __launch_bounds__(256) void k_mproj(
    const float* __restrict__ ctx, const float* __restrict__ wp,
    ushort* __restrict__ Mfh, ushort* __restrict__ Mfl) {
  int blk = blockIdx.x;
  int b = blk >> 6, h = (blk >> 3) & 7, oq = blk & 7;
  int tid = threadIdx.x;
  int o = oq * 64 + (tid & 63);
  int d0 = (tid >> 6) * 16;
  __shared__ float cs[64][64];
  #pragma unroll
  for (int it = 0; it < 4; ++it) {
    int idx = (tid + 256 * it) * 4;
    *(float4*)&cs[idx >> 6][idx & 63] =
        *(const float4*)&ctx[(size_t)(b * 8 + h) * 4096 + idx];
  }
  __syncthreads();
  float wv[64];
  #pragma unroll
  for (int e = 0; e < 64; ++e) wv[e] = wp[(size_t)o * 512 + h * 64 + e];
  for (int d = d0; d < d0 + 16; ++d) {
    float s = 0.f;
    #pragma unroll
    for (int e = 0; e < 64; ++e) s += cs[d][e] * wv[e];
    s *= (1.f / 512.f);
    ushort hi = f2b(s);
    size_t idx = ((size_t)b * 512 + o) * 512 + h * 64 + d;
    Mfh[idx] = hi;
    Mfl[idx] = f2b(s - b2f(hi));
  }
}

// K8: beff[b][o] = sum_c' bqkv[1024+c'] * Mf[b][o][c'] + bproj[o]
__global__ void k_beff(const ushort* __restrict__ Mfh, const ushort* __restrict__ Mfl,
                       const float* __restrict__ bqkv,
                       const float* __restrict__ bproj, float* __restrict__ beff) {
  int w = threadIdx.x >> 6, lane = threadIdx.x & 63;
  int t = blockIdx.x * 4 + w;  // 0..2047
  int b = t >> 9, o = t & 511;
  size_t base = ((size_t)b * 512 + o) * 512;
  float s = 0.f;
  #pragma unroll
  for (int c = 0; c < 512; c += 64) {
    float m = b2f(Mfh[base + c + lane]) + b2f(Mfl[base + c + lane]);
    s += bqkv[1024 + c + lane] * m;
  }
  #pragma unroll
  for (int off = 32; off > 0; off >>= 1) s += __shfl_down(s, off);
  if (lane == 0) beff[t] = s + bproj[o];
}

// ---------------------------------------------------------------------------
extern "C" void kernel_launch(void* const* d_in, const int* in_sizes, int n_in,
                              void* d_out, int out_size, void* d_ws, size_t ws_size,
                              hipStream_t stream) {
  const float* x    = (const float*)d_in[0];
  const float* lpw  = (const float*)d_in[1];
  const float* lvw  = (const float*)d_in[2];
  const float* wqkv = (const float*)d_in[3];
  const float* bqkv = (const float*)d_in[4];
  const float* wproj= (const float*)d_in[5];
  const float* bproj= (const float*)d_in[6];
  const float* omega= (const float*)d_in[7];
  const float* w1   = (const float*)d_in[8];
  const float* b1   = (const float*)d_in[9];
  const float* w2   = (const float*)d_in[10];
  const float* b2   = (const float*)d_in[11];
  const float* wg   = (const float*)d_in[12];
  const float* bg   = (const float*)d_in[13];
  float* out = (float*)d_out;

  constexpr size_t MB = 1024 * 1024;
  char* w = (char*)d_ws;
  int*   pcntP  = (int*)(w);                      // 64 KiB
  int*   pcntV  = (int*)(w + 64 * 1024);          // 64 KiB
  float* attn   = (float*)(w + 128 * 1024);
  float* gate   = (float*)(w + 144 * 1024);
  float* etabP  = (float*)(w + 160 * 1024);
  float* etabV  = (float*)(w + 176 * 1024);
  float* fcntP  = (float*)(w + 192 * 1024);
  float* fcntV  = (float*)(w + 208 * 1024);
  float* pe2    = (float*)(w + 256 * 1024);       // 1 MiB
  float* gpe    = (float*)(w + 1280 * 1024);
  float* ropem  = (float*)(w + 1344 * 1024);      // 1 MiB
  ushort* Xh    = (ushort*)(w + 4 * MB);          // 16 MiB
  ushort* qT    = (ushort*)(w + 20 * MB);         // 16 MiB [B,H,D,N]
  ushort* kT    = (ushort*)(w + 36 * MB);         // 16 MiB
  ushort* Whqk  = (ushort*)(w + 52 * MB);         // 1 MiB
  ushort* Wvth  = (ushort*)(w + 53 * MB);         // 0.5 MiB
  ushort* Wvtl  = (ushort*)(w + 53 * MB + 512 * 1024);  // 0.5 MiB
  ushort* Mfh   = (ushort*)(w + 54 * MB);         // 2 MiB [B*512][512]
  ushort* Mfl   = (ushort*)(w + 56 * MB);         // 2 MiB
  ushort* G2h   = (ushort*)(w + 58 * MB);         // 2 MiB
  float* beff   = (float*)(w + 60 * MB);          // 8 KiB
  float* ctxp   = (float*)(w + 61 * MB);          // 8 MiB
  float* ctx    = (float*)(w + 69 * MB);          // 0.5 MiB -> 69.5 MiB

  k_counts_prep<<<BB * 256, 512, 0, stream>>>(x, pcntP, pcntV, Xh);
  k_etab2<<<16, 256, 0, stream>>>(lpw, lvw, pcntP, pcntV, etabP, etabV, fcntP, fcntV);
  k_gsum<<<NN, 256, 0, stream>>>(fcntP, fcntV, etabP, etabV, attn);
  k_norm<<<1, 1024, 0, stream>>>(attn, gate);
  k_pe<<<1024, 256, 0, stream>>>(omega, w1, b1, w2, b2, pe2);
  k_gatepe<<<1, 256, 0, stream>>>(pe2, wg, bg, gpe);
  k_ropemul<<<1024, 256, 0, stream>>>(pe2, gpe, ropem);
  k_prep_h<<<512, 256, 0, stream>>>(wqkv, Whqk, 1024 * CC);
  k_prep_wvt<<<64, 256, 0, stream>>>(wqkv, Wvth, Wvtl);

  // q,k GEMM: M=16384, N=1024 -> 1024 blocks (4/CU)
  k_gemm_t<128, 1, 1><<<1024, 256, 0, stream>>>(Xh, Whqk, nullptr, bqkv, gate,
                                                ropem, nullptr, qT, kT, 8, 0);
  k_ctx_mfma<<<512, 256, 0, stream>>>(qT, kT, ctxp);
  k_ctx_red<<<512, 256, 0, stream>>>(ctxp, ctx);
  k_mproj<<<256, 256, 0, stream>>>(ctx, wproj, Mfh, Mfl);
  // G2 = Mf * Wv^T via MFMA: M=2048, N=512 -> 64 blocks, bf16 out
  k_gemm_t<128, 2, 3><<<64, 256, 0, stream>>>(Mfh, Wvth, Wvtl, nullptr, nullptr,
                                              nullptr, nullptr, G2h, nullptr, 4, 512);
  k_beff<<<512, 256, 0, stream>>>(Mfh, Mfl, bqkv, bproj, beff);

  // out GEMM: out = gate*(Xh * G2_b^T) + beff; M=16384, N=512 -> BN=64,
  // 1024 blocks (4/CU)
  k_gemm_t<64, 1, 2><<<1024, 256, 0, stream>>>(Xh, G2h, nullptr, beff, gate,
                                               nullptr, out, nullptr, nullptr, 8, 512);
}

// Round 13
// 186.034 us; speedup vs baseline: 1.8398x; 1.0104x over previous
//
#include <hip/hip_runtime.h>
#include <hip/hip_bf16.h>
#include <math.h>

constexpr int BB = 4;
constexpr int NN = 4096;
constexpr int CC = 512;
constexpr int HH = 8;
constexpr int DD = 64;
constexpr int NCNT = NN - 2;

typedef __bf16 bf16x8 __attribute__((ext_vector_type(8)));
typedef float f32x4 __attribute__((ext_vector_type(4)));

__device__ __forceinline__ float b2f(ushort u) {
  unsigned v = ((unsigned)u) << 16;
  return __builtin_bit_cast(float, v);
}
__device__ __forceinline__ ushort f2b(float f) {
  __hip_bfloat16 h = __float2bfloat16(f);
  return __builtin_bit_cast(ushort, h);
}
__device__ __forceinline__ void gload16(const ushort* g, ushort* l) {
  __builtin_amdgcn_global_load_lds(
      (const __attribute__((address_space(1))) unsigned int*)g,
      (__attribute__((address_space(3))) unsigned int*)l, 16, 0, 0);
}

// ---------------------------------------------------------------------------
// K1: second-diff sign counts + fused x -> bf16 (per-batch partials, no atomics)
// ---------------------------------------------------------------------------
__global__ __launch_bounds__(512) void k_counts_prep(
    const float* __restrict__ x, int* __restrict__ pcntP,
    int* __restrict__ pcntV, ushort* __restrict__ Xh) {
  int b = blockIdx.x >> 8;
  int tile = blockIdx.x & 255;
  int c = threadIdx.x;
  int lane = threadIdx.x & 63;
  int i0 = tile * 16;
  const float* xb = x + (size_t)b * NN * CC + c;

  float v[18];
  #pragma unroll
  for (int r = 0; r < 18; ++r) {
    int i = i0 + r;
    v[r] = xb[(size_t)(i < NN ? i : NN - 1) * CC];  // independent loads
  }

  #pragma unroll
  for (int r = 0; r < 16; ++r)
    Xh[((size_t)b * NN + i0 + r) * CC + c] = f2b(v[r]);

  __shared__ int redP[16], redV[16];
  if (threadIdx.x < 16) { redP[threadIdx.x] = 0; redV[threadIdx.x] = 0; }
  __syncthreads();

  #pragma unroll
  for (int r = 0; r < 16; ++r) {
    int i = i0 + r;
    if (i < NCNT) {
      float d2 = (v[r + 2] - v[r + 1]) - (v[r + 1] - v[r]);
      unsigned long long mneg = __ballot(d2 < 0.0f);
      unsigned long long mpos = __ballot(d2 > 0.0f);
      if (lane == 0) {
        atomicAdd(&redP[r], __popcll(mneg));
        atomicAdd(&redV[r], __popcll(mpos));
      }
    }
  }
  __syncthreads();
  if (threadIdx.x < 16) {
    int i = i0 + threadIdx.x;
    pcntP[b * NN + i] = (i < NCNT) ? redP[threadIdx.x] : 0;
    pcntV[b * NN + i] = (i < NCNT) ? redV[threadIdx.x] : 0;
  }
}

// ---------------------------------------------------------------------------
// K2pre: exp tables + batch-summed float counts (one pass)
// ---------------------------------------------------------------------------
__global__ void k_etab2(const float* __restrict__ lpw, const float* __restrict__ lvw,
                        const int* __restrict__ pcntP, const int* __restrict__ pcntV,
                        float* __restrict__ etabP, float* __restrict__ etabV,
                        float* __restrict__ fcntP, float* __restrict__ fcntV) {
  int i = blockIdx.x * 256 + threadIdx.x;  // 0..4095
  float ipw = expf(-lpw[0]);
  float ivw = expf(-lvw[0]);
  float t1 = (float)i * ipw;
  float t2 = (float)i * ivw;
  etabP[i] = expf(-t1 * t1);
  etabV[i] = expf(-t2 * t2);
  fcntP[i] = (float)(pcntP[i] + pcntP[NN + i] + pcntP[2 * NN + i] + pcntP[3 * NN + i]);
  fcntV[i] = (float)(pcntV[i] + pcntV[NN + i] + pcntV[2 * NN + i] + pcntV[3 * NN + i]);
}

// ---------------------------------------------------------------------------
// K2a: Gaussian sums via tables (float counts)
// ---------------------------------------------------------------------------
__global__ void k_gsum(const float* __restrict__ fcntP, const float* __restrict__ fcntV,
                       const float* __restrict__ etabP, const float* __restrict__ etabV,
                       float* __restrict__ attn) {
  int p = blockIdx.x;
  int tid = threadIdx.x;
  float acc = 0.f;
  for (int i = tid; i < NCNT; i += 256) {
    int a = p - 1 - i;
    a = a < 0 ? -a : a;
    acc += fcntP[i] * etabP[a] + fcntV[i] * etabV[a];
  }
  __shared__ float red[256];
  red[tid] = acc;
  __syncthreads();
  for (int s = 128; s > 0; s >>= 1) {
    if (tid < s) red[tid] += red[tid + s];
    __syncthreads();
  }
  if (tid == 0) attn[p] = red[0];
}

// ---------------------------------------------------------------------------
// K2b: min-max normalize
// ---------------------------------------------------------------------------
__global__ void k_norm(const float* __restrict__ attn, float* __restrict__ gate) {
  int tid = threadIdx.x;  // 1024
  float v0 = attn[tid], v1 = attn[tid + 1024], v2 = attn[tid + 2048], v3 = attn[tid + 3072];
  float mn = fminf(fminf(v0, v1), fminf(v2, v3));
  float mx = fmaxf(fmaxf(v0, v1), fmaxf(v2, v3));
  __shared__ float rmn[1024], rmx[1024];
  rmn[tid] = mn; rmx[tid] = mx;
  __syncthreads();
  for (int s = 512; s > 0; s >>= 1) {
    if (tid < s) {
      rmn[tid] = fminf(rmn[tid], rmn[tid + s]);
      rmx[tid] = fmaxf(rmx[tid], rmx[tid + s]);
    }
    __syncthreads();
  }
  float lo = rmn[0];
  float denom = rmx[0] - rmn[0] + 1e-6f;
  gate[tid]        = (v0 - lo) / denom;
  gate[tid + 1024] = (v1 - lo) / denom;
  gate[tid + 2048] = (v2 - lo) / denom;
  gate[tid + 3072] = (v3 - lo) / denom;
}

// ---------------------------------------------------------------------------
// K3a: spectral PE conv path -> pe2 [64][4096]; 4 positions per 256-thr block
// ---------------------------------------------------------------------------
__global__ __launch_bounds__(256) void k_pe(
    const float* __restrict__ omega,
    const float* __restrict__ w1, const float* __restrict__ b1,
    const float* __restrict__ w2, const float* __restrict__ b2,
    float* __restrict__ pe2) {
  int g = threadIdx.x >> 6;   // group 0..3
  int j = threadIdx.x & 63;
  int n = blockIdx.x * 4 + g;
  __shared__ float pec[4][3][64];
  __shared__ float hs[4][128];
  for (int t = 0; t < 3; ++t) {
    int m = n + t - 1;
    float v = 0.f;
    if (m >= 0 && m < NN) {
      int l1 = m >> 6, l2 = m & 63;
      float rel = (float)(l1 - l2);
      v = (j < 32) ? sinf(rel * omega[j]) : cosf(rel * omega[j - 32]);
    }
    pec[g][t][j] = v;
  }
  __syncthreads();
  for (int o = j; o < 128; o += 64) {
    int ci = o >> 1;
    float hv = b1[o];
    #pragma unroll
    for (int t = 0; t < 3; ++t) hv += pec[g][t][ci] * w1[o * 3 + t];
    hv = 0.5f * hv * (1.f + erff(hv * 0.70710678118654752f));
    hs[g][o] = hv;
  }
  __syncthreads();
  float acc = b2[j];
  for (int o = 0; o < 128; ++o) acc += hs[g][o] * w2[j * 128 + o];
  pe2[(size_t)j * NN + n] = acc;
}

// ---------------------------------------------------------------------------
// K3b: channel means -> sigmoid gate gpe[64]
// ---------------------------------------------------------------------------
__global__ void k_gatepe(const float* __restrict__ pe2,
                         const float* __restrict__ wg, const float* __restrict__ bg,
                         float* __restrict__ gpe) {
  int tid = threadIdx.x;  // 256
  int j = tid & 63, part = tid >> 6;
  float s = 0.f;
  const float* row = pe2 + (size_t)j * NN + part * 1024;
  for (int t = 0; t < 1024; ++t) s += row[t];
  __shared__ float ps[4][64];
  __shared__ float mean[64];
  ps[part][j] = s;
  __syncthreads();
  if (tid < 64) mean[j] = (ps[0][j] + ps[1][j] + ps[2][j] + ps[3][j]) * (1.f / 4096.f);
  __syncthreads();
  if (tid < 64) {
    float g = bg[j];
    for (int k2 = 0; k2 < 64; ++k2) g += wg[j * 64 + k2] * mean[k2];
    gpe[j] = 1.f / (1.f + expf(-g));
  }
}

// ---------------------------------------------------------------------------
// K3c: rope multiplier
// ---------------------------------------------------------------------------
__global__ void k_ropemul(const float* __restrict__ pe2, const float* __restrict__ gpe,
                          float* __restrict__ ropem) {
  int idx = blockIdx.x * 256 + threadIdx.x;
  int n = idx >> 6, dd = idx & 63;
  ropem[idx] = 1.f + pe2[(size_t)dd * NN + n] * gpe[n >> 6] * 0.35355339059327373f;
}

// Prep: f32 -> bf16 (weights, hi only)
__global__ void k_prep_h(const float* __restrict__ src,
                         ushort* __restrict__ Sh, int nelem) {
  int idx4 = (blockIdx.x * 256 + threadIdx.x) * 4;
  if (idx4 >= nelem) return;
  float4 v = *(const float4*)&src[idx4];
  ushort4 h;
  ((ushort*)&h)[0] = f2b(v.x);
  ((ushort*)&h)[1] = f2b(v.y);
  ((ushort*)&h)[2] = f2b(v.z);
  ((ushort*)&h)[3] = f2b(v.w);
  *(ushort4*)&Sh[idx4] = h;
}

// ---------------------------------------------------------------------------
// Prep: Wv^T (wqkv rows 1024..1535 transposed) -> bf16 hi/lo [512 c][512 c']
// ---------------------------------------------------------------------------
__global__ __launch_bounds__(256) void k_prep_wvt(const float* __restrict__ wqkv,
                                                  ushort* __restrict__ Wvth,
                                                  ushort* __restrict__ Wvtl) {
  int bx = blockIdx.x & 7;   // c tile
  int by = blockIdx.x >> 3;  // c' tile
  __shared__ float t[64][65];
  int tid = threadIdx.x;
  #pragma unroll
  for (int it = 0; it < 4; ++it) {
    int idx = tid + it * 256;
    int r = idx >> 4;
    int c4 = (idx & 15) * 4;
    float4 v = *(const float4*)&wqkv[(size_t)(1024 + by * 64 + r) * 512 + bx * 64 + c4];
    t[r][c4] = v.x; t[r][c4 + 1] = v.y; t[r][c4 + 2] = v.z; t[r][c4 + 3] = v.w;
  }
  __syncthreads();
  #pragma unroll
  for (int it = 0; it < 4; ++it) {
    int idx = tid + it * 256;
    int r = idx >> 4;
    int c4 = (idx & 15) * 4;
    ushort4 h4, l4;
    #pragma unroll
    for (int q = 0; q < 4; ++q) {
      float v = t[c4 + q][r];
      ushort hi = f2b(v);
      ((ushort*)&h4)[q] = hi;
      ((ushort*)&l4)[q] = f2b(v - b2f(hi));
    }
    size_t o = (size_t)(bx * 64 + r) * 512 + by * 64 + c4;
    *(ushort4*)&Wvth[o] = h4;
    *(ushort4*)&Wvtl[o] = l4;
  }
}

// ---------------------------------------------------------------------------
// Plain double-buffered bf16 MFMA GEMM, fully unrolled K-loop (static buffer
// indices, pointer bases computed once). 128 x BN tile, BK=32, 4 waves (2x2).
// NOTE: no min-waves in launch_bounds -- (256,4) capped VGPR at 64 and caused
// ~55 MB/dispatch of spill traffic (round-12 regression).
// EPI=1: qk epilogue. EPI=2: out epilogue (f32, per-batch B). EPI=3: bf16 out.
// ---------------------------------------------------------------------------
template <int BN, int BTERMS, int EPI>
__global__ __launch_bounds__(256) void k_gemm_t(
    const ushort* __restrict__ Ag, const ushort* __restrict__ Bgh,
    const ushort* __restrict__ Bgl,
    const float* __restrict__ bias, const float* __restrict__ gate,
    const float* __restrict__ ropem,
    float* __restrict__ outF, ushort* __restrict__ qT, ushort* __restrict__ kT,
    int ntn, int ncols) {
  constexpr int NF = BN / 32;  // B n-frags per wave (wave covers BN/2 cols)
  const int nwg = gridDim.x;
  const int hw = blockIdx.x;
  const int logical = (hw & 7) * (nwg >> 3) + (hw >> 3);
  const int m0 = (logical / ntn) * 128, n0 = (logical % ntn) * BN;

  const int tid = threadIdx.x, wave = tid >> 6, lane = tid & 63;
  const int wm = wave >> 1, wn = wave & 1;
  __shared__ ushort sA[2][4096];
  __shared__ ushort sB[2][BTERMS * BN * 32];
  f32x4 acc[4][NF] = {};

  const int lr = lane >> 2;
  const int ci = lane & 3;
  const int scol = (ci ^ ((lr >> 1) & 3)) * 8;           // inverse-swz source col
  const int rA = lane & 15;
  const int cswz = ((lane >> 4) ^ ((rA >> 1) & 3)) * 8;  // read-side swizzle

  const int chunk0 = wave * 2, chunk1 = wave * 2 + 1;

  const ushort* Bh_ = Bgh + (EPI == 2 ? (size_t)(m0 >> 12) * 262144 : 0);
  const ushort* Bl_ = (BTERMS == 2)
      ? (Bgl + (EPI == 2 ? (size_t)(m0 >> 12) * 262144 : 0)) : nullptr;

  // base pointers (computed once; per-step k-offset = T*32 elements)
  const ushort* pA0 = Ag + (size_t)(m0 + chunk0 * 16 + lr) * CC + scol;
  const ushort* pA1 = Ag + (size_t)(m0 + chunk1 * 16 + lr) * CC + scol;
  const ushort* pB0;
  const ushort* pB1 = nullptr;
  const ushort* pB0l = nullptr;
  const ushort* pB1l = nullptr;
  if (BN == 128) {
    pB0 = Bh_ + (size_t)(n0 + chunk0 * 16 + lr) * CC + scol;
    pB1 = Bh_ + (size_t)(n0 + chunk1 * 16 + lr) * CC + scol;
    if (BTERMS == 2) {
      pB0l = Bl_ + (size_t)(n0 + chunk0 * 16 + lr) * CC + scol;
      pB1l = Bl_ + (size_t)(n0 + chunk1 * 16 + lr) * CC + scol;
    }
  } else {
    pB0 = Bh_ + (size_t)(n0 + wave * 16 + lr) * CC + scol;
  }

#define STAGE(T, S)                                                        \
  {                                                                        \
    gload16(pA0 + (T) * 32, &sA[S][chunk0 * 512]);                         \
    gload16(pA1 + (T) * 32, &sA[S][chunk1 * 512]);                         \
    if (BN == 128) {                                                       \
      gload16(pB0 + (T) * 32, &sB[S][chunk0 * 512]);                       \
      gload16(pB1 + (T) * 32, &sB[S][chunk1 * 512]);                       \
      if (BTERMS == 2) {                                                   \
        gload16(pB0l + (T) * 32, &sB[S][4096 + chunk0 * 512]);             \
        gload16(pB1l + (T) * 32, &sB[S][4096 + chunk1 * 512]);             \
      }                                                                    \
    } else {                                                               \
      gload16(pB0 + (T) * 32, &sB[S][wave * 512]);                         \
    }                                                                      \
  }

  STAGE(0, 0);
  __syncthreads();  // tile 0 landed

  #pragma unroll
  for (int t = 0; t < 16; ++t) {
    if (t < 15) STAGE(t + 1, (t + 1) & 1);  // issue early; lands by barrier
    const int cur = t & 1;
    bf16x8 af[4], bhf[NF], blf[NF];
    #pragma unroll
    for (int m = 0; m < 4; ++m)
      af[m] = *(const bf16x8*)(&sA[cur][(wm * 64 + m * 16 + rA) * 32 + cswz]);
    #pragma unroll
    for (int n = 0; n < NF; ++n) {
      int off = (wn * (BN / 2) + n * 16 + rA) * 32 + cswz;
      bhf[n] = *(const bf16x8*)(&sB[cur][off]);
      if (BTERMS == 2) blf[n] = *(const bf16x8*)(&sB[cur][4096 + off]);
    }
    #pragma unroll
    for (int m = 0; m < 4; ++m)
      #pragma unroll
      for (int n = 0; n < NF; ++n) {
        acc[m][n] = __builtin_amdgcn_mfma_f32_16x16x32_bf16(af[m], bhf[n], acc[m][n], 0, 0, 0);
        if (BTERMS == 2)
          acc[m][n] = __builtin_amdgcn_mfma_f32_16x16x32_bf16(af[m], blf[n], acc[m][n], 0, 0, 0);
      }
    __syncthreads();  // next tile landed; this tile's reads done
  }
#undef STAGE

  const int kj = lane >> 4, l15 = lane & 15;
  #pragma unroll
  for (int m = 0; m < 4; ++m) {
    #pragma unroll
    for (int n = 0; n < NF; ++n) {
      if (EPI == 2) {
        #pragma unroll
        for (int r = 0; r < 4; ++r) {
          int row = m0 + wm * 64 + m * 16 + kj * 4 + r;
          int col = n0 + wn * (BN / 2) + n * 16 + l15;
          int nseq = row & (NN - 1), b = row >> 12;
          float val = acc[m][n][r] * gate[nseq] + bias[b * 512 + col];
          outF[(size_t)row * ncols + col] = val;
        }
      } else if (EPI == 3) {
        #pragma unroll
        for (int r = 0; r < 4; ++r) {
          int row = m0 + wm * 64 + m * 16 + kj * 4 + r;
          int col = n0 + wn * (BN / 2) + n * 16 + l15;
          qT[(size_t)row * ncols + col] = f2b(acc[m][n][r]);
        }
      } else {
        // qk: packed ushort4 store over 4 consecutive nseq
        int rowb = m0 + wm * 64 + m * 16 + kj * 4;
        int col = n0 + wn * (BN / 2) + n * 16 + l15;
        int nseqb = rowb & (NN - 1), b = rowb >> 12;
        int part = col >> 9, h = (col >> 6) & 7, dd = col & 63;
        ushort4 pk;
        #pragma unroll
        for (int r = 0; r < 4; ++r) {
          int nseq = nseqb + r;
          float val = acc[m][n][r] * gate[nseq] + bias[col];
          float e = val > 0.f ? val + 1.f : expf(val);  // elu+1
          ((ushort*)&pk)[r] = f2b(e * ropem[nseq * 64 + dd]);
        }
        ushort* dst = (part == 0 ? qT : kT) +
                      ((size_t)(b * HH + h) * DD + dd) * NN + nseqb;
        *(ushort4*)dst = pk;
      }
    }
  }
}

// ---------------------------------------------------------------------------
// K5a: ctx via MFMA from global; 512 blocks (2/CU), in-block LDS reduce of
// the 4 wave partials -> ctxp[bh*16+chunk][4096].
// ---------------------------------------------------------------------------
__global__ __launch_bounds__(256) void k_ctx_mfma(
    const ushort* __restrict__ qT, const ushort* __restrict__ kT,
    float* __restrict__ ctxp) {
  int blk = blockIdx.x;
  int bh = blk >> 4, chunk = blk & 15;
  int wave = threadIdx.x >> 6, lane = threadIdx.x & 63;
  int l15 = lane & 15, kj = lane >> 4;
  const size_t base = (size_t)bh * DD * NN;
  const int n0 = chunk * 256 + wave * 64;
  f32x4 acc[4][4] = {};
  #pragma unroll
  for (int ks = 0; ks < 2; ++ks) {
    const int nb = n0 + ks * 32 + kj * 8;
    bf16x8 qa[4], ka[4];
    #pragma unroll
    for (int m = 0; m < 4; ++m)
      qa[m] = *(const bf16x8*)(qT + base + (size_t)(m * 16 + l15) * NN + nb);
    #pragma unroll
    for (int n = 0; n < 4; ++n)
      ka[n] = *(const bf16x8*)(kT + base + (size_t)(n * 16 + l15) * NN + nb);
    #pragma unroll
    for (int m = 0; m < 4; ++m)
      #pragma unroll
      for (int n = 0; n < 4; ++n)
        acc[m][n] = __builtin_amdgcn_mfma_f32_16x16x32_bf16(qa[m], ka[n], acc[m][n], 0, 0, 0);
  }
  __shared__ float red[4][4096];
  #pragma unroll
  for (int m = 0; m < 4; ++m)
    #pragma unroll
    for (int n = 0; n < 4; ++n)
      #pragma unroll
      for (int r = 0; r < 4; ++r)
        red[wave][(m * 16 + kj * 4 + r) * 64 + n * 16 + l15] = acc[m][n][r];
  __syncthreads();
  const float scale = 1.f / 512.f;
  float* dst = ctxp + (size_t)(bh * 16 + chunk) * 4096;
  #pragma unroll
  for (int e = 0; e < 16; ++e) {
    int idx = threadIdx.x + e * 256;
    float s = red[0][idx] + red[1][idx] + red[2][idx] + red[3][idx];
    dst[idx] = s * scale;
  }
}

// K5b: reduce 16 partials -> ctx[bh][64][64]; one thread per element
__global__ void k_ctx_red(const float* __restrict__ ctxp, float* __restrict__ ctx) {
  int idx = blockIdx.x * 256 + threadIdx.x;  // 0..131071
  int bh = idx >> 12, off = idx & 4095;
  float s = 0.f;
  #pragma unroll
  for (int c2 = 0; c2 < 16; ++c2)
    s += ctxp[((size_t)bh * 16 + c2) * 4096 + off];
  ctx[idx] = s;
}

// ---------------------------------------------------------------------------
// K6: Mf[b][o][h*64+d] = (1/512)*sum_e ctx[b,h,d,e]*wp[o,h*64+e]; bf16 hi/lo.
// ---------------------------------------------------------------------------
__global__ __launch_bounds__(256) void k_mproj(
    const float* __restrict__ ctx, const float* __restrict__ wp,
    ushort* __restrict__ Mfh, ushort* __restrict__ Mfl) {
  int blk = blockIdx.x;
  int b = blk >> 6, h = (blk >> 3) & 7, oq = blk & 7;
  int tid = threadIdx.x;
  int o = oq * 64 + (tid & 63);
  int d0 = (tid >> 6) * 16;
  __shared__ float cs[64][64];
  #pragma unroll
  for (int it = 0; it < 4; ++it) {
    int idx = (tid + 256 * it) * 4;
    *(float4*)&cs[idx >> 6][idx & 63] =
        *(const float4*)&ctx[(size_t)(b * 8 + h) * 4096 + idx];
  }
  __syncthreads();
  float wv[64];
  #pragma unroll
  for (int e = 0; e < 64; ++e) wv[e] = wp[(size_t)o * 512 + h * 64 + e];
  for (int d = d0; d < d0 + 16; ++d) {
    float s = 0.f;
    #pragma unroll
    for (int e = 0; e < 64; ++e) s += cs[d][e] * wv[e];
    s *= (1.f / 512.f);
    ushort hi = f2b(s);
    size_t idx = ((size_t)b * 512 + o) * 512 + h * 64 + d;
    Mfh[idx] = hi;
    Mfl[idx] = f2b(s - b2f(hi));
  }
}

// K8: beff[b][o] = sum_c' bqkv[1024+c'] * Mf[b][o][c'] + bproj[o]
__global__ void k_beff(const ushort* __restrict__ Mfh, const ushort* __restrict__ Mfl,
                       const float* __restrict__ bqkv,
                       const float* __restrict__ bproj, float* __restrict__ beff) {
  int w = threadIdx.x >> 6, lane = threadIdx.x & 63;
  int t = blockIdx.x * 4 + w;  // 0..2047
  int b = t >> 9, o = t & 511;
  size_t base = ((size_t)b * 512 + o) * 512;
  float s = 0.f;
  #pragma unroll
  for (int c = 0; c < 512; c += 64) {
    float m = b2f(Mfh[base + c + lane]) + b2f(Mfl[base + c + lane]);
    s += bqkv[1024 + c + lane] * m;
  }
  #pragma unroll
  for (int off = 32; off > 0; off >>= 1) s += __shfl_down(s, off);
  if (lane == 0) beff[t] = s + bproj[o];
}

// ---------------------------------------------------------------------------
extern "C" void kernel_launch(void* const* d_in, const int* in_sizes, int n_in,
                              void* d_out, int out_size, void* d_ws, size_t ws_size,
                              hipStream_t stream) {
  const float* x    = (const float*)d_in[0];
  const float* lpw  = (const float*)d_in[1];
  const float* lvw  = (const float*)d_in[2];
  const float* wqkv = (const float*)d_in[3];
  const float* bqkv = (const float*)d_in[4];
  const float* wproj= (const float*)d_in[5];
  const float* bproj= (const float*)d_in[6];
  const float* omega= (const float*)d_in[7];
  const float* w1   = (const float*)d_in[8];
  const float* b1   = (const float*)d_in[9];
  const float* w2   = (const float*)d_in[10];
  const float* b2   = (const float*)d_in[11];
  const float* wg   = (const float*)d_in[12];
  const float* bg   = (const float*)d_in[13];
  float* out = (float*)d_out;

  constexpr size_t MB = 1024 * 1024;
  char* w = (char*)d_ws;
  int*   pcntP  = (int*)(w);                      // 64 KiB
  int*   pcntV  = (int*)(w + 64 * 1024);          // 64 KiB
  float* attn   = (float*)(w + 128 * 1024);
  float* gate   = (float*)(w + 144 * 1024);
  float* etabP  = (float*)(w + 160 * 1024);
  float* etabV  = (float*)(w + 176 * 1024);
  float* fcntP  = (float*)(w + 192 * 1024);
  float* fcntV  = (float*)(w + 208 * 1024);
  float* pe2    = (float*)(w + 256 * 1024);       // 1 MiB
  float* gpe    = (float*)(w + 1280 * 1024);
  float* ropem  = (float*)(w + 1344 * 1024);      // 1 MiB
  ushort* Xh    = (ushort*)(w + 4 * MB);          // 16 MiB
  ushort* qT    = (ushort*)(w + 20 * MB);         // 16 MiB [B,H,D,N]
  ushort* kT    = (ushort*)(w + 36 * MB);         // 16 MiB
  ushort* Whqk  = (ushort*)(w + 52 * MB);         // 1 MiB
  ushort* Wvth  = (ushort*)(w + 53 * MB);         // 0.5 MiB
  ushort* Wvtl  = (ushort*)(w + 53 * MB + 512 * 1024);  // 0.5 MiB
  ushort* Mfh   = (ushort*)(w + 54 * MB);         // 2 MiB [B*512][512]
  ushort* Mfl   = (ushort*)(w + 56 * MB);         // 2 MiB
  ushort* G2h   = (ushort*)(w + 58 * MB);         // 2 MiB
  float* beff   = (float*)(w + 60 * MB);          // 8 KiB
  float* ctxp   = (float*)(w + 61 * MB);          // 8 MiB
  float* ctx    = (float*)(w + 69 * MB);          // 0.5 MiB -> 69.5 MiB

  k_counts_prep<<<BB * 256, 512, 0, stream>>>(x, pcntP, pcntV, Xh);
  k_etab2<<<16, 256, 0, stream>>>(lpw, lvw, pcntP, pcntV, etabP, etabV, fcntP, fcntV);
  k_gsum<<<NN, 256, 0, stream>>>(fcntP, fcntV, etabP, etabV, attn);
  k_norm<<<1, 1024, 0, stream>>>(attn, gate);
  k_pe<<<1024, 256, 0, stream>>>(omega, w1, b1, w2, b2, pe2);
  k_gatepe<<<1, 256, 0, stream>>>(pe2, wg, bg, gpe);
  k_ropemul<<<1024, 256, 0, stream>>>(pe2, gpe, ropem);
  k_prep_h<<<512, 256, 0, stream>>>(wqkv, Whqk, 1024 * CC);
  k_prep_wvt<<<64, 256, 0, stream>>>(wqkv, Wvth, Wvtl);

  // q,k GEMM: M=16384, N=1024 -> 1024 blocks (4/CU)
  k_gemm_t<128, 1, 1><<<1024, 256, 0, stream>>>(Xh, Whqk, nullptr, bqkv, gate,
                                                ropem, nullptr, qT, kT, 8, 0);
  k_ctx_mfma<<<512, 256, 0, stream>>>(qT, kT, ctxp);
  k_ctx_red<<<512, 256, 0, stream>>>(ctxp, ctx);
  k_mproj<<<256, 256, 0, stream>>>(ctx, wproj, Mfh, Mfl);
  // G2 = Mf * Wv^T via MFMA: M=2048, N=512 -> 64 blocks, bf16 out
  k_gemm_t<128, 2, 3><<<64, 256, 0, stream>>>(Mfh, Wvth, Wvtl, nullptr, nullptr,
                                              nullptr, nullptr, G2h, nullptr, 4, 512);
  k_beff<<<512, 256, 0, stream>>>(Mfh, Mfl, bqkv, bproj, beff);

  // out GEMM: out = gate*(Xh * G2_b^T) + beff; M=16384, N=512 -> BN=64,
  // 1024 blocks (4/CU)
  k_gemm_t<64, 1, 2><<<1024, 256, 0, stream>>>(Xh, G2h, nullptr, beff, gate,
                                               nullptr, out, nullptr, nullptr, 8, 512);
}

// Round 14
// 178.712 us; speedup vs baseline: 1.9152x; 1.0410x over previous
//
#include <hip/hip_runtime.h>
#include <hip/hip_bf16.h>
#include <math.h>

constexpr int BB = 4;
constexpr int NN = 4096;
constexpr int CC = 512;
constexpr int HH = 8;
constexpr int DD = 64;
constexpr int NCNT = NN - 2;

typedef __bf16 bf16x8 __attribute__((ext_vector_type(8)));
typedef float f32x4 __attribute__((ext_vector_type(4)));

__device__ __forceinline__ float b2f(ushort u) {
  unsigned v = ((unsigned)u) << 16;
  return __builtin_bit_cast(float, v);
}
__device__ __forceinline__ ushort f2b(float f) {
  __hip_bfloat16 h = __float2bfloat16(f);
  return __builtin_bit_cast(ushort, h);
}
__device__ __forceinline__ void gload16(const ushort* g, ushort* l) {
  __builtin_amdgcn_global_load_lds(
      (const __attribute__((address_space(1))) unsigned int*)g,
      (__attribute__((address_space(3))) unsigned int*)l, 16, 0, 0);
}

// ---------------------------------------------------------------------------
// K1: second-diff sign counts + fused x -> bf16 (per-batch partials, no atomics)
// ---------------------------------------------------------------------------
__global__ __launch_bounds__(512) void k_counts_prep(
    const float* __restrict__ x, int* __restrict__ pcntP,
    int* __restrict__ pcntV, ushort* __restrict__ Xh) {
  int b = blockIdx.x >> 8;
  int tile = blockIdx.x & 255;
  int c = threadIdx.x;
  int lane = threadIdx.x & 63;
  int i0 = tile * 16;
  const float* xb = x + (size_t)b * NN * CC + c;

  float v[18];
  #pragma unroll
  for (int r = 0; r < 18; ++r) {
    int i = i0 + r;
    v[r] = xb[(size_t)(i < NN ? i : NN - 1) * CC];  // independent loads
  }

  #pragma unroll
  for (int r = 0; r < 16; ++r)
    Xh[((size_t)b * NN + i0 + r) * CC + c] = f2b(v[r]);

  __shared__ int redP[16], redV[16];
  if (threadIdx.x < 16) { redP[threadIdx.x] = 0; redV[threadIdx.x] = 0; }
  __syncthreads();

  #pragma unroll
  for (int r = 0; r < 16; ++r) {
    int i = i0 + r;
    if (i < NCNT) {
      float d2 = (v[r + 2] - v[r + 1]) - (v[r + 1] - v[r]);
      unsigned long long mneg = __ballot(d2 < 0.0f);
      unsigned long long mpos = __ballot(d2 > 0.0f);
      if (lane == 0) {
        atomicAdd(&redP[r], __popcll(mneg));
        atomicAdd(&redV[r], __popcll(mpos));
      }
    }
  }
  __syncthreads();
  if (threadIdx.x < 16) {
    int i = i0 + threadIdx.x;
    pcntP[b * NN + i] = (i < NCNT) ? redP[threadIdx.x] : 0;
    pcntV[b * NN + i] = (i < NCNT) ? redV[threadIdx.x] : 0;
  }
}

// ---------------------------------------------------------------------------
// K2pre: exp tables + batch-summed float counts (one pass)
// ---------------------------------------------------------------------------
__global__ void k_etab2(const float* __restrict__ lpw, const float* __restrict__ lvw,
                        const int* __restrict__ pcntP, const int* __restrict__ pcntV,
                        float* __restrict__ etabP, float* __restrict__ etabV,
                        float* __restrict__ fcntP, float* __restrict__ fcntV) {
  int i = blockIdx.x * 256 + threadIdx.x;  // 0..4095
  float ipw = expf(-lpw[0]);
  float ivw = expf(-lvw[0]);
  float t1 = (float)i * ipw;
  float t2 = (float)i * ivw;
  etabP[i] = expf(-t1 * t1);
  etabV[i] = expf(-t2 * t2);
  fcntP[i] = (float)(pcntP[i] + pcntP[NN + i] + pcntP[2 * NN + i] + pcntP[3 * NN + i]);
  fcntV[i] = (float)(pcntV[i] + pcntV[NN + i] + pcntV[2 * NN + i] + pcntV[3 * NN + i]);
}

// ---------------------------------------------------------------------------
// K2a: Gaussian sums via tables (float counts)
// ---------------------------------------------------------------------------
__global__ void k_gsum(const float* __restrict__ fcntP, const float* __restrict__ fcntV,
                       const float* __restrict__ etabP, const float* __restrict__ etabV,
                       float* __restrict__ attn) {
  int p = blockIdx.x;
  int tid = threadIdx.x;
  float acc = 0.f;
  for (int i = tid; i < NCNT; i += 256) {
    int a = p - 1 - i;
    a = a < 0 ? -a : a;
    acc += fcntP[i] * etabP[a] + fcntV[i] * etabV[a];
  }
  __shared__ float red[256];
  red[tid] = acc;
  __syncthreads();
  for (int s = 128; s > 0; s >>= 1) {
    if (tid < s) red[tid] += red[tid + s];
    __syncthreads();
  }
  if (tid == 0) attn[p] = red[0];
}

// ---------------------------------------------------------------------------
// K2b: min-max normalize
// ---------------------------------------------------------------------------
__global__ void k_norm(const float* __restrict__ attn, float* __restrict__ gate) {
  int tid = threadIdx.x;  // 1024
  float v0 = attn[tid], v1 = attn[tid + 1024], v2 = attn[tid + 2048], v3 = attn[tid + 3072];
  float mn = fminf(fminf(v0, v1), fminf(v2, v3));
  float mx = fmaxf(fmaxf(v0, v1), fmaxf(v2, v3));
  __shared__ float rmn[1024], rmx[1024];
  rmn[tid] = mn; rmx[tid] = mx;
  __syncthreads();
  for (int s = 512; s > 0; s >>= 1) {
    if (tid < s) {
      rmn[tid] = fminf(rmn[tid], rmn[tid + s]);
      rmx[tid] = fmaxf(rmx[tid], rmx[tid + s]);
    }
    __syncthreads();
  }
  float lo = rmn[0];
  float denom = rmx[0] - rmn[0] + 1e-6f;
  gate[tid]        = (v0 - lo) / denom;
  gate[tid + 1024] = (v1 - lo) / denom;
  gate[tid + 2048] = (v2 - lo) / denom;
  gate[tid + 3072] = (v3 - lo) / denom;
}

// ---------------------------------------------------------------------------
// K3a: spectral PE conv path -> pe2 [64][4096]; 4 positions per 256-thr block
// ---------------------------------------------------------------------------
__global__ __launch_bounds__(256) void k_pe(
    const float* __restrict__ omega,
    const float* __restrict__ w1, const float* __restrict__ b1,
    const float* __restrict__ w2, const float* __restrict__ b2,
    float* __restrict__ pe2) {
  int g = threadIdx.x >> 6;   // group 0..3
  int j = threadIdx.x & 63;
  int n = blockIdx.x * 4 + g;
  __shared__ float pec[4][3][64];
  __shared__ float hs[4][128];
  for (int t = 0; t < 3; ++t) {
    int m = n + t - 1;
    float v = 0.f;
    if (m >= 0 && m < NN) {
      int l1 = m >> 6, l2 = m & 63;
      float rel = (float)(l1 - l2);
      v = (j < 32) ? sinf(rel * omega[j]) : cosf(rel * omega[j - 32]);
    }
    pec[g][t][j] = v;
  }
  __syncthreads();
  for (int o = j; o < 128; o += 64) {
    int ci = o >> 1;
    float hv = b1[o];
    #pragma unroll
    for (int t = 0; t < 3; ++t) hv += pec[g][t][ci] * w1[o * 3 + t];
    hv = 0.5f * hv * (1.f + erff(hv * 0.70710678118654752f));
    hs[g][o] = hv;
  }
  __syncthreads();
  float acc = b2[j];
  for (int o = 0; o < 128; ++o) acc += hs[g][o] * w2[j * 128 + o];
  pe2[(size_t)j * NN + n] = acc;
}

// ---------------------------------------------------------------------------
// K3b: channel means -> sigmoid gate gpe[64]
// ---------------------------------------------------------------------------
__global__ void k_gatepe(const float* __restrict__ pe2,
                         const float* __restrict__ wg, const float* __restrict__ bg,
                         float* __restrict__ gpe) {
  int tid = threadIdx.x;  // 256
  int j = tid & 63, part = tid >> 6;
  float s = 0.f;
  const float* row = pe2 + (size_t)j * NN + part * 1024;
  for (int t = 0; t < 1024; ++t) s += row[t];
  __shared__ float ps[4][64];
  __shared__ float mean[64];
  ps[part][j] = s;
  __syncthreads();
  if (tid < 64) mean[j] = (ps[0][j] + ps[1][j] + ps[2][j] + ps[3][j]) * (1.f / 4096.f);
  __syncthreads();
  if (tid < 64) {
    float g = bg[j];
    for (int k2 = 0; k2 < 64; ++k2) g += wg[j * 64 + k2] * mean[k2];
    gpe[j] = 1.f / (1.f + expf(-g));
  }
}

// ---------------------------------------------------------------------------
// K3c: rope multiplier
// ---------------------------------------------------------------------------
__global__ void k_ropemul(const float* __restrict__ pe2, const float* __restrict__ gpe,
                          float* __restrict__ ropem) {
  int idx = blockIdx.x * 256 + threadIdx.x;
  int n = idx >> 6, dd = idx & 63;
  ropem[idx] = 1.f + pe2[(size_t)dd * NN + n] * gpe[n >> 6] * 0.35355339059327373f;
}

// Prep: f32 -> bf16 (weights, hi only)
__global__ void k_prep_h(const float* __restrict__ src,
                         ushort* __restrict__ Sh, int nelem) {
  int idx4 = (blockIdx.x * 256 + threadIdx.x) * 4;
  if (idx4 >= nelem) return;
  float4 v = *(const float4*)&src[idx4];
  ushort4 h;
  ((ushort*)&h)[0] = f2b(v.x);
  ((ushort*)&h)[1] = f2b(v.y);
  ((ushort*)&h)[2] = f2b(v.z);
  ((ushort*)&h)[3] = f2b(v.w);
  *(ushort4*)&Sh[idx4] = h;
}

// ---------------------------------------------------------------------------
// Prep: Wv^T (wqkv rows 1024..1535 transposed) -> bf16 hi/lo [512 c][512 c']
// ---------------------------------------------------------------------------
__global__ __launch_bounds__(256) void k_prep_wvt(const float* __restrict__ wqkv,
                                                  ushort* __restrict__ Wvth,
                                                  ushort* __restrict__ Wvtl) {
  int bx = blockIdx.x & 7;   // c tile
  int by = blockIdx.x >> 3;  // c' tile
  __shared__ float t[64][65];
  int tid = threadIdx.x;
  #pragma unroll
  for (int it = 0; it < 4; ++it) {
    int idx = tid + it * 256;
    int r = idx >> 4;
    int c4 = (idx & 15) * 4;
    float4 v = *(const float4*)&wqkv[(size_t)(1024 + by * 64 + r) * 512 + bx * 64 + c4];
    t[r][c4] = v.x; t[r][c4 + 1] = v.y; t[r][c4 + 2] = v.z; t[r][c4 + 3] = v.w;
  }
  __syncthreads();
  #pragma unroll
  for (int it = 0; it < 4; ++it) {
    int idx = tid + it * 256;
    int r = idx >> 4;
    int c4 = (idx & 15) * 4;
    ushort4 h4, l4;
    #pragma unroll
    for (int q = 0; q < 4; ++q) {
      float v = t[c4 + q][r];
      ushort hi = f2b(v);
      ((ushort*)&h4)[q] = hi;
      ((ushort*)&l4)[q] = f2b(v - b2f(hi));
    }
    size_t o = (size_t)(bx * 64 + r) * 512 + by * 64 + c4;
    *(ushort4*)&Wvth[o] = h4;
    *(ushort4*)&Wvtl[o] = l4;
  }
}

// ---------------------------------------------------------------------------
// Fat-M GEMM: 256 x BN tile, BK=32, 8 waves (4m x 2n), 512 threads, 2 LDS
// buffers, one __syncthreads per step, fully unrolled. Same zero-conflict
// swizzle as the 4-wave version. LDS 40-48 KB -> 2-3 blocks/CU; serial
// K-steps per CU halved vs the 128-tile version (the round-13 lever).
// EPI=1: qk epilogue (gate, elu+1, rope; q/k TRANSPOSED [bh][d][n], packed).
// EPI=2: out epilogue (gate*acc + beff[b][col], f32 out, per-batch B).
// ---------------------------------------------------------------------------
template <int BN, int EPI>
__global__ __launch_bounds__(512) void k_gemm8(
    const ushort* __restrict__ Ag, const ushort* __restrict__ Bgh,
    const float* __restrict__ bias, const float* __restrict__ gate,
    const float* __restrict__ ropem,
    float* __restrict__ outF, ushort* __restrict__ qT, ushort* __restrict__ kT,
    int ntn, int ncols) {
  constexpr int NF = BN / 32;      // n-frags per wave (wave covers BN/2 cols)
  constexpr int BCH = BN / 16;     // B chunks (512 elems each)
  const int nwg = gridDim.x;
  const int hw = blockIdx.x;
  const int logical = (hw & 7) * (nwg >> 3) + (hw >> 3);
  const int m0 = (logical / ntn) * 256, n0 = (logical % ntn) * BN;

  const int tid = threadIdx.x, wave = tid >> 6, lane = tid & 63;
  const int wm = wave >> 1, wn = wave & 1;
  __shared__ ushort sA[2][8192];
  __shared__ ushort sB[2][BN * 32];
  f32x4 acc[4][NF] = {};

  const int lr = lane >> 2;
  const int ci = lane & 3;
  const int scol = (ci ^ ((lr >> 1) & 3)) * 8;           // inverse-swz source col
  const int rA = lane & 15;
  const int cswz = ((lane >> 4) ^ ((rA >> 1) & 3)) * 8;  // read-side swizzle

  // A: 16 chunks (16 rows each); wave w stages chunks 2w, 2w+1.
  // B: BCH chunks; wave w stages chunk w (guarded when BCH < 8).
  const ushort* pA0 = Ag + (size_t)(m0 + (2 * wave) * 16 + lr) * CC + scol;
  const ushort* pA1 = Ag + (size_t)(m0 + (2 * wave + 1) * 16 + lr) * CC + scol;
  const ushort* Bh_ = Bgh + (EPI == 2 ? (size_t)(m0 >> 12) * 262144 : 0);
  const ushort* pB0 = Bh_ + (size_t)(n0 + wave * 16 + lr) * CC + scol;

#define STAGE(T, S)                                                        \
  {                                                                        \
    gload16(pA0 + (T) * 32, &sA[S][(2 * wave) * 512]);                     \
    gload16(pA1 + (T) * 32, &sA[S][(2 * wave + 1) * 512]);                 \
    if (BCH == 8) {                                                        \
      gload16(pB0 + (T) * 32, &sB[S][wave * 512]);                         \
    } else {                                                               \
      if (wave < BCH) gload16(pB0 + (T) * 32, &sB[S][wave * 512]);         \
    }                                                                      \
  }

  STAGE(0, 0);
  __syncthreads();  // tile 0 landed

  #pragma unroll
  for (int t = 0; t < 16; ++t) {
    if (t < 15) STAGE(t + 1, (t + 1) & 1);  // issue early; lands by barrier
    const int cur = t & 1;
    bf16x8 af[4], bhf[NF];
    #pragma unroll
    for (int m = 0; m < 4; ++m)
      af[m] = *(const bf16x8*)(&sA[cur][(wm * 64 + m * 16 + rA) * 32 + cswz]);
    #pragma unroll
    for (int n = 0; n < NF; ++n)
      bhf[n] = *(const bf16x8*)(&sB[cur][(wn * (BN / 2) + n * 16 + rA) * 32 + cswz]);
    #pragma unroll
    for (int m = 0; m < 4; ++m)
      #pragma unroll
      for (int n = 0; n < NF; ++n)
        acc[m][n] = __builtin_amdgcn_mfma_f32_16x16x32_bf16(af[m], bhf[n], acc[m][n], 0, 0, 0);
    __syncthreads();  // next tile landed; this tile's reads done
  }
#undef STAGE

  const int kj = lane >> 4, l15 = lane & 15;
  #pragma unroll
  for (int m = 0; m < 4; ++m) {
    #pragma unroll
    for (int n = 0; n < NF; ++n) {
      if (EPI == 2) {
        #pragma unroll
        for (int r = 0; r < 4; ++r) {
          int row = m0 + wm * 64 + m * 16 + kj * 4 + r;
          int col = n0 + wn * (BN / 2) + n * 16 + l15;
          int nseq = row & (NN - 1), b = row >> 12;
          float val = acc[m][n][r] * gate[nseq] + bias[b * 512 + col];
          outF[(size_t)row * ncols + col] = val;
        }
      } else {
        // qk: packed ushort4 store over 4 consecutive nseq
        int rowb = m0 + wm * 64 + m * 16 + kj * 4;
        int col = n0 + wn * (BN / 2) + n * 16 + l15;
        int nseqb = rowb & (NN - 1), b = rowb >> 12;
        int part = col >> 9, h = (col >> 6) & 7, dd = col & 63;
        ushort4 pk;
        #pragma unroll
        for (int r = 0; r < 4; ++r) {
          int nseq = nseqb + r;
          float val = acc[m][n][r] * gate[nseq] + bias[col];
          float e = val > 0.f ? val + 1.f : expf(val);  // elu+1
          ((ushort*)&pk)[r] = f2b(e * ropem[nseq * 64 + dd]);
        }
        ushort* dst = (part == 0 ? qT : kT) +
                      ((size_t)(b * HH + h) * DD + dd) * NN + nseqb;
        *(ushort4*)dst = pk;
      }
    }
  }
}

// ---------------------------------------------------------------------------
// 4-wave 128-tile GEMM kept for G2 (BTERMS=2, bf16 out).
// ---------------------------------------------------------------------------
__global__ __launch_bounds__(256) void k_gemm_g2(
    const ushort* __restrict__ Ag, const ushort* __restrict__ Bgh,
    const ushort* __restrict__ Bgl, ushort* __restrict__ outB, int ntn) {
  const int nwg = gridDim.x;
  const int hw = blockIdx.x;
  const int logical = (hw & 7) * (nwg >> 3) + (hw >> 3);
  const int m0 = (logical / ntn) * 128, n0 = (logical % ntn) * 128;

  const int tid = threadIdx.x, wave = tid >> 6, lane = tid & 63;
  const int wm = wave >> 1, wn = wave & 1;
  __shared__ ushort sA[2][4096];
  __shared__ ushort sB[2][8192];
  f32x4 acc[4][4] = {};

  const int lr = lane >> 2;
  const int ci = lane & 3;
  const int scol = (ci ^ ((lr >> 1) & 3)) * 8;
  const int rA = lane & 15;
  const int cswz = ((lane >> 4) ^ ((rA >> 1) & 3)) * 8;

  const int chunk0 = wave * 2, chunk1 = wave * 2 + 1;
  const ushort* pA0 = Ag + (size_t)(m0 + chunk0 * 16 + lr) * CC + scol;
  const ushort* pA1 = Ag + (size_t)(m0 + chunk1 * 16 + lr) * CC + scol;
  const ushort* pB0 = Bgh + (size_t)(n0 + chunk0 * 16 + lr) * CC + scol;
  const ushort* pB1 = Bgh + (size_t)(n0 + chunk1 * 16 + lr) * CC + scol;
  const ushort* pB0l = Bgl + (size_t)(n0 + chunk0 * 16 + lr) * CC + scol;
  const ushort* pB1l = Bgl + (size_t)(n0 + chunk1 * 16 + lr) * CC + scol;

#define STAGE(T, S)                                                        \
  {                                                                        \
    gload16(pA0 + (T) * 32, &sA[S][chunk0 * 512]);                         \
    gload16(pA1 + (T) * 32, &sA[S][chunk1 * 512]);                         \
    gload16(pB0 + (T) * 32, &sB[S][chunk0 * 512]);                         \
    gload16(pB1 + (T) * 32, &sB[S][chunk1 * 512]);                         \
    gload16(pB0l + (T) * 32, &sB[S][4096 + chunk0 * 512]);                 \
    gload16(pB1l + (T) * 32, &sB[S][4096 + chunk1 * 512]);                 \
  }

  STAGE(0, 0);
  __syncthreads();

  #pragma unroll
  for (int t = 0; t < 16; ++t) {
    if (t < 15) STAGE(t + 1, (t + 1) & 1);
    const int cur = t & 1;
    bf16x8 af[4], bh[4], bl[4];
    #pragma unroll
    for (int m = 0; m < 4; ++m)
      af[m] = *(const bf16x8*)(&sA[cur][(wm * 64 + m * 16 + rA) * 32 + cswz]);
    #pragma unroll
    for (int n = 0; n < 4; ++n) {
      int off = (wn * 64 + n * 16 + rA) * 32 + cswz;
      bh[n] = *(const bf16x8*)(&sB[cur][off]);
      bl[n] = *(const bf16x8*)(&sB[cur][4096 + off]);
    }
    #pragma unroll
    for (int m = 0; m < 4; ++m)
      #pragma unroll
      for (int n = 0; n < 4; ++n) {
        acc[m][n] = __builtin_amdgcn_mfma_f32_16x16x32_bf16(af[m], bh[n], acc[m][n], 0, 0, 0);
        acc[m][n] = __builtin_amdgcn_mfma_f32_16x16x32_bf16(af[m], bl[n], acc[m][n], 0, 0, 0);
      }
    __syncthreads();
  }
#undef STAGE

  const int kj = lane >> 4, l15 = lane & 15;
  #pragma unroll
  for (int m = 0; m < 4; ++m)
    #pragma unroll
    for (int n = 0; n < 4; ++n)
      #pragma unroll
      for (int r = 0; r < 4; ++r) {
        int row = m0 + wm * 64 + m * 16 + kj * 4 + r;
        int col = n0 + wn * 64 + n * 16 + l15;
        outB[(size_t)row * 512 + col] = f2b(acc[m][n][r]);
      }
}

// ---------------------------------------------------------------------------
// K5a: ctx via MFMA from global; 512 blocks, in-block LDS reduce.
// ---------------------------------------------------------------------------
__global__ __launch_bounds__(256) void k_ctx_mfma(
    const ushort* __restrict__ qT, const ushort* __restrict__ kT,
    float* __restrict__ ctxp) {
  int blk = blockIdx.x;
  int bh = blk >> 4, chunk = blk & 15;
  int wave = threadIdx.x >> 6, lane = threadIdx.x & 63;
  int l15 = lane & 15, kj = lane >> 4;
  const size_t base = (size_t)bh * DD * NN;
  const int n0 = chunk * 256 + wave * 64;
  f32x4 acc[4][4] = {};
  #pragma unroll
  for (int ks = 0; ks < 2; ++ks) {
    const int nb = n0 + ks * 32 + kj * 8;
    bf16x8 qa[4], ka[4];
    #pragma unroll
    for (int m = 0; m < 4; ++m)
      qa[m] = *(const bf16x8*)(qT + base + (size_t)(m * 16 + l15) * NN + nb);
    #pragma unroll
    for (int n = 0; n < 4; ++n)
      ka[n] = *(const bf16x8*)(kT + base + (size_t)(n * 16 + l15) * NN + nb);
    #pragma unroll
    for (int m = 0; m < 4; ++m)
      #pragma unroll
      for (int n = 0; n < 4; ++n)
        acc[m][n] = __builtin_amdgcn_mfma_f32_16x16x32_bf16(qa[m], ka[n], acc[m][n], 0, 0, 0);
  }
  __shared__ float red[4][4096];
  #pragma unroll
  for (int m = 0; m < 4; ++m)
    #pragma unroll
    for (int n = 0; n < 4; ++n)
      #pragma unroll
      for (int r = 0; r < 4; ++r)
        red[wave][(m * 16 + kj * 4 + r) * 64 + n * 16 + l15] = acc[m][n][r];
  __syncthreads();
  const float scale = 1.f / 512.f;
  float* dst = ctxp + (size_t)(bh * 16 + chunk) * 4096;
  #pragma unroll
  for (int e = 0; e < 16; ++e) {
    int idx = threadIdx.x + e * 256;
    float s = red[0][idx] + red[1][idx] + red[2][idx] + red[3][idx];
    dst[idx] = s * scale;
  }
}

// K5b: reduce 16 partials -> ctx[bh][64][64]; one thread per element
__global__ void k_ctx_red(const float* __restrict__ ctxp, float* __restrict__ ctx) {
  int idx = blockIdx.x * 256 + threadIdx.x;  // 0..131071
  int bh = idx >> 12, off = idx & 4095;
  float s = 0.f;
  #pragma unroll
  for (int c2 = 0; c2 < 16; ++c2)
    s += ctxp[((size_t)bh * 16 + c2) * 4096 + off];
  ctx[idx] = s;
}

// ---------------------------------------------------------------------------
// K6: Mf[b][o][h*64+d] = (1/512)*sum_e ctx[b,h,d,e]*wp[o,h*64+e]; bf16 hi/lo.
// ---------------------------------------------------------------------------
__global__ __launch_bounds__(256) void k_mproj(
    const float* __restrict__ ctx, const float* __restrict__ wp,
    ushort* __restrict__ Mfh, ushort* __restrict__ Mfl) {
  int blk = blockIdx.x;
  int b = blk >> 6, h = (blk >> 3) & 7, oq = blk & 7;
  int tid = threadIdx.x;
  int o = oq * 64 + (tid & 63);
  int d0 = (tid >> 6) * 16;
  __shared__ float cs[64][64];
  #pragma unroll
  for (int it = 0; it < 4; ++it) {
    int idx = (tid + 256 * it) * 4;
    *(float4*)&cs[idx >> 6][idx & 63] =
        *(const float4*)&ctx[(size_t)(b * 8 + h) * 4096 + idx];
  }
  __syncthreads();
  float wv[64];
  #pragma unroll
  for (int e = 0; e < 64; ++e) wv[e] = wp[(size_t)o * 512 + h * 64 + e];
  for (int d = d0; d < d0 + 16; ++d) {
    float s = 0.f;
    #pragma unroll
    for (int e = 0; e < 64; ++e) s += cs[d][e] * wv[e];
    s *= (1.f / 512.f);
    ushort hi = f2b(s);
    size_t idx = ((size_t)b * 512 + o) * 512 + h * 64 + d;
    Mfh[idx] = hi;
    Mfl[idx] = f2b(s - b2f(hi));
  }
}

// K8: beff[b][o] = sum_c' bqkv[1024+c'] * Mf[b][o][c'] + bproj[o]
__global__ void k_beff(const ushort* __restrict__ Mfh, const ushort* __restrict__ Mfl,
                       const float* __restrict__ bqkv,
                       const float* __restrict__ bproj, float* __restrict__ beff) {
  int w = threadIdx.x >> 6, lane = threadIdx.x & 63;
  int t = blockIdx.x * 4 + w;  // 0..2047
  int b = t >> 9, o = t & 511;
  size_t base = ((size_t)b * 512 + o) * 512;
  float s = 0.f;
  #pragma unroll
  for (int c = 0; c < 512; c += 64) {
    float m = b2f(Mfh[base + c + lane]) + b2f(Mfl[base + c + lane]);
    s += bqkv[1024 + c + lane] * m;
  }
  #pragma unroll
  for (int off = 32; off > 0; off >>= 1) s += __shfl_down(s, off);
  if (lane == 0) beff[t] = s + bproj[o];
}

// ---------------------------------------------------------------------------
extern "C" void kernel_launch(void* const* d_in, const int* in_sizes, int n_in,
                              void* d_out, int out_size, void* d_ws, size_t ws_size,
                              hipStream_t stream) {
  const float* x    = (const float*)d_in[0];
  const float* lpw  = (const float*)d_in[1];
  const float* lvw  = (const float*)d_in[2];
  const float* wqkv = (const float*)d_in[3];
  const float* bqkv = (const float*)d_in[4];
  const float* wproj= (const float*)d_in[5];
  const float* bproj= (const float*)d_in[6];
  const float* omega= (const float*)d_in[7];
  const float* w1   = (const float*)d_in[8];
  const float* b1   = (const float*)d_in[9];
  const float* w2   = (const float*)d_in[10];
  const float* b2   = (const float*)d_in[11];
  const float* wg   = (const float*)d_in[12];
  const float* bg   = (const float*)d_in[13];
  float* out = (float*)d_out;

  constexpr size_t MB = 1024 * 1024;
  char* w = (char*)d_ws;
  int*   pcntP  = (int*)(w);                      // 64 KiB
  int*   pcntV  = (int*)(w + 64 * 1024);          // 64 KiB
  float* attn   = (float*)(w + 128 * 1024);
  float* gate   = (float*)(w + 144 * 1024);
  float* etabP  = (float*)(w + 160 * 1024);
  float* etabV  = (float*)(w + 176 * 1024);
  float* fcntP  = (float*)(w + 192 * 1024);
  float* fcntV  = (float*)(w + 208 * 1024);
  float* pe2    = (float*)(w + 256 * 1024);       // 1 MiB
  float* gpe    = (float*)(w + 1280 * 1024);
  float* ropem  = (float*)(w + 1344 * 1024);      // 1 MiB
  ushort* Xh    = (ushort*)(w + 4 * MB);          // 16 MiB
  ushort* qT    = (ushort*)(w + 20 * MB);         // 16 MiB [B,H,D,N]
  ushort* kT    = (ushort*)(w + 36 * MB);         // 16 MiB
  ushort* Whqk  = (ushort*)(w + 52 * MB);         // 1 MiB
  ushort* Wvth  = (ushort*)(w + 53 * MB);         // 0.5 MiB
  ushort* Wvtl  = (ushort*)(w + 53 * MB + 512 * 1024);  // 0.5 MiB
  ushort* Mfh   = (ushort*)(w + 54 * MB);         // 2 MiB [B*512][512]
  ushort* Mfl   = (ushort*)(w + 56 * MB);         // 2 MiB
  ushort* G2h   = (ushort*)(w + 58 * MB);         // 2 MiB
  float* beff   = (float*)(w + 60 * MB);          // 8 KiB
  float* ctxp   = (float*)(w + 61 * MB);          // 8 MiB
  float* ctx    = (float*)(w + 69 * MB);          // 0.5 MiB -> 69.5 MiB

  k_counts_prep<<<BB * 256, 512, 0, stream>>>(x, pcntP, pcntV, Xh);
  k_etab2<<<16, 256, 0, stream>>>(lpw, lvw, pcntP, pcntV, etabP, etabV, fcntP, fcntV);
  k_gsum<<<NN, 256, 0, stream>>>(fcntP, fcntV, etabP, etabV, attn);
  k_norm<<<1, 1024, 0, stream>>>(attn, gate);
  k_pe<<<1024, 256, 0, stream>>>(omega, w1, b1, w2, b2, pe2);
  k_gatepe<<<1, 256, 0, stream>>>(pe2, wg, bg, gpe);
  k_ropemul<<<1024, 256, 0, stream>>>(pe2, gpe, ropem);
  k_prep_h<<<512, 256, 0, stream>>>(wqkv, Whqk, 1024 * CC);
  k_prep_wvt<<<64, 256, 0, stream>>>(wqkv, Wvth, Wvtl);

  // q,k GEMM: M=16384, N=1024 -> 64 x 8 = 512 blocks (2/CU), 512 threads
  k_gemm8<128, 1><<<512, 512, 0, stream>>>(Xh, Whqk, bqkv, gate, ropem,
                                           nullptr, qT, kT, 8, 0);
  k_ctx_mfma<<<512, 256, 0, stream>>>(qT, kT, ctxp);
  k_ctx_red<<<512, 256, 0, stream>>>(ctxp, ctx);
  k_mproj<<<256, 256, 0, stream>>>(ctx, wproj, Mfh, Mfl);
  // G2 = Mf * Wv^T via MFMA (2-term B): M=2048, N=512 -> 64 blocks
  k_gemm_g2<<<64, 256, 0, stream>>>(Mfh, Wvth, Wvtl, G2h, 4);
  k_beff<<<512, 256, 0, stream>>>(Mfh, Mfl, bqkv, bproj, beff);

  // out GEMM: out = gate*(Xh * G2_b^T) + beff; M=16384, N=512 -> BN=64,
  // 64 x 8 = 512 blocks (2/CU), 512 threads
  k_gemm8<64, 2><<<512, 512, 0, stream>>>(Xh, G2h, beff, gate, nullptr,
                                          out, nullptr, nullptr, 8, 512);
}

// Round 15
// 169.276 us; speedup vs baseline: 2.0219x; 1.0557x over previous
//
#include <hip/hip_runtime.h>
#include <hip/hip_bf16.h>
#include <math.h>

constexpr int BB = 4;
constexpr int NN = 4096;
constexpr int CC = 512;
constexpr int HH = 8;
constexpr int DD = 64;
constexpr int NCNT = NN - 2;

typedef __bf16 bf16x8 __attribute__((ext_vector_type(8)));
typedef float f32x4 __attribute__((ext_vector_type(4)));

__device__ __forceinline__ float b2f(ushort u) {
  unsigned v = ((unsigned)u) << 16;
  return __builtin_bit_cast(float, v);
}
__device__ __forceinline__ ushort f2b(float f) {
  __hip_bfloat16 h = __float2bfloat16(f);
  return __builtin_bit_cast(ushort, h);
}
__device__ __forceinline__ void gload16(const ushort* g, ushort* l) {
  __builtin_amdgcn_global_load_lds(
      (const __attribute__((address_space(1))) unsigned int*)g,
      (__attribute__((address_space(3))) unsigned int*)l, 16, 0, 0);
}

// ---------------------------------------------------------------------------
// K_FRONT: fused independent prep work, branch on blockIdx.
//   [0,1024)    counts_prep: second-diff sign counts + x -> bf16
//   [1024,1536) pe: spectral PE conv path (8 positions per block)
//   [1536,1792) prep_h: wqkv rows 0..1023 -> bf16
//   [1792,1856) prep_wvt: Wv^T -> bf16 hi/lo
// ---------------------------------------------------------------------------
__global__ __launch_bounds__(512) void k_front(
    const float* __restrict__ x, int* __restrict__ pcntP,
    int* __restrict__ pcntV, ushort* __restrict__ Xh,
    const float* __restrict__ omega,
    const float* __restrict__ w1, const float* __restrict__ b1,
    const float* __restrict__ w2, const float* __restrict__ b2,
    float* __restrict__ pe2,
    const float* __restrict__ wqkv, ushort* __restrict__ Whqk,
    ushort* __restrict__ Wvth, ushort* __restrict__ Wvtl) {
  __shared__ __attribute__((aligned(16))) char sm[16896];
  const int blk = blockIdx.x;
  const int tid = threadIdx.x;

  if (blk < 1024) {
    // ---- counts_prep ----
    int b = blk >> 8;
    int tile = blk & 255;
    int c = tid;
    int lane = tid & 63;
    int i0 = tile * 16;
    const float* xb = x + (size_t)b * NN * CC + c;

    float v[18];
    #pragma unroll
    for (int r = 0; r < 18; ++r) {
      int i = i0 + r;
      v[r] = xb[(size_t)(i < NN ? i : NN - 1) * CC];
    }
    #pragma unroll
    for (int r = 0; r < 16; ++r)
      Xh[((size_t)b * NN + i0 + r) * CC + c] = f2b(v[r]);

    int* redP = (int*)sm;
    int* redV = redP + 16;
    if (tid < 16) { redP[tid] = 0; redV[tid] = 0; }
    __syncthreads();
    #pragma unroll
    for (int r = 0; r < 16; ++r) {
      int i = i0 + r;
      if (i < NCNT) {
        float d2 = (v[r + 2] - v[r + 1]) - (v[r + 1] - v[r]);
        unsigned long long mneg = __ballot(d2 < 0.0f);
        unsigned long long mpos = __ballot(d2 > 0.0f);
        if (lane == 0) {
          atomicAdd(&redP[r], __popcll(mneg));
          atomicAdd(&redV[r], __popcll(mpos));
        }
      }
    }
    __syncthreads();
    if (tid < 16) {
      int i = i0 + tid;
      pcntP[b * NN + i] = (i < NCNT) ? redP[tid] : 0;
      pcntV[b * NN + i] = (i < NCNT) ? redV[tid] : 0;
    }
  } else if (blk < 1536) {
    // ---- pe: 8 positions per 512-thr block ----
    int pblk = blk - 1024;
    int g = tid >> 6;        // 0..7
    int j = tid & 63;
    int n = pblk * 8 + g;
    float (*pec)[3][64] = (float (*)[3][64])sm;            // 8*3*64*4 = 6144 B
    float (*hs)[128] = (float (*)[128])(sm + 6144);        // 8*128*4 = 4096 B
    for (int t = 0; t < 3; ++t) {
      int m = n + t - 1;
      float v = 0.f;
      if (m >= 0 && m < NN) {
        int l1 = m >> 6, l2 = m & 63;
        float rel = (float)(l1 - l2);
        v = (j < 32) ? sinf(rel * omega[j]) : cosf(rel * omega[j - 32]);
      }
      pec[g][t][j] = v;
    }
    __syncthreads();
    for (int o = j; o < 128; o += 64) {
      int ci = o >> 1;
      float hv = b1[o];
      #pragma unroll
      for (int t = 0; t < 3; ++t) hv += pec[g][t][ci] * w1[o * 3 + t];
      hv = 0.5f * hv * (1.f + erff(hv * 0.70710678118654752f));
      hs[g][o] = hv;
    }
    __syncthreads();
    float acc = b2[j];
    for (int o = 0; o < 128; ++o) acc += hs[g][o] * w2[j * 128 + o];
    pe2[(size_t)j * NN + n] = acc;
  } else if (blk < 1792) {
    // ---- prep_h: wqkv rows 0..1023 -> bf16 ----
    int hblk = blk - 1536;
    int idx4 = (hblk * 512 + tid) * 4;   // covers 1024*512 exactly
    float4 v = *(const float4*)&wqkv[idx4];
    ushort4 h;
    ((ushort*)&h)[0] = f2b(v.x);
    ((ushort*)&h)[1] = f2b(v.y);
    ((ushort*)&h)[2] = f2b(v.z);
    ((ushort*)&h)[3] = f2b(v.w);
    *(ushort4*)&Whqk[idx4] = h;
  } else {
    // ---- prep_wvt (256 active threads, block-uniform barriers) ----
    int wblk = blk - 1792;
    int bx = wblk & 7;   // c tile
    int by = wblk >> 3;  // c' tile
    float (*t)[65] = (float (*)[65])sm;  // 64*65*4 = 16640 B
    if (tid < 256) {
      #pragma unroll
      for (int it = 0; it < 4; ++it) {
        int idx = tid + it * 256;
        int r = idx >> 4;
        int c4 = (idx & 15) * 4;
        float4 v = *(const float4*)&wqkv[(size_t)(1024 + by * 64 + r) * 512 + bx * 64 + c4];
        t[r][c4] = v.x; t[r][c4 + 1] = v.y; t[r][c4 + 2] = v.z; t[r][c4 + 3] = v.w;
      }
    }
    __syncthreads();
    if (tid < 256) {
      #pragma unroll
      for (int it = 0; it < 4; ++it) {
        int idx = tid + it * 256;
        int r = idx >> 4;
        int c4 = (idx & 15) * 4;
        ushort4 h4, l4;
        #pragma unroll
        for (int q = 0; q < 4; ++q) {
          float v = t[c4 + q][r];
          ushort hi = f2b(v);
          ((ushort*)&h4)[q] = hi;
          ((ushort*)&l4)[q] = f2b(v - b2f(hi));
        }
        size_t o = (size_t)(bx * 64 + r) * 512 + by * 64 + c4;
        *(ushort4*)&Wvth[o] = h4;
        *(ushort4*)&Wvtl[o] = l4;
      }
    }
  }
}

// ---------------------------------------------------------------------------
// K_MID1: blk 0..15 etab2, blk 16 gatepe.
// ---------------------------------------------------------------------------
__global__ __launch_bounds__(256) void k_mid1(
    const float* __restrict__ lpw, const float* __restrict__ lvw,
    const int* __restrict__ pcntP, const int* __restrict__ pcntV,
    float* __restrict__ etabP, float* __restrict__ etabV,
    float* __restrict__ fcntP, float* __restrict__ fcntV,
    const float* __restrict__ pe2, const float* __restrict__ wg,
    const float* __restrict__ bg, float* __restrict__ gpe) {
  const int blk = blockIdx.x;
  const int tid = threadIdx.x;
  if (blk < 16) {
    int i = blk * 256 + tid;
    float ipw = expf(-lpw[0]);
    float ivw = expf(-lvw[0]);
    float t1 = (float)i * ipw;
    float t2 = (float)i * ivw;
    etabP[i] = expf(-t1 * t1);
    etabV[i] = expf(-t2 * t2);
    fcntP[i] = (float)(pcntP[i] + pcntP[NN + i] + pcntP[2 * NN + i] + pcntP[3 * NN + i]);
    fcntV[i] = (float)(pcntV[i] + pcntV[NN + i] + pcntV[2 * NN + i] + pcntV[3 * NN + i]);
  } else {
    int j = tid & 63, part = tid >> 6;
    float s = 0.f;
    const float* row = pe2 + (size_t)j * NN + part * 1024;
    for (int t = 0; t < 1024; ++t) s += row[t];
    __shared__ float ps[4][64];
    __shared__ float mean[64];
    ps[part][j] = s;
    __syncthreads();
    if (tid < 64) mean[j] = (ps[0][j] + ps[1][j] + ps[2][j] + ps[3][j]) * (1.f / 4096.f);
    __syncthreads();
    if (tid < 64) {
      float g = bg[j];
      for (int k2 = 0; k2 < 64; ++k2) g += wg[j * 64 + k2] * mean[k2];
      gpe[j] = 1.f / (1.f + expf(-g));
    }
  }
}

// ---------------------------------------------------------------------------
// K_MID2: blk 0..4095 gsum, blk 4096..5119 ropemul.
// ---------------------------------------------------------------------------
__global__ __launch_bounds__(256) void k_mid2(
    const float* __restrict__ fcntP, const float* __restrict__ fcntV,
    const float* __restrict__ etabP, const float* __restrict__ etabV,
    float* __restrict__ attn,
    const float* __restrict__ pe2, const float* __restrict__ gpe,
    float* __restrict__ ropem) {
  const int blk = blockIdx.x;
  const int tid = threadIdx.x;
  if (blk < 4096) {
    int p = blk;
    float acc = 0.f;
    for (int i = tid; i < NCNT; i += 256) {
      int a = p - 1 - i;
      a = a < 0 ? -a : a;
      acc += fcntP[i] * etabP[a] + fcntV[i] * etabV[a];
    }
    __shared__ float red[256];
    red[tid] = acc;
    __syncthreads();
    for (int s = 128; s > 0; s >>= 1) {
      if (tid < s) red[tid] += red[tid + s];
      __syncthreads();
    }
    if (tid == 0) attn[p] = red[0];
  } else {
    int idx = (blk - 4096) * 256 + tid;
    int n = idx >> 6, dd = idx & 63;
    ropem[idx] = 1.f + pe2[(size_t)dd * NN + n] * gpe[n >> 6] * 0.35355339059327373f;
  }
}

// ---------------------------------------------------------------------------
// K2b: min-max normalize
// ---------------------------------------------------------------------------
__global__ void k_norm(const float* __restrict__ attn, float* __restrict__ gate) {
  int tid = threadIdx.x;  // 1024
  float v0 = attn[tid], v1 = attn[tid + 1024], v2 = attn[tid + 2048], v3 = attn[tid + 3072];
  float mn = fminf(fminf(v0, v1), fminf(v2, v3));
  float mx = fmaxf(fmaxf(v0, v1), fmaxf(v2, v3));
  __shared__ float rmn[1024], rmx[1024];
  rmn[tid] = mn; rmx[tid] = mx;
  __syncthreads();
  for (int s = 512; s > 0; s >>= 1) {
    if (tid < s) {
      rmn[tid] = fminf(rmn[tid], rmn[tid + s]);
      rmx[tid] = fmaxf(rmx[tid], rmx[tid + s]);
    }
    __syncthreads();
  }
  float lo = rmn[0];
  float denom = rmx[0] - rmn[0] + 1e-6f;
  gate[tid]        = (v0 - lo) / denom;
  gate[tid + 1024] = (v1 - lo) / denom;
  gate[tid + 2048] = (v2 - lo) / denom;
  gate[tid + 3072] = (v3 - lo) / denom;
}

// ---------------------------------------------------------------------------
// Fat-M GEMM: 256 x BN tile, BK=32, 8 waves (4m x 2n), 512 threads, 2 LDS
// buffers, one __syncthreads per step, fully unrolled, zero-conflict swizzle.
// EPI=1: qk epilogue (gate, elu+1, rope; q/k TRANSPOSED [bh][d][n], packed).
// EPI=2: out epilogue (gate*acc + beff[b][col], f32 out, per-batch B).
// ---------------------------------------------------------------------------
template <int BN, int EPI>
__global__ __launch_bounds__(512) void k_gemm8(
    const ushort* __restrict__ Ag, const ushort* __restrict__ Bgh,
    const float* __restrict__ bias, const float* __restrict__ gate,
    const float* __restrict__ ropem,
    float* __restrict__ outF, ushort* __restrict__ qT, ushort* __restrict__ kT,
    int ntn, int ncols) {
  constexpr int NF = BN / 32;
  constexpr int BCH = BN / 16;
  const int nwg = gridDim.x;
  const int hw = blockIdx.x;
  const int logical = (hw & 7) * (nwg >> 3) + (hw >> 3);
  const int m0 = (logical / ntn) * 256, n0 = (logical % ntn) * BN;

  const int tid = threadIdx.x, wave = tid >> 6, lane = tid & 63;
  const int wm = wave >> 1, wn = wave & 1;
  __shared__ ushort sA[2][8192];
  __shared__ ushort sB[2][BN * 32];
  f32x4 acc[4][NF] = {};

  const int lr = lane >> 2;
  const int ci = lane & 3;
  const int scol = (ci ^ ((lr >> 1) & 3)) * 8;
  const int rA = lane & 15;
  const int cswz = ((lane >> 4) ^ ((rA >> 1) & 3)) * 8;

  const ushort* pA0 = Ag + (size_t)(m0 + (2 * wave) * 16 + lr) * CC + scol;
  const ushort* pA1 = Ag + (size_t)(m0 + (2 * wave + 1) * 16 + lr) * CC + scol;
  const ushort* Bh_ = Bgh + (EPI == 2 ? (size_t)(m0 >> 12) * 262144 : 0);
  const ushort* pB0 = Bh_ + (size_t)(n0 + wave * 16 + lr) * CC + scol;

#define STAGE(T, S)                                                        \
  {                                                                        \
    gload16(pA0 + (T) * 32, &sA[S][(2 * wave) * 512]);                     \
    gload16(pA1 + (T) * 32, &sA[S][(2 * wave + 1) * 512]);                 \
    if (BCH == 8) {                                                        \
      gload16(pB0 + (T) * 32, &sB[S][wave * 512]);                         \
    } else {                                                               \
      if (wave < BCH) gload16(pB0 + (T) * 32, &sB[S][wave * 512]);         \
    }                                                                      \
  }

  STAGE(0, 0);
  __syncthreads();

  #pragma unroll
  for (int t = 0; t < 16; ++t) {
    if (t < 15) STAGE(t + 1, (t + 1) & 1);
    const int cur = t & 1;
    bf16x8 af[4], bhf[NF];
    #pragma unroll
    for (int m = 0; m < 4; ++m)
      af[m] = *(const bf16x8*)(&sA[cur][(wm * 64 + m * 16 + rA) * 32 + cswz]);
    #pragma unroll
    for (int n = 0; n < NF; ++n)
      bhf[n] = *(const bf16x8*)(&sB[cur][(wn * (BN / 2) + n * 16 + rA) * 32 + cswz]);
    #pragma unroll
    for (int m = 0; m < 4; ++m)
      #pragma unroll
      for (int n = 0; n < NF; ++n)
        acc[m][n] = __builtin_amdgcn_mfma_f32_16x16x32_bf16(af[m], bhf[n], acc[m][n], 0, 0, 0);
    __syncthreads();
  }
#undef STAGE

  const int kj = lane >> 4, l15 = lane & 15;
  #pragma unroll
  for (int m = 0; m < 4; ++m) {
    #pragma unroll
    for (int n = 0; n < NF; ++n) {
      if (EPI == 2) {
        #pragma unroll
        for (int r = 0; r < 4; ++r) {
          int row = m0 + wm * 64 + m * 16 + kj * 4 + r;
          int col = n0 + wn * (BN / 2) + n * 16 + l15;
          int nseq = row & (NN - 1), b = row >> 12;
          float val = acc[m][n][r] * gate[nseq] + bias[b * 512 + col];
          outF[(size_t)row * ncols + col] = val;
        }
      } else {
        int rowb = m0 + wm * 64 + m * 16 + kj * 4;
        int col = n0 + wn * (BN / 2) + n * 16 + l15;
        int nseqb = rowb & (NN - 1), b = rowb >> 12;
        int part = col >> 9, h = (col >> 6) & 7, dd = col & 63;
        ushort4 pk;
        #pragma unroll
        for (int r = 0; r < 4; ++r) {
          int nseq = nseqb + r;
          float val = acc[m][n][r] * gate[nseq] + bias[col];
          float e = val > 0.f ? val + 1.f : expf(val);  // elu+1
          ((ushort*)&pk)[r] = f2b(e * ropem[nseq * 64 + dd]);
        }
        ushort* dst = (part == 0 ? qT : kT) +
                      ((size_t)(b * HH + h) * DD + dd) * NN + nseqb;
        *(ushort4*)dst = pk;
      }
    }
  }
}

// ---------------------------------------------------------------------------
// K5a: ctx via MFMA from global; 512 blocks, in-block LDS reduce.
// ---------------------------------------------------------------------------
__global__ __launch_bounds__(256) void k_ctx_mfma(
    const ushort* __restrict__ qT, const ushort* __restrict__ kT,
    float* __restrict__ ctxp) {
  int blk = blockIdx.x;
  int bh = blk >> 4, chunk = blk & 15;
  int wave = threadIdx.x >> 6, lane = threadIdx.x & 63;
  int l15 = lane & 15, kj = lane >> 4;
  const size_t base = (size_t)bh * DD * NN;
  const int n0 = chunk * 256 + wave * 64;
  f32x4 acc[4][4] = {};
  #pragma unroll
  for (int ks = 0; ks < 2; ++ks) {
    const int nb = n0 + ks * 32 + kj * 8;
    bf16x8 qa[4], ka[4];
    #pragma unroll
    for (int m = 0; m < 4; ++m)
      qa[m] = *(const bf16x8*)(qT + base + (size_t)(m * 16 + l15) * NN + nb);
    #pragma unroll
    for (int n = 0; n < 4; ++n)
      ka[n] = *(const bf16x8*)(kT + base + (size_t)(n * 16 + l15) * NN + nb);
    #pragma unroll
    for (int m = 0; m < 4; ++m)
      #pragma unroll
      for (int n = 0; n < 4; ++n)
        acc[m][n] = __builtin_amdgcn_mfma_f32_16x16x32_bf16(qa[m], ka[n], acc[m][n], 0, 0, 0);
  }
  __shared__ float red[4][4096];
  #pragma unroll
  for (int m = 0; m < 4; ++m)
    #pragma unroll
    for (int n = 0; n < 4; ++n)
      #pragma unroll
      for (int r = 0; r < 4; ++r)
        red[wave][(m * 16 + kj * 4 + r) * 64 + n * 16 + l15] = acc[m][n][r];
  __syncthreads();
  const float scale = 1.f / 512.f;
  float* dst = ctxp + (size_t)(bh * 16 + chunk) * 4096;
  #pragma unroll
  for (int e = 0; e < 16; ++e) {
    int idx = threadIdx.x + e * 256;
    float s = red[0][idx] + red[1][idx] + red[2][idx] + red[3][idx];
    dst[idx] = s * scale;
  }
}

// K5b: reduce 16 partials -> ctx[bh][64][64]
__global__ void k_ctx_red(const float* __restrict__ ctxp, float* __restrict__ ctx) {
  int idx = blockIdx.x * 256 + threadIdx.x;
  int bh = idx >> 12, off = idx & 4095;
  float s = 0.f;
  #pragma unroll
  for (int c2 = 0; c2 < 16; ++c2)
    s += ctxp[((size_t)bh * 16 + c2) * 4096 + off];
  ctx[idx] = s;
}

// ---------------------------------------------------------------------------
// K6: Mf[b][o][h*64+d] = (1/512)*sum_e ctx[b,h,d,e]*wp[o,h*64+e]; bf16 hi/lo.
// ---------------------------------------------------------------------------
__global__ __launch_bounds__(256) void k_mproj(
    const float* __restrict__ ctx, const float* __restrict__ wp,
    ushort* __restrict__ Mfh, ushort* __restrict__ Mfl) {
  int blk = blockIdx.x;
  int b = blk >> 6, h = (blk >> 3) & 7, oq = blk & 7;
  int tid = threadIdx.x;
  int o = oq * 64 + (tid & 63);
  int d0 = (tid >> 6) * 16;
  __shared__ float cs[64][64];
  #pragma unroll
  for (int it = 0; it < 4; ++it) {
    int idx = (tid + 256 * it) * 4;
    *(float4*)&cs[idx >> 6][idx & 63] =
        *(const float4*)&ctx[(size_t)(b * 8 + h) * 4096 + idx];
  }
  __syncthreads();
  float wv[64];
  #pragma unroll
  for (int e = 0; e < 64; ++e) wv[e] = wp[(size_t)o * 512 + h * 64 + e];
  for (int d = d0; d < d0 + 16; ++d) {
    float s = 0.f;
    #pragma unroll
    for (int e = 0; e < 64; ++e) s += cs[d][e] * wv[e];
    s *= (1.f / 512.f);
    ushort hi = f2b(s);
    size_t idx = ((size_t)b * 512 + o) * 512 + h * 64 + d;
    Mfh[idx] = hi;
    Mfl[idx] = f2b(s - b2f(hi));
  }
}

// ---------------------------------------------------------------------------
// K_TAIL: blk 0..63 g2 (4-wave 128-tile MFMA GEMM, 2-term B, bf16 out);
//         blk 64..575 beff.
// ---------------------------------------------------------------------------
__global__ __launch_bounds__(256) void k_tail(
    const ushort* __restrict__ Mfh, const ushort* __restrict__ Mfl,
    const ushort* __restrict__ Wvth, const ushort* __restrict__ Wvtl,
    ushort* __restrict__ G2h,
    const float* __restrict__ bqkv, const float* __restrict__ bproj,
    float* __restrict__ beff) {
  const int blk = blockIdx.x;
  if (blk < 64) {
    const int logical = (blk & 7) * 8 + (blk >> 3);
    const int m0 = (logical / 4) * 128, n0 = (logical % 4) * 128;
    const int tid = threadIdx.x, wave = tid >> 6, lane = tid & 63;
    const int wm = wave >> 1, wn = wave & 1;
    __shared__ ushort sA[2][4096];
    __shared__ ushort sB[2][8192];
    f32x4 acc[4][4] = {};

    const int lr = lane >> 2;
    const int ci = lane & 3;
    const int scol = (ci ^ ((lr >> 1) & 3)) * 8;
    const int rA = lane & 15;
    const int cswz = ((lane >> 4) ^ ((rA >> 1) & 3)) * 8;

    const int chunk0 = wave * 2, chunk1 = wave * 2 + 1;
    const ushort* pA0 = Mfh + (size_t)(m0 + chunk0 * 16 + lr) * CC + scol;
    const ushort* pA1 = Mfh + (size_t)(m0 + chunk1 * 16 + lr) * CC + scol;
    const ushort* pB0 = Wvth + (size_t)(n0 + chunk0 * 16 + lr) * CC + scol;
    const ushort* pB1 = Wvth + (size_t)(n0 + chunk1 * 16 + lr) * CC + scol;
    const ushort* pB0l = Wvtl + (size_t)(n0 + chunk0 * 16 + lr) * CC + scol;
    const ushort* pB1l = Wvtl + (size_t)(n0 + chunk1 * 16 + lr) * CC + scol;

#define STAGE(T, S)                                                        \
    {                                                                      \
      gload16(pA0 + (T) * 32, &sA[S][chunk0 * 512]);                       \
      gload16(pA1 + (T) * 32, &sA[S][chunk1 * 512]);                       \
      gload16(pB0 + (T) * 32, &sB[S][chunk0 * 512]);                       \
      gload16(pB1 + (T) * 32, &sB[S][chunk1 * 512]);                       \
      gload16(pB0l + (T) * 32, &sB[S][4096 + chunk0 * 512]);               \
      gload16(pB1l + (T) * 32, &sB[S][4096 + chunk1 * 512]);               \
    }

    STAGE(0, 0);
    __syncthreads();
    #pragma unroll
    for (int t = 0; t < 16; ++t) {
      if (t < 15) STAGE(t + 1, (t + 1) & 1);
      const int cur = t & 1;
      bf16x8 af[4], bh[4], bl[4];
      #pragma unroll
      for (int m = 0; m < 4; ++m)
        af[m] = *(const bf16x8*)(&sA[cur][(wm * 64 + m * 16 + rA) * 32 + cswz]);
      #pragma unroll
      for (int n = 0; n < 4; ++n) {
        int off = (wn * 64 + n * 16 + rA) * 32 + cswz;
        bh[n] = *(const bf16x8*)(&sB[cur][off]);
        bl[n] = *(const bf16x8*)(&sB[cur][4096 + off]);
      }
      #pragma unroll
      for (int m = 0; m < 4; ++m)
        #pragma unroll
        for (int n = 0; n < 4; ++n) {
          acc[m][n] = __builtin_amdgcn_mfma_f32_16x16x32_bf16(af[m], bh[n], acc[m][n], 0, 0, 0);
          acc[m][n] = __builtin_amdgcn_mfma_f32_16x16x32_bf16(af[m], bl[n], acc[m][n], 0, 0, 0);
        }
      __syncthreads();
    }
#undef STAGE

    const int kj = lane >> 4, l15 = lane & 15;
    #pragma unroll
    for (int m = 0; m < 4; ++m)
      #pragma unroll
      for (int n = 0; n < 4; ++n)
        #pragma unroll
        for (int r = 0; r < 4; ++r) {
          int row = m0 + wm * 64 + m * 16 + kj * 4 + r;
          int col = n0 + wn * 64 + n * 16 + l15;
          G2h[(size_t)row * 512 + col] = f2b(acc[m][n][r]);
        }
  } else {
    // ---- beff ----
    int w = threadIdx.x >> 6, lane = threadIdx.x & 63;
    int t = (blk - 64) * 4 + w;  // 0..2047
    int b = t >> 9, o = t & 511;
    size_t base = ((size_t)b * 512 + o) * 512;
    float s = 0.f;
    #pragma unroll
    for (int c = 0; c < 512; c += 64) {
      float m = b2f(Mfh[base + c + lane]) + b2f(Mfl[base + c + lane]);
      s += bqkv[1024 + c + lane] * m;
    }
    #pragma unroll
    for (int off = 32; off > 0; off >>= 1) s += __shfl_down(s, off);
    if (lane == 0) beff[t] = s + bproj[o];
  }
}

// ---------------------------------------------------------------------------
extern "C" void kernel_launch(void* const* d_in, const int* in_sizes, int n_in,
                              void* d_out, int out_size, void* d_ws, size_t ws_size,
                              hipStream_t stream) {
  const float* x    = (const float*)d_in[0];
  const float* lpw  = (const float*)d_in[1];
  const float* lvw  = (const float*)d_in[2];
  const float* wqkv = (const float*)d_in[3];
  const float* bqkv = (const float*)d_in[4];
  const float* wproj= (const float*)d_in[5];
  const float* bproj= (const float*)d_in[6];
  const float* omega= (const float*)d_in[7];
  const float* w1   = (const float*)d_in[8];
  const float* b1   = (const float*)d_in[9];
  const float* w2   = (const float*)d_in[10];
  const float* b2   = (const float*)d_in[11];
  const float* wg   = (const float*)d_in[12];
  const float* bg   = (const float*)d_in[13];
  float* out = (float*)d_out;

  constexpr size_t MB = 1024 * 1024;
  char* w = (char*)d_ws;
  int*   pcntP  = (int*)(w);                      // 64 KiB
  int*   pcntV  = (int*)(w + 64 * 1024);          // 64 KiB
  float* attn   = (float*)(w + 128 * 1024);
  float* gate   = (float*)(w + 144 * 1024);
  float* etabP  = (float*)(w + 160 * 1024);
  float* etabV  = (float*)(w + 176 * 1024);
  float* fcntP  = (float*)(w + 192 * 1024);
  float* fcntV  = (float*)(w + 208 * 1024);
  float* pe2    = (float*)(w + 256 * 1024);       // 1 MiB
  float* gpe    = (float*)(w + 1280 * 1024);
  float* ropem  = (float*)(w + 1344 * 1024);      // 1 MiB
  ushort* Xh    = (ushort*)(w + 4 * MB);          // 16 MiB
  ushort* qT    = (ushort*)(w + 20 * MB);         // 16 MiB [B,H,D,N]
  ushort* kT    = (ushort*)(w + 36 * MB);         // 16 MiB
  ushort* Whqk  = (ushort*)(w + 52 * MB);         // 1 MiB
  ushort* Wvth  = (ushort*)(w + 53 * MB);         // 0.5 MiB
  ushort* Wvtl  = (ushort*)(w + 53 * MB + 512 * 1024);  // 0.5 MiB
  ushort* Mfh   = (ushort*)(w + 54 * MB);         // 2 MiB [B*512][512]
  ushort* Mfl   = (ushort*)(w + 56 * MB);         // 2 MiB
  ushort* G2h   = (ushort*)(w + 58 * MB);         // 2 MiB
  float* beff   = (float*)(w + 60 * MB);          // 8 KiB
  float* ctxp   = (float*)(w + 61 * MB);          // 8 MiB
  float* ctx    = (float*)(w + 69 * MB);          // 0.5 MiB -> 69.5 MiB

  // fused front: counts_prep (1024) | pe (512) | prep_h (256) | prep_wvt (64)
  k_front<<<1856, 512, 0, stream>>>(x, pcntP, pcntV, Xh, omega, w1, b1, w2, b2,
                                    pe2, wqkv, Whqk, Wvth, Wvtl);
  // fused: etab2 (16) | gatepe (1)
  k_mid1<<<17, 256, 0, stream>>>(lpw, lvw, pcntP, pcntV, etabP, etabV,
                                 fcntP, fcntV, pe2, wg, bg, gpe);
  // fused: gsum (4096) | ropemul (1024)
  k_mid2<<<5120, 256, 0, stream>>>(fcntP, fcntV, etabP, etabV, attn,
                                   pe2, gpe, ropem);
  k_norm<<<1, 1024, 0, stream>>>(attn, gate);

  // q,k GEMM: M=16384, N=1024 -> 512 blocks (2/CU), 512 threads
  k_gemm8<128, 1><<<512, 512, 0, stream>>>(Xh, Whqk, bqkv, gate, ropem,
                                           nullptr, qT, kT, 8, 0);
  k_ctx_mfma<<<512, 256, 0, stream>>>(qT, kT, ctxp);
  k_ctx_red<<<512, 256, 0, stream>>>(ctxp, ctx);
  k_mproj<<<256, 256, 0, stream>>>(ctx, wproj, Mfh, Mfl);
  // fused: g2 (64) | beff (512)
  k_tail<<<576, 256, 0, stream>>>(Mfh, Mfl, Wvth, Wvtl, G2h, bqkv, bproj, beff);

  // out GEMM: M=16384, N=512, BN=64 -> 512 blocks, 512 threads
  k_gemm8<64, 2><<<512, 512, 0, stream>>>(Xh, G2h, beff, gate, nullptr,
                                          out, nullptr, nullptr, 8, 512);
}